// Round 3
// baseline (953.344 us; speedup 1.0000x reference)
//
#include <hip/hip_runtime.h>
#include <math.h>

constexpr int N  = 60000;
constexpr int F  = 256;
constexpr int H  = 128;
constexpr int C  = 256;
constexpr int E  = 600000;
constexpr int ET = 1500;

// ---------------- histograms (cell-dst degree + cluster counts) ----------------
__global__ void hg_hist(const int* __restrict__ cdst, int* __restrict__ deg,
                        const int* __restrict__ lab, int* __restrict__ ccnt) {
  int e = blockIdx.x * 256 + threadIdx.x;
  if (e < E) atomicAdd(&deg[cdst[e]], 1);
  if (e < N) atomicAdd(&ccnt[lab[e]], 1);
}

// single-block exclusive scan of deg[0..n) -> off[0..n]
__global__ __launch_bounds__(1024) void hg_scan_one(const int* __restrict__ deg, int* __restrict__ off, int n) {
  __shared__ int ls[1024];
  int t = threadIdx.x;
  const int per = (n + 1023) / 1024;
  int i0 = t * per, i1 = min(n, i0 + per);
  int s = 0;
  for (int i = i0; i < i1; ++i) s += deg[i];
  ls[t] = s;
  __syncthreads();
  for (int ofs = 1; ofs < 1024; ofs <<= 1) {
    int v = (t >= ofs) ? ls[t - ofs] : 0;
    __syncthreads();
    ls[t] += v;
    __syncthreads();
  }
  int run = ls[t] - s;
  for (int i = i0; i < i1; ++i) { int d = deg[i]; off[i] = run; run += d; }
  if (t == 1023) off[n] = ls[t];
}

__global__ void hg_cell_scatter(const int* __restrict__ csrc, const int* __restrict__ cdst,
                                const int* __restrict__ off, int* __restrict__ cur, int* __restrict__ csr) {
  int e = blockIdx.x * 256 + threadIdx.x;
  if (e < E) {
    int d = cdst[e];
    int p = atomicAdd(&cur[d], 1);
    csr[off[d] + p] = csrc[e];
  }
}

__global__ void hg_clu_scan(const int* __restrict__ cnt, int* __restrict__ coff) {
  __shared__ int s[256];
  int t = threadIdx.x;
  int v0 = cnt[t];
  s[t] = v0;
  __syncthreads();
  for (int ofs = 1; ofs < 256; ofs <<= 1) {
    int v = (t >= ofs) ? s[t - ofs] : 0;
    __syncthreads();
    s[t] += v;
    __syncthreads();
  }
  coff[t + 1] = s[t];
  if (t == 0) coff[0] = 0;
}

__global__ void hg_clu_scatter(const int* __restrict__ lab, const int* __restrict__ coff,
                               int* __restrict__ cur, int* __restrict__ list) {
  int i = blockIdx.x * 256 + threadIdx.x;
  if (i < N) {
    int c = lab[i];
    int p = atomicAdd(&cur[c], 1);
    list[coff[c] + p] = i;
  }
}

// tissue CSR (dst-major) + dinv, single block
__global__ __launch_bounds__(256) void hg_tissue_csr(const int* __restrict__ tsrc, const int* __restrict__ tdst,
                                                     int* __restrict__ toff, int* __restrict__ tlist,
                                                     float* __restrict__ dinv) {
  __shared__ int hst[256], incl[256], pos[256];
  int t = threadIdx.x;
  hst[t] = 0;
  __syncthreads();
  for (int e = t; e < ET; e += 256) atomicAdd(&hst[tdst[e]], 1);
  __syncthreads();
  int v = hst[t];
  dinv[t] = rsqrtf((float)(v + 1));
  incl[t] = v;
  __syncthreads();
  for (int ofs = 1; ofs < 256; ofs <<= 1) {
    int u = (t >= ofs) ? incl[t - ofs] : 0;
    __syncthreads();
    incl[t] += u;
    __syncthreads();
  }
  toff[t + 1] = incl[t];
  if (t == 0) toff[0] = 0;
  pos[t] = incl[t] - v;
  __syncthreads();
  for (int e = t; e < ET; e += 256) {
    int d = tdst[e];
    int p = atomicAdd(&pos[d], 1);
    tlist[p] = tsrc[e];
  }
}

// ---------------- weight transposes ----------------
struct TArgs { const float* src[10]; float* dst[10]; int R[10]; int Cc[10]; };

__global__ __launch_bounds__(256) void hg_transpose(TArgs a) {
  int job = blockIdx.y;
  int R = a.R[job], Cc = a.Cc[job];
  int total = R * Cc;
  const float* s = a.src[job];
  float* d = a.dst[job];
  for (int idx = blockIdx.x * 256 + threadIdx.x; idx < total; idx += gridDim.x * 256) {
    int cI = idx / R, r = idx - cI * R;
    d[idx] = s[r * Cc + cI];
  }
}

// ---------------- composite weight precompute ----------------
__global__ __launch_bounds__(256) void hg_pc0(const float* __restrict__ gatW1, const float* __restrict__ Wcp,
                                              const float* __restrict__ bcp, float* __restrict__ Wcompt,
                                              float* __restrict__ bcomp) {
  int j = blockIdx.x, k = threadIdx.x;
  float a = 0.f;
#pragma unroll 4
  for (int m = 0; m < 128; ++m) a = fmaf(gatW1[j * 128 + m], Wcp[m * 256 + k], a);
  Wcompt[k * 128 + j] = a;
  if (k == 0) {
    float b = 0.f;
    for (int m = 0; m < 128; ++m) b = fmaf(gatW1[j * 128 + m], bcp[m], b);
    bcomp[j] = b;
  }
}

__global__ __launch_bounds__(128) void hg_pc1(const float* __restrict__ tdWo, const float* __restrict__ tdWv,
                                              const float* __restrict__ tdbv, const float* __restrict__ tdbo,
                                              float* __restrict__ A_td, float* __restrict__ Wcat_t,
                                              float* __restrict__ bcat) {
  int j = blockIdx.x, k = threadIdx.x;
  float a = 0.f;
#pragma unroll 4
  for (int p = 0; p < 128; ++p) a = fmaf(tdWo[j * 128 + p], tdWv[p * 128 + k], a);
  A_td[j * 128 + k] = a;
  Wcat_t[k * 896 + j] = a;
  if (k == 0) {
    float b = 0.f;
    for (int p = 0; p < 128; ++p) b = fmaf(tdWo[j * 128 + p], tdbv[p], b);
    bcat[j] = b + tdbo[j];
  }
}

__global__ __launch_bounds__(128) void hg_pc2(const float* __restrict__ Wih, const float* __restrict__ bih,
                                              const float* __restrict__ Whh, const float* __restrict__ bhh,
                                              const float* __restrict__ A_td, float* __restrict__ Wcat_t,
                                              float* __restrict__ bcat) {
  int jj = blockIdx.x, k = threadIdx.x;
  const float* coef;
  float extra, bb;
  int dcol;
  int j;
  if (jj < 384) {
    j = jj; coef = Wih + (size_t)j * 256; extra = Wih[(size_t)j * 256 + 128 + k]; dcol = 128 + j; bb = bih[j];
  } else {
    j = jj - 384; coef = Whh + (size_t)j * 128; extra = 0.f; dcol = 512 + j; bb = bhh[j];
  }
  float a = 0.f;
#pragma unroll 4
  for (int m = 0; m < 128; ++m) a = fmaf(coef[m], A_td[m * 128 + k], a);
  Wcat_t[k * 896 + dcol] = a + extra;
  if (k == 0) {
    float b = 0.f;
    for (int m = 0; m < 128; ++m) b = fmaf(coef[m], bcat[m], b);
    bcat[dcol] = b + bb;
  }
}

// ---------------- tissue init: per-cluster mean + projection ----------------
__global__ __launch_bounds__(256) void hg_tissue_init(const float* __restrict__ feat, const int* __restrict__ list,
                                                      const int* __restrict__ coff, const float* __restrict__ Wtpt,
                                                      const float* __restrict__ btp, float* __restrict__ tish) {
  int c = blockIdx.x, t = threadIdx.x;
  __shared__ float mrow[256];
  int s0 = coff[c], n = coff[c + 1] - s0;
  float acc = 0.f;
#pragma unroll 4
  for (int i = 0; i < n; ++i) acc += feat[(size_t)list[s0 + i] * F + t];
  mrow[t] = acc / fmaxf((float)n, 1.f);
  __syncthreads();
  if (t < 128) {
    float a = btp[t];
#pragma unroll 4
    for (int k = 0; k < 256; ++k) a = fmaf(mrow[k], Wtpt[k * 128 + t], a);
    tish[c * 128 + t] = a;
  }
}

// ---------------- persistent GEMM (K=256) with GAT-coef epilogue ----------------
__global__ __launch_bounds__(256) void hg_gemm_coef(
    const float* __restrict__ A, int M,
    const float* __restrict__ Wt, const float* __restrict__ bias,
    float* __restrict__ outp,
    const float* __restrict__ avs, const float* __restrict__ avd,
    float* __restrict__ o_s, float* __restrict__ o_d,
    int* __restrict__ ticket) {
  __shared__ float Alds[64][68];
  __shared__ float Wlds[64][132];
  __shared__ int sh_tile;
  const int t = threadIdx.x;
  const int tx = t & 15, ty = t >> 4;
  const int ntiles = (M + 63) >> 6;

  for (;;) {
    if (t == 0) sh_tile = atomicAdd(ticket, 1);
    __syncthreads();
    const int tile = sh_tile;
    __syncthreads();
    if (tile >= ntiles) break;
    const int m0 = tile * 64;

    float acc[4][8];
#pragma unroll
    for (int r = 0; r < 4; ++r)
#pragma unroll
      for (int c = 0; c < 8; ++c) acc[r][c] = 0.f;

    for (int kc = 0; kc < 256; kc += 64) {
#pragma unroll
      for (int i = 0; i < 4; ++i) {
        int row = ty + i * 16;
        int gm = m0 + row;
        float4 v = make_float4(0.f, 0.f, 0.f, 0.f);
        if (gm < M) v = *(const float4*)&A[(size_t)gm * 256 + kc + tx * 4];
        *(float4*)&Alds[row][tx * 4] = v;
      }
      {
        int c4 = t & 31, r0 = t >> 5;
#pragma unroll
        for (int i = 0; i < 8; ++i) {
          int row = r0 + i * 8;
          *(float4*)&Wlds[row][c4 * 4] = *(const float4*)&Wt[(size_t)(kc + row) * 128 + c4 * 4];
        }
      }
      __syncthreads();
#pragma unroll 4
      for (int k4 = 0; k4 < 16; ++k4) {
        float4 av[4];
#pragma unroll
        for (int r = 0; r < 4; ++r) av[r] = *(const float4*)&Alds[ty * 4 + r][k4 * 4];
#pragma unroll
        for (int kk = 0; kk < 4; ++kk) {
          float4 w0 = *(const float4*)&Wlds[k4 * 4 + kk][tx * 4];
          float4 w1 = *(const float4*)&Wlds[k4 * 4 + kk][64 + tx * 4];
          float wr[8] = {w0.x, w0.y, w0.z, w0.w, w1.x, w1.y, w1.z, w1.w};
#pragma unroll
          for (int r = 0; r < 4; ++r) {
            float a = (kk == 0) ? av[r].x : (kk == 1) ? av[r].y : (kk == 2) ? av[r].z : av[r].w;
#pragma unroll
            for (int c = 0; c < 8; ++c) acc[r][c] = fmaf(a, wr[c], acc[r][c]);
          }
        }
      }
      __syncthreads();
    }

    {
      float bA[8];
#pragma unroll
      for (int c = 0; c < 4; ++c) {
        bA[c] = bias[tx * 4 + c];
        bA[4 + c] = bias[64 + tx * 4 + c];
      }
#pragma unroll
      for (int r = 0; r < 4; ++r)
#pragma unroll
        for (int c = 0; c < 8; ++c) acc[r][c] += bA[c];
    }

#pragma unroll
    for (int r = 0; r < 4; ++r) {
      int gm = m0 + ty * 4 + r;
      if (gm < M) {
        float* op = outp + (size_t)gm * 128 + tx * 4;
        *(float4*)op        = make_float4(acc[r][0], acc[r][1], acc[r][2], acc[r][3]);
        *(float4*)(op + 64) = make_float4(acc[r][4], acc[r][5], acc[r][6], acc[r][7]);
      }
    }

    {
      float4 s0 = *(const float4*)&avs[tx * 4], s1 = *(const float4*)&avs[64 + tx * 4];
      float4 d0 = *(const float4*)&avd[tx * 4], d1 = *(const float4*)&avd[64 + tx * 4];
#pragma unroll
      for (int r = 0; r < 4; ++r) {
        float psA = acc[r][0] * s0.x + acc[r][1] * s0.y + acc[r][2] * s0.z + acc[r][3] * s0.w;
        float psB = acc[r][4] * s1.x + acc[r][5] * s1.y + acc[r][6] * s1.z + acc[r][7] * s1.w;
        float pdA = acc[r][0] * d0.x + acc[r][1] * d0.y + acc[r][2] * d0.z + acc[r][3] * d0.w;
        float pdB = acc[r][4] * d1.x + acc[r][5] * d1.y + acc[r][6] * d1.z + acc[r][7] * d1.w;
        psA += __shfl_xor(psA, 1); psA += __shfl_xor(psA, 2);
        psB += __shfl_xor(psB, 1); psB += __shfl_xor(psB, 2);
        pdA += __shfl_xor(pdA, 1); pdA += __shfl_xor(pdA, 2);
        pdB += __shfl_xor(pdB, 1); pdB += __shfl_xor(pdB, 2);
        int gm = m0 + ty * 4 + r;
        if ((tx & 3) == 0 && gm < M) {
          int h = tx >> 2;
          o_s[(size_t)gm * 8 + h] = psA;
          o_s[(size_t)gm * 8 + 4 + h] = psB;
          o_d[(size_t)gm * 8 + h] = pdA;
          o_d[(size_t)gm * 8 + 4 + h] = pdB;
        }
      }
    }
  }
}

// ---------------- single-pass K+V GEMM (K=128) with s_att epilogue ----------------
#define KV_COMPUTE(ACC)                                                              \
  _Pragma("unroll 4")                                                                \
  for (int k4 = 0; k4 < 16; ++k4) {                                                  \
    float4 av[4];                                                                    \
    _Pragma("unroll")                                                                \
    for (int r = 0; r < 4; ++r) av[r] = *(const float4*)&Alds[ty * 4 + r][k4 * 4];   \
    _Pragma("unroll")                                                                \
    for (int kk = 0; kk < 4; ++kk) {                                                 \
      float4 w0 = *(const float4*)&Wlds[k4 * 4 + kk][tx * 4];                        \
      float4 w1 = *(const float4*)&Wlds[k4 * 4 + kk][64 + tx * 4];                   \
      float wr[8] = {w0.x, w0.y, w0.z, w0.w, w1.x, w1.y, w1.z, w1.w};                \
      _Pragma("unroll")                                                              \
      for (int r = 0; r < 4; ++r) {                                                  \
        float a = (kk == 0) ? av[r].x : (kk == 1) ? av[r].y : (kk == 2) ? av[r].z : av[r].w; \
        _Pragma("unroll")                                                            \
        for (int c = 0; c < 8; ++c) ACC[r][c] = fmaf(a, wr[c], ACC[r][c]);           \
      }                                                                              \
    }                                                                                \
  }

__global__ __launch_bounds__(256) void hg_gemm_kv(
    const float* __restrict__ A, int M,
    const float* __restrict__ Wkt, const float* __restrict__ bk,
    const float* __restrict__ Wvt, const float* __restrict__ bv,
    const float* __restrict__ q, const int* __restrict__ lab,
    float* __restrict__ vout, float* __restrict__ satt,
    int* __restrict__ ticket) {
  __shared__ float Alds[64][68];
  __shared__ float Wlds[64][132];
  __shared__ int sh_tile;
  const int t = threadIdx.x, tx = t & 15, ty = t >> 4;
  const int ntiles = (M + 63) >> 6;

  for (;;) {
    if (t == 0) sh_tile = atomicAdd(ticket, 1);
    __syncthreads();
    const int tile = sh_tile;
    __syncthreads();
    if (tile >= ntiles) break;
    const int m0 = tile * 64;

    float acck[4][8], accv[4][8];
#pragma unroll
    for (int r = 0; r < 4; ++r)
#pragma unroll
      for (int c = 0; c < 8; ++c) { acck[r][c] = 0.f; accv[r][c] = 0.f; }

    for (int kc = 0; kc < 128; kc += 64) {
#pragma unroll
      for (int i = 0; i < 4; ++i) {
        int row = ty + i * 16, gm = m0 + row;
        float4 v4 = make_float4(0.f, 0.f, 0.f, 0.f);
        if (gm < M) v4 = *(const float4*)&A[(size_t)gm * 128 + kc + tx * 4];
        *(float4*)&Alds[row][tx * 4] = v4;
      }
      {
        int c4 = t & 31, r0 = t >> 5;
#pragma unroll
        for (int i = 0; i < 8; ++i) {
          int row = r0 + i * 8;
          *(float4*)&Wlds[row][c4 * 4] = *(const float4*)&Wkt[(size_t)(kc + row) * 128 + c4 * 4];
        }
      }
      __syncthreads();
      KV_COMPUTE(acck);
      __syncthreads();
      {
        int c4 = t & 31, r0 = t >> 5;
#pragma unroll
        for (int i = 0; i < 8; ++i) {
          int row = r0 + i * 8;
          *(float4*)&Wlds[row][c4 * 4] = *(const float4*)&Wvt[(size_t)(kc + row) * 128 + c4 * 4];
        }
      }
      __syncthreads();
      KV_COMPUTE(accv);
      __syncthreads();
    }

#pragma unroll
    for (int c = 0; c < 4; ++c) {
      float bkA = bk[tx * 4 + c], bkB = bk[64 + tx * 4 + c];
      float bvA = bv[tx * 4 + c], bvB = bv[64 + tx * 4 + c];
#pragma unroll
      for (int r = 0; r < 4; ++r) {
        acck[r][c] += bkA; acck[r][4 + c] += bkB;
        accv[r][c] += bvA; accv[r][4 + c] += bvB;
      }
    }

#pragma unroll
    for (int r = 0; r < 4; ++r) {
      int gm = m0 + ty * 4 + r;
      if (gm < M) {
        float* op = vout + (size_t)gm * 128 + tx * 4;
        *(float4*)op        = make_float4(accv[r][0], accv[r][1], accv[r][2], accv[r][3]);
        *(float4*)(op + 64) = make_float4(accv[r][4], accv[r][5], accv[r][6], accv[r][7]);
      }
    }

#pragma unroll
    for (int r = 0; r < 4; ++r) {
      int gm = m0 + ty * 4 + r;
      int lr = (gm < M) ? lab[gm] : 0;
      float4 q0 = *(const float4*)&q[(size_t)lr * 128 + tx * 4];
      float4 q1 = *(const float4*)&q[(size_t)lr * 128 + 64 + tx * 4];
      float psA = acck[r][0] * q0.x + acck[r][1] * q0.y + acck[r][2] * q0.z + acck[r][3] * q0.w;
      float psB = acck[r][4] * q1.x + acck[r][5] * q1.y + acck[r][6] * q1.z + acck[r][7] * q1.w;
      psA += __shfl_xor(psA, 1); psA += __shfl_xor(psA, 2);
      psB += __shfl_xor(psB, 1); psB += __shfl_xor(psB, 2);
      if ((tx & 3) == 0 && gm < M) {
        int h = tx >> 2;
        satt[(size_t)gm * 8 + h] = psA;
        satt[(size_t)gm * 8 + 4 + h] = psB;
      }
    }
  }
}

// ---------------- GAT aggregation: one WAVE per dst node ----------------
#define GMAXE 64
__global__ __launch_bounds__(256) void hg_gat_agg(const float* __restrict__ hproj, const float* __restrict__ a_s,
                                                  const float* __restrict__ a_d, const int* __restrict__ remap,
                                                  const int* __restrict__ off, const int* __restrict__ csr,
                                                  const float* __restrict__ bias, float* __restrict__ outh,
                                                  int nNodes) {
  const int wid = threadIdx.x >> 6;
  const int l = threadIdx.x & 63;
  const int node = blockIdx.x * 4 + wid;
  __shared__ int srcs_s[4][GMAXE];
  __shared__ float w_s[4][GMAXE][8];
  if (node >= nNodes) return;
  int* srcs = srcs_s[wid];
  float (*wls)[8] = w_s[wid];
  const int o0 = off[node], deg = off[node + 1] - o0;
  const int dl = remap ? remap[node] : node;
  const int hsc = l & 7;   // score-space head
  const int hf  = l >> 3;  // accumulate-space head (features 2l, 2l+1)
  const float adh = a_d[dl * 8 + hsc];
  const float ash = a_s[dl * 8 + hsc];
  float msc = -INFINITY, zsc = 0.f;
  float2 acc = make_float2(0.f, 0.f);
  const float2* hp2 = (const float2*)hproj;

  for (int cb = 0; cb < deg; cb += GMAXE) {
    const int len = min(GMAXE, deg - cb);
    if (l < len) {
      int s = csr[o0 + cb + l];
      srcs[l] = remap ? remap[s] : s;
    }
    asm volatile("s_waitcnt lgkmcnt(0)" ::: "memory");
    // raw scores (one lane per (edge, head))
    float lm = -INFINITY;
    for (int base = 0; base < len; base += 8) {
      int e = base + (l >> 3);
      if (e < len) {
        float sc = a_s[srcs[e] * 8 + hsc] + adh;
        sc = sc > 0.f ? sc : 0.2f * sc;
        wls[e][hsc] = sc;
        lm = fmaxf(lm, sc);
      }
    }
    lm = fmaxf(lm, __shfl_xor(lm, 8));
    lm = fmaxf(lm, __shfl_xor(lm, 16));
    lm = fmaxf(lm, __shfl_xor(lm, 32));
    float mnew = fmaxf(msc, lm);
    float rs = __expf(msc - mnew);  // 0 on first chunk
    float zc = 0.f;
    for (int base = 0; base < len; base += 8) {
      int e = base + (l >> 3);
      if (e < len) {
        float wv = __expf(wls[e][hsc] - mnew);
        wls[e][hsc] = wv;
        zc += wv;
      }
    }
    asm volatile("s_waitcnt lgkmcnt(0)" ::: "memory");
    zc += __shfl_xor(zc, 8); zc += __shfl_xor(zc, 16); zc += __shfl_xor(zc, 32);
    zsc = zsc * rs + zc;
    msc = mnew;
    float rsa = __shfl(rs, hf * 9);
    acc.x *= rsa; acc.y *= rsa;
#pragma unroll 4
    for (int e = 0; e < len; ++e) {
      float wv = wls[e][hf];
      float2 hv = hp2[(size_t)srcs[e] * 64 + l];
      acc.x = fmaf(wv, hv.x, acc.x);
      acc.y = fmaf(wv, hv.y, acc.y);
    }
  }
  // self-loop
  float ssl = ash + adh;
  ssl = ssl > 0.f ? ssl : 0.2f * ssl;
  float mnew = fmaxf(msc, ssl);
  float rs = __expf(msc - mnew);
  float wsl = __expf(ssl - mnew);
  zsc = zsc * rs + wsl;
  float rsa = __shfl(rs, hf * 9);
  float wsa = __shfl(wsl, hf * 9);
  float2 hv = hp2[(size_t)dl * 64 + l];
  acc.x = acc.x * rsa + wsa * hv.x;
  acc.y = acc.y * rsa + wsa * hv.y;
  float zh = __shfl(zsc, hf * 9);
  float2 bv = *(const float2*)&bias[l * 2];
  float ox = acc.x / zh + bv.x;
  float oy = acc.y / zh + bv.y;
  ox = ox > 0.f ? ox : expm1f(ox);
  oy = oy > 0.f ? oy : expm1f(oy);
  ((float2*)outh)[(size_t)node * 64 + l] = make_float2(ox, oy);
}

// ---------------- tissue GCN (agg-then-project, fused g-GEMM) + q projection ----------------
__global__ __launch_bounds__(128) void hg_gcn_q(const float* __restrict__ tin, const int* __restrict__ toff,
                                                const int* __restrict__ tlist, const float* __restrict__ dinv,
                                                const float* __restrict__ gt, const float* __restrict__ gcnb,
                                                const float* __restrict__ Wqt, const float* __restrict__ bq,
                                                float* __restrict__ q) {
  int c = blockIdx.x, t = threadIdx.x;
  __shared__ float xa[128], trow[128];
  float dc = dinv[c];
  float acc = tin[c * 128 + t] * dc * dc;
  int s0 = toff[c], s1 = toff[c + 1];
  for (int i = s0; i < s1; ++i) {
    int s = tlist[i];
    acc = fmaf(tin[s * 128 + t], dinv[s] * dc, acc);
  }
  xa[t] = acc;
  __syncthreads();
  float th = 0.f;
#pragma unroll 4
  for (int k = 0; k < 128; ++k) th = fmaf(xa[k], gt[k * 128 + t], th);
  float vv = fmaxf(th + gcnb[t], 0.f);
  trow[t] = vv;
  __syncthreads();
  float qa = bq[t];
#pragma unroll 4
  for (int k = 0; k < 128; ++k) qa = fmaf(trow[k], Wqt[k * 128 + t], qa);
  q[c * 128 + t] = qa * 0.25f;  // 1/sqrt(DH)
}

// ---------------- bottom-up per-cluster softmax + context (2-way cell split) ----------------
__global__ __launch_bounds__(256) void hg_bu_ctx(const float* __restrict__ s_att, const float* __restrict__ v,
                                                 const int* __restrict__ list, const int* __restrict__ coff,
                                                 float* __restrict__ ctx) {
  int c = blockIdx.x, t = threadIdx.x;
  int s0 = coff[c], n = coff[c + 1] - s0;
  int tf = t & 127, half = t >> 7;
  __shared__ float red[32][8];
  __shared__ float mh[8];
  __shared__ float accs[128];
  __shared__ float zsh[16];
  int g = t >> 3, h8 = t & 7;
  float lm = -INFINITY;
  for (int i = g; i < n; i += 32) lm = fmaxf(lm, s_att[(size_t)list[s0 + i] * 8 + h8]);
  red[g][h8] = lm;
  __syncthreads();
  if (t < 8) {
    float m2 = -INFINITY;
#pragma unroll
    for (int i = 0; i < 32; ++i) m2 = fmaxf(m2, red[i][t]);
    mh[t] = m2;
  }
  __syncthreads();
  int h = tf >> 4;
  float m = mh[h], z = 0.f, acc = 0.f;
#pragma unroll 2
  for (int i = half; i < n; i += 2) {
    int cell = list[s0 + i];
    float w = __expf(s_att[(size_t)cell * 8 + h] - m);
    acc = fmaf(w, v[(size_t)cell * 128 + tf], acc);
    z += w;
  }
  if (half) accs[tf] = acc;
  if ((tf & 15) == 0) zsh[half * 8 + h] = z;
  __syncthreads();
  if (!half) {
    float at = acc + accs[tf];
    float zt = zsh[h] + zsh[8 + h];
    ctx[c * 128 + tf] = (n > 0) ? at / zt : 0.f;
  }
}

// ---------------- fused cluster chain: Wo, td+GRU composite, gates, next-layer GAT proj ----------------
__global__ __launch_bounds__(256) void hg_chain(
    const float* __restrict__ ctx, const float* __restrict__ Wot, const float* __restrict__ bo,
    const float* __restrict__ Wcat_t, const float* __restrict__ bcat,
    const float* __restrict__ gatWt, const float* __restrict__ avs, const float* __restrict__ avd,
    float* __restrict__ tish, float* __restrict__ ccell,
    float* __restrict__ hprojc, float* __restrict__ a_s2, float* __restrict__ a_d2) {
  int c = blockIdx.x, t = threadIdx.x;
  int tf = t & 127, ks = t >> 7;
  __shared__ float b0[128], b1[128], part[2][128], catv[896];
  if (t < 128) b0[t] = ctx[c * 128 + t];
  __syncthreads();
  // stage 1: tissue_h = ctx @ Wo^T + bo   (2-way k-split)
  {
    float ps = 0.f;
    const float* wp = Wot + (size_t)ks * 64 * 128 + tf;
#pragma unroll 4
    for (int k = 0; k < 64; ++k) ps = fmaf(b0[ks * 64 + k], wp[k * 128], ps);
    part[ks][tf] = ps;
  }
  __syncthreads();
  if (t < 128) {
    float v = part[0][t] + part[1][t] + bo[t];
    b1[t] = v;
    tish[c * 128 + t] = v;
  }
  __syncthreads();
  // stage 2: catv = b1 @ Wcat + bcat  (896 outputs)
  for (int j = t; j < 896; j += 256) {
    float a = bcat[j];
#pragma unroll 4
    for (int k = 0; k < 128; ++k) a = fmaf(b1[k], Wcat_t[k * 896 + j], a);
    catv[j] = a;
  }
  __syncthreads();
  // stage 3: GRU gates -> new cell_h (per cluster)
  if (t < 128) {
    float td = catv[t];
    float r = 1.f / (1.f + expf(-(catv[128 + t] + catv[512 + t])));
    float z = 1.f / (1.f + expf(-(catv[256 + t] + catv[640 + t])));
    float nn = tanhf(catv[384 + t] + r * catv[768 + t]);
    float cn = (1.f - z) * nn + z * td;
    ccell[c * 128 + t] = cn;
    b0[t] = cn;
  }
  __syncthreads();
  // stage 4: next-layer GAT projection + coefs
  if (gatWt) {
    float ps = 0.f;
    const float* wp = gatWt + (size_t)ks * 64 * 128 + tf;
#pragma unroll 4
    for (int k = 0; k < 64; ++k) ps = fmaf(b0[ks * 64 + k], wp[k * 128], ps);
    part[ks][tf] = ps;
    __syncthreads();
    if (t < 128) {
      float hp = part[0][t] + part[1][t];
      hprojc[c * 128 + t] = hp;
      float pss = hp * avs[t], pdd = hp * avd[t];
      pss += __shfl_xor(pss, 1); pss += __shfl_xor(pss, 2); pss += __shfl_xor(pss, 4); pss += __shfl_xor(pss, 8);
      pdd += __shfl_xor(pdd, 1); pdd += __shfl_xor(pdd, 2); pdd += __shfl_xor(pdd, 4); pdd += __shfl_xor(pdd, 8);
      if ((t & 15) == 0) {
        a_s2[c * 8 + (t >> 4)] = pss;
        a_d2[c * 8 + (t >> 4)] = pdd;
      }
    }
  }
}

// ---------------- readout + classifier ----------------
__global__ __launch_bounds__(256) void hg_readout(const float* __restrict__ ccell2, const float* __restrict__ tish,
                                                  const int* __restrict__ cnt, const float* __restrict__ Wc1t,
                                                  const float* __restrict__ bc1, const float* __restrict__ Wc2t,
                                                  const float* __restrict__ bc2, const float* __restrict__ Wc3,
                                                  const float* __restrict__ bc3, float* __restrict__ outp) {
  __shared__ float emb[512], h1s[256], h2s[128];
  int t = threadIdx.x;
  if (t < 128) {
    float sm = 0.f, mx = -INFINITY;
    for (int c = 0; c < C; ++c) {
      float vv = ccell2[c * 128 + t];
      int n = cnt[c];
      sm += (float)n * vv;
      if (n > 0) mx = fmaxf(mx, vv);
    }
    emb[t] = sm / (float)N;
    emb[128 + t] = mx;
  } else {
    int tt = t - 128;
    float sm = 0.f, mx = -INFINITY;
    for (int c = 0; c < C; ++c) {
      float vv = tish[c * 128 + tt];
      sm += vv;
      mx = fmaxf(mx, vv);
    }
    emb[256 + tt] = sm * (1.f / (float)C);
    emb[384 + tt] = mx;
  }
  __syncthreads();
  float a = bc1[t];
#pragma unroll 4
  for (int kk = 0; kk < 512; ++kk) a = fmaf(emb[kk], Wc1t[kk * 256 + t], a);
  h1s[t] = fmaxf(a, 0.f);
  __syncthreads();
  if (t < 128) {
    float a2 = bc2[t];
#pragma unroll 4
    for (int kk = 0; kk < 256; ++kk) a2 = fmaf(h1s[kk], Wc2t[kk * 128 + t], a2);
    h2s[t] = fmaxf(a2, 0.f);
  }
  __syncthreads();
  if (t < 4) {
    float o = bc3[t];
    for (int kk = 0; kk < 128; ++kk) o = fmaf(h2s[kk], Wc3[t * 128 + kk], o);
    outp[t] = o;
  }
}

// ---------------- host launcher ----------------
extern "C" void kernel_launch(void* const* d_in, const int* in_sizes, int n_in,
                              void* d_out, int out_size, void* d_ws, size_t ws_size,
                              hipStream_t stream) {
  (void)in_sizes; (void)n_in; (void)out_size; (void)ws_size;
  const float* feat  = (const float*)d_in[0];
  const int*   eidx  = (const int*)d_in[1];
  const int*   lab   = (const int*)d_in[2];
  const int*   tidx  = (const int*)d_in[3];
  const float* Wcp   = (const float*)d_in[4];
  const float* bcp   = (const float*)d_in[5];
  const float* Wtp   = (const float*)d_in[6];
  const float* btp   = (const float*)d_in[7];
  const float* gatW  = (const float*)d_in[8];
  const float* gasrc = (const float*)d_in[9];
  const float* gadst = (const float*)d_in[10];
  const float* gatb  = (const float*)d_in[11];
  const float* gcnW  = (const float*)d_in[12];
  const float* gcnb  = (const float*)d_in[13];
  const float* buWq  = (const float*)d_in[14];
  const float* buWk  = (const float*)d_in[15];
  const float* buWv  = (const float*)d_in[16];
  const float* bubq  = (const float*)d_in[17];
  const float* bubk  = (const float*)d_in[18];
  const float* bubv  = (const float*)d_in[19];
  const float* buWo  = (const float*)d_in[20];
  const float* bubo  = (const float*)d_in[21];
  const float* tdWv  = (const float*)d_in[22];
  const float* tdbv  = (const float*)d_in[23];
  const float* tdWo  = (const float*)d_in[24];
  const float* tdbo  = (const float*)d_in[25];
  const float* Wih   = (const float*)d_in[26];
  const float* bih   = (const float*)d_in[27];
  const float* Whh   = (const float*)d_in[28];
  const float* bhh   = (const float*)d_in[29];
  const float* Wc1   = (const float*)d_in[30];
  const float* bc1   = (const float*)d_in[31];
  const float* Wc2   = (const float*)d_in[32];
  const float* bc2   = (const float*)d_in[33];
  const float* Wc3   = (const float*)d_in[34];
  const float* bc3   = (const float*)d_in[35];
  float* outp = (float*)d_out;

  const int* csrc = eidx;
  const int* cdst = eidx + E;
  const int* tsrc = tidx;
  const int* tdst = tidx + ET;

  char* w = (char*)d_ws;
  auto alloc = [&](size_t bytes) -> void* {
    void* p = (void*)w;
    w += (bytes + 255) & ~(size_t)255;
    return p;
  };
  char* cnt0 = w;
  int* deg_cell = (int*)alloc((size_t)N * 4);
  int* cur_cell = (int*)alloc((size_t)N * 4);
  int* clu_cnt  = (int*)alloc((size_t)C * 4);
  int* clu_cur  = (int*)alloc((size_t)C * 4);
  int* tickets  = (int*)alloc(16 * 4);
  size_t cntBytes = (size_t)(w - cnt0);
  int* off_cell = (int*)alloc((size_t)(N + 1) * 4);
  int* csr      = (int*)alloc((size_t)E * 4);
  int* clu_off  = (int*)alloc((size_t)(C + 1) * 4);
  int* clu_list = (int*)alloc((size_t)N * 4);
  int* toff     = (int*)alloc((size_t)(C + 1) * 4);
  int* tlist    = (int*)alloc((size_t)ET * 4);
  float* dinv   = (float*)alloc((size_t)C * 4);
  float* buf1   = (float*)alloc((size_t)N * 128 * 4);
  float* buf2   = (float*)alloc((size_t)N * 128 * 4);
  float* a_s    = (float*)alloc((size_t)N * 8 * 4);
  float* a_d    = (float*)alloc((size_t)N * 8 * 4);
  float* s_att  = (float*)alloc((size_t)N * 8 * 4);
  float* tish   = (float*)alloc((size_t)C * 128 * 4);
  float* qb     = (float*)alloc((size_t)C * 128 * 4);
  float* ctxb   = (float*)alloc((size_t)C * 128 * 4);
  float* ccell  = (float*)alloc((size_t)C * 128 * 4);
  float* hprojc = (float*)alloc((size_t)C * 128 * 4);
  float* a_sc   = (float*)alloc((size_t)C * 8 * 4);
  float* a_dc   = (float*)alloc((size_t)C * 8 * 4);
  float* A_td   = (float*)alloc(128 * 128 * 4);
  float* Wcat_t = (float*)alloc(128 * 896 * 4);
  float* bcat   = (float*)alloc(896 * 4);
  float* Wcompt = (float*)alloc(256 * 128 * 4);
  float* bcomp  = (float*)alloc(128 * 4);
  float* Wtpt   = (float*)alloc(256 * 128 * 4);
  float* g1t    = (float*)alloc(128 * 128 * 4);
  float* g2t    = (float*)alloc(128 * 128 * 4);
  float* Wqt    = (float*)alloc(128 * 128 * 4);
  float* Wkt    = (float*)alloc(128 * 128 * 4);
  float* Wvt    = (float*)alloc(128 * 128 * 4);
  float* Wot    = (float*)alloc(128 * 128 * 4);
  float* gatW2t = (float*)alloc(128 * 128 * 4);
  float* Wc1t   = (float*)alloc(512 * 256 * 4);
  float* Wc2t   = (float*)alloc(256 * 128 * 4);

  hipMemsetAsync(cnt0, 0, cntBytes, stream);

  hg_hist<<<(E + 255) / 256, 256, 0, stream>>>(cdst, deg_cell, lab, clu_cnt);
  hg_scan_one<<<1, 1024, 0, stream>>>(deg_cell, off_cell, N);
  hg_cell_scatter<<<(E + 255) / 256, 256, 0, stream>>>(csrc, cdst, off_cell, cur_cell, csr);
  hg_clu_scan<<<1, 256, 0, stream>>>(clu_cnt, clu_off);
  hg_clu_scatter<<<(N + 255) / 256, 256, 0, stream>>>(lab, clu_off, clu_cur, clu_list);
  hg_tissue_csr<<<1, 256, 0, stream>>>(tsrc, tdst, toff, tlist, dinv);

  TArgs ta;
  ta.src[0] = Wtp;            ta.dst[0] = Wtpt;   ta.R[0] = 128; ta.Cc[0] = 256;
  ta.src[1] = gcnW;           ta.dst[1] = g1t;    ta.R[1] = 128; ta.Cc[1] = 128;
  ta.src[2] = gcnW + 128*128; ta.dst[2] = g2t;    ta.R[2] = 128; ta.Cc[2] = 128;
  ta.src[3] = buWq;           ta.dst[3] = Wqt;    ta.R[3] = 128; ta.Cc[3] = 128;
  ta.src[4] = buWk;           ta.dst[4] = Wkt;    ta.R[4] = 128; ta.Cc[4] = 128;
  ta.src[5] = buWv;           ta.dst[5] = Wvt;    ta.R[5] = 128; ta.Cc[5] = 128;
  ta.src[6] = buWo;           ta.dst[6] = Wot;    ta.R[6] = 128; ta.Cc[6] = 128;
  ta.src[7] = gatW + 128*128; ta.dst[7] = gatW2t; ta.R[7] = 128; ta.Cc[7] = 128;
  ta.src[8] = Wc1;            ta.dst[8] = Wc1t;   ta.R[8] = 256; ta.Cc[8] = 512;
  ta.src[9] = Wc2;            ta.dst[9] = Wc2t;   ta.R[9] = 128; ta.Cc[9] = 256;
  hg_transpose<<<dim3(64, 10), 256, 0, stream>>>(ta);

  hg_pc0<<<128, 256, 0, stream>>>(gatW, Wcp, bcp, Wcompt, bcomp);
  hg_pc1<<<128, 128, 0, stream>>>(tdWo, tdWv, tdbv, tdbo, A_td, Wcat_t, bcat);
  hg_pc2<<<768, 128, 0, stream>>>(Wih, bih, Whh, bhh, A_td, Wcat_t, bcat);

  hg_tissue_init<<<C, 256, 0, stream>>>(feat, clu_list, clu_off, Wtpt, btp, tish);

  const int gBig = 768;
  // hproj_l1 = feat @ (gatW1*Wcp)^T + comp-bias, with GAT coef epilogue
  hg_gemm_coef<<<gBig, 256, 0, stream>>>(feat, N, Wcompt, bcomp, buf2, gasrc, gadst, a_s, a_d, tickets + 0);
  // ---- layer 1 ----
  hg_gat_agg<<<(N + 3) / 4, 256, 0, stream>>>(buf2, a_s, a_d, nullptr, off_cell, csr, gatb, buf1, N);
  hg_gcn_q<<<C, 128, 0, stream>>>(tish, toff, tlist, dinv, g1t, gcnb, Wqt, bubq, qb);
  hg_gemm_kv<<<gBig, 256, 0, stream>>>(buf1, N, Wkt, bubk, Wvt, bubv, qb, lab, buf2, s_att, tickets + 1);
  hg_bu_ctx<<<C, 256, 0, stream>>>(s_att, buf2, clu_list, clu_off, ctxb);
  hg_chain<<<C, 256, 0, stream>>>(ctxb, Wot, bubo, Wcat_t, bcat, gatW2t, gasrc + 128, gadst + 128,
                                  tish, ccell, hprojc, a_sc, a_dc);
  // ---- layer 2 ----
  hg_gat_agg<<<(N + 3) / 4, 256, 0, stream>>>(hprojc, a_sc, a_dc, lab, off_cell, csr, gatb + 128, buf1, N);
  hg_gcn_q<<<C, 128, 0, stream>>>(tish, toff, tlist, dinv, g2t, gcnb + 128, Wqt, bubq, qb);
  hg_gemm_kv<<<gBig, 256, 0, stream>>>(buf1, N, Wkt, bubk, Wvt, bubv, qb, lab, buf2, s_att, tickets + 2);
  hg_bu_ctx<<<C, 256, 0, stream>>>(s_att, buf2, clu_list, clu_off, ctxb);
  hg_chain<<<C, 256, 0, stream>>>(ctxb, Wot, bubo, Wcat_t, bcat, nullptr, nullptr, nullptr,
                                  tish, ccell, nullptr, nullptr, nullptr);

  hg_readout<<<1, 256, 0, stream>>>(ccell, tish, clu_cnt, Wc1t, bc1, Wc2t, bc2, Wc3, bc3, outp);
}

// Round 4
// 826.159 us; speedup vs baseline: 1.1539x; 1.1539x over previous
//
#include <hip/hip_runtime.h>
#include <math.h>

constexpr int N  = 60000;
constexpr int F  = 256;
constexpr int H  = 128;
constexpr int C  = 256;
constexpr int E  = 600000;
constexpr int ET = 1500;

// ---------------- histograms (cell-dst degree + cluster counts) ----------------
__global__ void hg_hist(const int* __restrict__ cdst, int* __restrict__ deg,
                        const int* __restrict__ lab, int* __restrict__ ccnt) {
  int e = blockIdx.x * 256 + threadIdx.x;
  if (e < E) atomicAdd(&deg[cdst[e]], 1);
  if (e < N) atomicAdd(&ccnt[lab[e]], 1);
}

// single-block exclusive scan of deg[0..n) -> off[0..n]
__global__ __launch_bounds__(1024) void hg_scan_one(const int* __restrict__ deg, int* __restrict__ off, int n) {
  __shared__ int ls[1024];
  int t = threadIdx.x;
  const int per = (n + 1023) / 1024;
  int i0 = t * per, i1 = min(n, i0 + per);
  int s = 0;
  for (int i = i0; i < i1; ++i) s += deg[i];
  ls[t] = s;
  __syncthreads();
  for (int ofs = 1; ofs < 1024; ofs <<= 1) {
    int v = (t >= ofs) ? ls[t - ofs] : 0;
    __syncthreads();
    ls[t] += v;
    __syncthreads();
  }
  int run = ls[t] - s;
  for (int i = i0; i < i1; ++i) { int d = deg[i]; off[i] = run; run += d; }
  if (t == 1023) off[n] = ls[t];
}

__global__ void hg_cell_scatter(const int* __restrict__ csrc, const int* __restrict__ cdst,
                                const int* __restrict__ off, int* __restrict__ cur, int* __restrict__ csr) {
  int e = blockIdx.x * 256 + threadIdx.x;
  if (e < E) {
    int d = cdst[e];
    int p = atomicAdd(&cur[d], 1);
    csr[off[d] + p] = csrc[e];
  }
}

// block 0: cluster count scan; block 1: tissue CSR + dinv
__global__ __launch_bounds__(256) void hg_setup256(const int* __restrict__ cnt, int* __restrict__ coff,
                                                   const int* __restrict__ tsrc, const int* __restrict__ tdst,
                                                   int* __restrict__ toff, int* __restrict__ tlist,
                                                   float* __restrict__ dinv) {
  int t = threadIdx.x;
  if (blockIdx.x == 0) {
    __shared__ int s[256];
    int v0 = cnt[t];
    s[t] = v0;
    __syncthreads();
    for (int ofs = 1; ofs < 256; ofs <<= 1) {
      int v = (t >= ofs) ? s[t - ofs] : 0;
      __syncthreads();
      s[t] += v;
      __syncthreads();
    }
    coff[t + 1] = s[t];
    if (t == 0) coff[0] = 0;
  } else {
    __shared__ int hst[256], incl[256], pos[256];
    hst[t] = 0;
    __syncthreads();
    for (int e = t; e < ET; e += 256) atomicAdd(&hst[tdst[e]], 1);
    __syncthreads();
    int v = hst[t];
    dinv[t] = rsqrtf((float)(v + 1));
    incl[t] = v;
    __syncthreads();
    for (int ofs = 1; ofs < 256; ofs <<= 1) {
      int u = (t >= ofs) ? incl[t - ofs] : 0;
      __syncthreads();
      incl[t] += u;
      __syncthreads();
    }
    toff[t + 1] = incl[t];
    if (t == 0) toff[0] = 0;
    pos[t] = incl[t] - v;
    __syncthreads();
    for (int e = t; e < ET; e += 256) {
      int d = tdst[e];
      int p = atomicAdd(&pos[d], 1);
      tlist[p] = tsrc[e];
    }
  }
}

__global__ void hg_clu_scatter(const int* __restrict__ lab, const int* __restrict__ coff,
                               int* __restrict__ cur, int* __restrict__ list) {
  int i = blockIdx.x * 256 + threadIdx.x;
  if (i < N) {
    int c = lab[i];
    int p = atomicAdd(&cur[c], 1);
    list[coff[c] + p] = i;
  }
}

// ---------------- weight transposes: dst[c*dld + r] = src[r*SC + c] ----------------
struct TJob { const float* src; float* dst; int SR; int SC; int dld; };
struct TArgs { TJob j[10]; };

__global__ __launch_bounds__(256) void hg_transpose(TArgs a) {
  TJob jb = a.j[blockIdx.y];
  int total = jb.SR * jb.SC;
  for (int idx = blockIdx.x * 256 + threadIdx.x; idx < total; idx += gridDim.x * 256) {
    int r = idx / jb.SC, c = idx - r * jb.SC;
    jb.dst[(size_t)c * jb.dld + r] = jb.src[idx];
  }
}

// ---------------- composite weight precompute ----------------
__global__ __launch_bounds__(256) void hg_pc0(const float* __restrict__ gatW1, const float* __restrict__ Wcp,
                                              const float* __restrict__ bcp, float* __restrict__ Wcompt,
                                              float* __restrict__ bcomp) {
  int j = blockIdx.x, k = threadIdx.x;
  float a = 0.f;
#pragma unroll 4
  for (int m = 0; m < 128; ++m) a = fmaf(gatW1[j * 128 + m], Wcp[m * 256 + k], a);
  Wcompt[k * 128 + j] = a;
  if (k == 0) {
    float b = 0.f;
    for (int m = 0; m < 128; ++m) b = fmaf(gatW1[j * 128 + m], bcp[m], b);
    bcomp[j] = b;
  }
}

__global__ __launch_bounds__(128) void hg_pc1(const float* __restrict__ tdWo, const float* __restrict__ tdWv,
                                              const float* __restrict__ tdbv, const float* __restrict__ tdbo,
                                              float* __restrict__ A_td, float* __restrict__ Wcat_t,
                                              float* __restrict__ bcat) {
  int j = blockIdx.x, k = threadIdx.x;
  float a = 0.f;
#pragma unroll 4
  for (int p = 0; p < 128; ++p) a = fmaf(tdWo[j * 128 + p], tdWv[p * 128 + k], a);
  A_td[j * 128 + k] = a;
  Wcat_t[k * 896 + j] = a;
  if (k == 0) {
    float b = 0.f;
    for (int p = 0; p < 128; ++p) b = fmaf(tdWo[j * 128 + p], tdbv[p], b);
    bcat[j] = b + tdbo[j];
  }
}

__global__ __launch_bounds__(128) void hg_pc2(const float* __restrict__ Wih, const float* __restrict__ bih,
                                              const float* __restrict__ Whh, const float* __restrict__ bhh,
                                              const float* __restrict__ A_td, float* __restrict__ Wcat_t,
                                              float* __restrict__ bcat) {
  int jj = blockIdx.x, k = threadIdx.x;
  const float* coef;
  float extra, bb;
  int dcol;
  int j;
  if (jj < 384) {
    j = jj; coef = Wih + (size_t)j * 256; extra = Wih[(size_t)j * 256 + 128 + k]; dcol = 128 + j; bb = bih[j];
  } else {
    j = jj - 384; coef = Whh + (size_t)j * 128; extra = 0.f; dcol = 512 + j; bb = bhh[j];
  }
  float a = 0.f;
#pragma unroll 4
  for (int m = 0; m < 128; ++m) a = fmaf(coef[m], A_td[m * 128 + k], a);
  Wcat_t[k * 896 + dcol] = a + extra;
  if (k == 0) {
    float b = 0.f;
    for (int m = 0; m < 128; ++m) b = fmaf(coef[m], bcat[m], b);
    bcat[dcol] = b + bb;
  }
}

// ---------------- tissue init: per-cluster mean + projection ----------------
__global__ __launch_bounds__(256) void hg_tissue_init(const float* __restrict__ feat, const int* __restrict__ list,
                                                      const int* __restrict__ coff, const float* __restrict__ Wtpt,
                                                      const float* __restrict__ btp, float* __restrict__ tish) {
  int c = blockIdx.x, t = threadIdx.x;
  __shared__ float mrow[256];
  int s0 = coff[c], n = coff[c + 1] - s0;
  float acc = 0.f;
#pragma unroll 4
  for (int i = 0; i < n; ++i) acc += feat[(size_t)list[s0 + i] * F + t];
  mrow[t] = acc / fmaxf((float)n, 1.f);
  __syncthreads();
  if (t < 128) {
    float a = btp[t];
#pragma unroll 4
    for (int k = 0; k < 256; ++k) a = fmaf(mrow[k], Wtpt[k * 128 + t], a);
    tish[c * 128 + t] = a;
  }
}

// ---------------- 128x128-tile fp32 GEMM, 8x8 micro-tile ----------------
// out[m][j] = sum_k A[m][k] * Wt[k][yt*128 + j] + bias
// EPI: 0 = plain store; 1 = store + GAT coef epilogue (e0=avs, e1=avd -> o0,o1)
//      2 = KV: yt==0 -> satt epilogue (e0=q, lab), no store; yt==1 -> store V
template <int K, int EPI>
__global__ __launch_bounds__(256, 3) void hg_gemm128(
    const float* __restrict__ A, int M,
    const float* __restrict__ Wt, int ldw,
    const float* __restrict__ bias0, const float* __restrict__ bias1,
    float* __restrict__ outp,
    const float* __restrict__ e0, const float* __restrict__ e1,
    const int* __restrict__ lab,
    float* __restrict__ o0, float* __restrict__ o1) {
  __shared__ float Al[32][132];
  __shared__ float Wl[32][132];
  const int t = threadIdx.x;
  const int tx = t & 15, ty = t >> 4;
  const int yt = blockIdx.y;
  const int m0 = blockIdx.x * 128;
  const float* Wb = Wt + yt * 128;
  const float* bias = (yt == 0) ? bias0 : bias1;

  float acc[8][8];
#pragma unroll
  for (int r = 0; r < 8; ++r)
#pragma unroll
    for (int c = 0; c < 8; ++c) acc[r][c] = 0.f;

  const int arow = t & 127, akh = t >> 7;
  const int wkr = t >> 3, wc0 = (t & 7) * 4;
  const int agm = m0 + arow;

  for (int kc = 0; kc < K; kc += 32) {
    // stage A tile transposed to k-major
#pragma unroll
    for (int f = 0; f < 4; ++f) {
      int k_off = akh * 16 + f * 4;
      float4 a = make_float4(0.f, 0.f, 0.f, 0.f);
      if (agm < M) a = *(const float4*)&A[(size_t)agm * K + kc + k_off];
      Al[k_off][arow] = a.x;
      Al[k_off + 1][arow] = a.y;
      Al[k_off + 2][arow] = a.z;
      Al[k_off + 3][arow] = a.w;
    }
    // stage W tile (already k-major)
#pragma unroll
    for (int f = 0; f < 4; ++f) {
      *(float4*)&Wl[wkr][wc0 + f * 32] = *(const float4*)&Wb[(size_t)(kc + wkr) * ldw + wc0 + f * 32];
    }
    __syncthreads();
#pragma unroll 2
    for (int kk = 0; kk < 32; ++kk) {
      float4 a0 = *(const float4*)&Al[kk][ty * 4];
      float4 a1 = *(const float4*)&Al[kk][64 + ty * 4];
      float4 w0 = *(const float4*)&Wl[kk][tx * 4];
      float4 w1 = *(const float4*)&Wl[kk][64 + tx * 4];
      float ar[8] = {a0.x, a0.y, a0.z, a0.w, a1.x, a1.y, a1.z, a1.w};
      float wr[8] = {w0.x, w0.y, w0.z, w0.w, w1.x, w1.y, w1.z, w1.w};
#pragma unroll
      for (int r = 0; r < 8; ++r)
#pragma unroll
        for (int c = 0; c < 8; ++c) acc[r][c] = fmaf(ar[r], wr[c], acc[r][c]);
    }
    __syncthreads();
  }

  // bias
  {
    float bA[8];
#pragma unroll
    for (int c = 0; c < 4; ++c) {
      bA[c] = bias[tx * 4 + c];
      bA[4 + c] = bias[64 + tx * 4 + c];
    }
#pragma unroll
    for (int r = 0; r < 8; ++r)
#pragma unroll
      for (int c = 0; c < 8; ++c) acc[r][c] += bA[c];
  }

  const bool do_store = (EPI != 2) || (yt == 1);
  if (do_store) {
#pragma unroll
    for (int r = 0; r < 8; ++r) {
      int gm = m0 + ((r < 4) ? (ty * 4 + r) : (64 + ty * 4 + r - 4));
      if (gm < M) {
        float* op = outp + (size_t)gm * 128 + tx * 4;
        *(float4*)op        = make_float4(acc[r][0], acc[r][1], acc[r][2], acc[r][3]);
        *(float4*)(op + 64) = make_float4(acc[r][4], acc[r][5], acc[r][6], acc[r][7]);
      }
    }
  }

  if (EPI == 1) {
    float4 s0 = *(const float4*)&e0[tx * 4], s1 = *(const float4*)&e0[64 + tx * 4];
    float4 d0 = *(const float4*)&e1[tx * 4], d1 = *(const float4*)&e1[64 + tx * 4];
#pragma unroll
    for (int r = 0; r < 8; ++r) {
      int gm = m0 + ((r < 4) ? (ty * 4 + r) : (64 + ty * 4 + r - 4));
      float psA = acc[r][0] * s0.x + acc[r][1] * s0.y + acc[r][2] * s0.z + acc[r][3] * s0.w;
      float psB = acc[r][4] * s1.x + acc[r][5] * s1.y + acc[r][6] * s1.z + acc[r][7] * s1.w;
      float pdA = acc[r][0] * d0.x + acc[r][1] * d0.y + acc[r][2] * d0.z + acc[r][3] * d0.w;
      float pdB = acc[r][4] * d1.x + acc[r][5] * d1.y + acc[r][6] * d1.z + acc[r][7] * d1.w;
      psA += __shfl_xor(psA, 1); psA += __shfl_xor(psA, 2);
      psB += __shfl_xor(psB, 1); psB += __shfl_xor(psB, 2);
      pdA += __shfl_xor(pdA, 1); pdA += __shfl_xor(pdA, 2);
      pdB += __shfl_xor(pdB, 1); pdB += __shfl_xor(pdB, 2);
      if ((tx & 3) == 0 && gm < M) {
        int h = tx >> 2;
        o0[(size_t)gm * 8 + h] = psA;
        o0[(size_t)gm * 8 + 4 + h] = psB;
        o1[(size_t)gm * 8 + h] = pdA;
        o1[(size_t)gm * 8 + 4 + h] = pdB;
      }
    }
  }
  if (EPI == 2 && yt == 0) {
#pragma unroll
    for (int r = 0; r < 8; ++r) {
      int gm = m0 + ((r < 4) ? (ty * 4 + r) : (64 + ty * 4 + r - 4));
      int lr = (gm < M) ? lab[gm] : 0;
      float4 q0 = *(const float4*)&e0[(size_t)lr * 128 + tx * 4];
      float4 q1 = *(const float4*)&e0[(size_t)lr * 128 + 64 + tx * 4];
      float psA = acc[r][0] * q0.x + acc[r][1] * q0.y + acc[r][2] * q0.z + acc[r][3] * q0.w;
      float psB = acc[r][4] * q1.x + acc[r][5] * q1.y + acc[r][6] * q1.z + acc[r][7] * q1.w;
      psA += __shfl_xor(psA, 1); psA += __shfl_xor(psA, 2);
      psB += __shfl_xor(psB, 1); psB += __shfl_xor(psB, 2);
      if ((tx & 3) == 0 && gm < M) {
        int h = tx >> 2;
        o0[(size_t)gm * 8 + h] = psA;
        o0[(size_t)gm * 8 + 4 + h] = psB;
      }
    }
  }
}

// ---------------- GAT aggregation: one WAVE per dst node ----------------
#define GMAXE 64
__global__ __launch_bounds__(256) void hg_gat_agg(const float* __restrict__ hproj, const float* __restrict__ a_s,
                                                  const float* __restrict__ a_d, const int* __restrict__ remap,
                                                  const int* __restrict__ off, const int* __restrict__ csr,
                                                  const float* __restrict__ bias, float* __restrict__ outh,
                                                  int nNodes) {
  const int wid = threadIdx.x >> 6;
  const int l = threadIdx.x & 63;
  const int node = blockIdx.x * 4 + wid;
  __shared__ int srcs_s[4][GMAXE];
  __shared__ float w_s[4][GMAXE][8];
  if (node >= nNodes) return;
  int* srcs = srcs_s[wid];
  float (*wls)[8] = w_s[wid];
  const int o0 = off[node], deg = off[node + 1] - o0;
  const int dl = remap ? remap[node] : node;
  const int hsc = l & 7;   // score-space head
  const int hf  = l >> 3;  // accumulate-space head (features 2l, 2l+1)
  const float adh = a_d[dl * 8 + hsc];
  const float ash = a_s[dl * 8 + hsc];
  float msc = -INFINITY, zsc = 0.f;
  float2 acc = make_float2(0.f, 0.f);
  const float2* hp2 = (const float2*)hproj;

  for (int cb = 0; cb < deg; cb += GMAXE) {
    const int len = min(GMAXE, deg - cb);
    if (l < len) {
      int s = csr[o0 + cb + l];
      srcs[l] = remap ? remap[s] : s;
    }
    asm volatile("s_waitcnt lgkmcnt(0)" ::: "memory");
    float lm = -INFINITY;
    for (int base = 0; base < len; base += 8) {
      int e = base + (l >> 3);
      if (e < len) {
        float sc = a_s[srcs[e] * 8 + hsc] + adh;
        sc = sc > 0.f ? sc : 0.2f * sc;
        wls[e][hsc] = sc;
        lm = fmaxf(lm, sc);
      }
    }
    lm = fmaxf(lm, __shfl_xor(lm, 8));
    lm = fmaxf(lm, __shfl_xor(lm, 16));
    lm = fmaxf(lm, __shfl_xor(lm, 32));
    float mnew = fmaxf(msc, lm);
    float rs = __expf(msc - mnew);
    float zc = 0.f;
    for (int base = 0; base < len; base += 8) {
      int e = base + (l >> 3);
      if (e < len) {
        float wv = __expf(wls[e][hsc] - mnew);
        wls[e][hsc] = wv;
        zc += wv;
      }
    }
    asm volatile("s_waitcnt lgkmcnt(0)" ::: "memory");
    zc += __shfl_xor(zc, 8); zc += __shfl_xor(zc, 16); zc += __shfl_xor(zc, 32);
    zsc = zsc * rs + zc;
    msc = mnew;
    float rsa = __shfl(rs, hf * 9);
    acc.x *= rsa; acc.y *= rsa;
#pragma unroll 4
    for (int e = 0; e < len; ++e) {
      float wv = wls[e][hf];
      float2 hv = hp2[(size_t)srcs[e] * 64 + l];
      acc.x = fmaf(wv, hv.x, acc.x);
      acc.y = fmaf(wv, hv.y, acc.y);
    }
  }
  float ssl = ash + adh;
  ssl = ssl > 0.f ? ssl : 0.2f * ssl;
  float mnew = fmaxf(msc, ssl);
  float rs = __expf(msc - mnew);
  float wsl = __expf(ssl - mnew);
  zsc = zsc * rs + wsl;
  float rsa = __shfl(rs, hf * 9);
  float wsa = __shfl(wsl, hf * 9);
  float2 hv = hp2[(size_t)dl * 64 + l];
  acc.x = acc.x * rsa + wsa * hv.x;
  acc.y = acc.y * rsa + wsa * hv.y;
  float zh = __shfl(zsc, hf * 9);
  float2 bv = *(const float2*)&bias[l * 2];
  float ox = acc.x / zh + bv.x;
  float oy = acc.y / zh + bv.y;
  ox = ox > 0.f ? ox : expm1f(ox);
  oy = oy > 0.f ? oy : expm1f(oy);
  ((float2*)outh)[(size_t)node * 64 + l] = make_float2(ox, oy);
}

// ---------------- tissue GCN (agg-then-project) + q projection ----------------
__global__ __launch_bounds__(128) void hg_gcn_q(const float* __restrict__ tin, const int* __restrict__ toff,
                                                const int* __restrict__ tlist, const float* __restrict__ dinv,
                                                const float* __restrict__ gt, const float* __restrict__ gcnb,
                                                const float* __restrict__ Wqt, const float* __restrict__ bq,
                                                float* __restrict__ q) {
  int c = blockIdx.x, t = threadIdx.x;
  __shared__ float xa[128], trow[128];
  float dc = dinv[c];
  float acc = tin[c * 128 + t] * dc * dc;
  int s0 = toff[c], s1 = toff[c + 1];
  for (int i = s0; i < s1; ++i) {
    int s = tlist[i];
    acc = fmaf(tin[s * 128 + t], dinv[s] * dc, acc);
  }
  xa[t] = acc;
  __syncthreads();
  float th = 0.f;
#pragma unroll 4
  for (int k = 0; k < 128; ++k) th = fmaf(xa[k], gt[k * 128 + t], th);
  float vv = fmaxf(th + gcnb[t], 0.f);
  trow[t] = vv;
  __syncthreads();
  float qa = bq[t];
#pragma unroll 4
  for (int k = 0; k < 128; ++k) qa = fmaf(trow[k], Wqt[k * 128 + t], qa);
  q[c * 128 + t] = qa * 0.25f;  // 1/sqrt(DH)
}

// ---------------- fused: per-cluster softmax+context, Wo, td+GRU, gates, next GAT proj ----------------
__global__ __launch_bounds__(256) void hg_bu_chain(
    const float* __restrict__ s_att, const float* __restrict__ v,
    const int* __restrict__ list, const int* __restrict__ coff,
    const float* __restrict__ Wot, const float* __restrict__ bo,
    const float* __restrict__ Wcat_t, const float* __restrict__ bcat,
    const float* __restrict__ gatWt, const float* __restrict__ avs, const float* __restrict__ avd,
    float* __restrict__ tish, float* __restrict__ ccell,
    float* __restrict__ hprojc, float* __restrict__ a_s2, float* __restrict__ a_d2) {
  int c = blockIdx.x, t = threadIdx.x;
  int s0 = coff[c], n = coff[c + 1] - s0;
  int tf = t & 127, half = t >> 7;
  __shared__ float red[32][8];
  __shared__ float mh[8];
  __shared__ float accs[128];
  __shared__ float zsh[16];
  __shared__ float b0[128], b1[128], part[2][128], catv[896];
  // --- softmax max per head ---
  int g = t >> 3, h8 = t & 7;
  float lm = -INFINITY;
  for (int i = g; i < n; i += 32) lm = fmaxf(lm, s_att[(size_t)list[s0 + i] * 8 + h8]);
  red[g][h8] = lm;
  __syncthreads();
  if (t < 8) {
    float m2 = -INFINITY;
#pragma unroll
    for (int i = 0; i < 32; ++i) m2 = fmaxf(m2, red[i][t]);
    mh[t] = m2;
  }
  __syncthreads();
  // --- weighted context (2-way cell split) ---
  int h = tf >> 4;
  float m = mh[h], z = 0.f, acc = 0.f;
#pragma unroll 2
  for (int i = half; i < n; i += 2) {
    int cell = list[s0 + i];
    float w = __expf(s_att[(size_t)cell * 8 + h] - m);
    acc = fmaf(w, v[(size_t)cell * 128 + tf], acc);
    z += w;
  }
  if (half) accs[tf] = acc;
  if ((tf & 15) == 0) zsh[half * 8 + h] = z;
  __syncthreads();
  if (!half) {
    float at = acc + accs[tf];
    float zt = zsh[h] + zsh[8 + h];
    b0[tf] = (n > 0) ? at / zt : 0.f;
  }
  __syncthreads();
  // --- stage 1: tissue_h = ctx @ Wo^T + bo (2-way k-split) ---
  int ks = t >> 7;
  {
    float ps = 0.f;
    const float* wp = Wot + (size_t)ks * 64 * 128 + tf;
#pragma unroll 4
    for (int k = 0; k < 64; ++k) ps = fmaf(b0[ks * 64 + k], wp[k * 128], ps);
    part[ks][tf] = ps;
  }
  __syncthreads();
  if (t < 128) {
    float vv = part[0][t] + part[1][t] + bo[t];
    b1[t] = vv;
    tish[c * 128 + t] = vv;
  }
  __syncthreads();
  // --- stage 2: catv = b1 @ Wcat + bcat ---
  for (int j = t; j < 896; j += 256) {
    float a = bcat[j];
#pragma unroll 4
    for (int k = 0; k < 128; ++k) a = fmaf(b1[k], Wcat_t[k * 896 + j], a);
    catv[j] = a;
  }
  __syncthreads();
  // --- stage 3: GRU gates ---
  if (t < 128) {
    float td = catv[t];
    float r = 1.f / (1.f + expf(-(catv[128 + t] + catv[512 + t])));
    float zz = 1.f / (1.f + expf(-(catv[256 + t] + catv[640 + t])));
    float nn = tanhf(catv[384 + t] + r * catv[768 + t]);
    float cn = (1.f - zz) * nn + zz * td;
    ccell[c * 128 + t] = cn;
    b0[t] = cn;
  }
  __syncthreads();
  // --- stage 4: next-layer GAT projection + coefs ---
  if (gatWt) {
    float ps = 0.f;
    const float* wp = gatWt + (size_t)ks * 64 * 128 + tf;
#pragma unroll 4
    for (int k = 0; k < 64; ++k) ps = fmaf(b0[ks * 64 + k], wp[k * 128], ps);
    part[ks][tf] = ps;
    __syncthreads();
    if (t < 128) {
      float hp = part[0][t] + part[1][t];
      hprojc[c * 128 + t] = hp;
      float pss = hp * avs[t], pdd = hp * avd[t];
      pss += __shfl_xor(pss, 1); pss += __shfl_xor(pss, 2); pss += __shfl_xor(pss, 4); pss += __shfl_xor(pss, 8);
      pdd += __shfl_xor(pdd, 1); pdd += __shfl_xor(pdd, 2); pdd += __shfl_xor(pdd, 4); pdd += __shfl_xor(pdd, 8);
      if ((t & 15) == 0) {
        a_s2[c * 8 + (t >> 4)] = pss;
        a_d2[c * 8 + (t >> 4)] = pdd;
      }
    }
  }
}

// ---------------- readout + classifier ----------------
__global__ __launch_bounds__(256) void hg_readout(const float* __restrict__ ccell2, const float* __restrict__ tish,
                                                  const int* __restrict__ cnt, const float* __restrict__ Wc1t,
                                                  const float* __restrict__ bc1, const float* __restrict__ Wc2t,
                                                  const float* __restrict__ bc2, const float* __restrict__ Wc3,
                                                  const float* __restrict__ bc3, float* __restrict__ outp) {
  __shared__ float emb[512], h1s[256], h2s[128];
  int t = threadIdx.x;
  if (t < 128) {
    float sm = 0.f, mx = -INFINITY;
    for (int c = 0; c < C; ++c) {
      float vv = ccell2[c * 128 + t];
      int n = cnt[c];
      sm += (float)n * vv;
      if (n > 0) mx = fmaxf(mx, vv);
    }
    emb[t] = sm / (float)N;
    emb[128 + t] = mx;
  } else {
    int tt = t - 128;
    float sm = 0.f, mx = -INFINITY;
    for (int c = 0; c < C; ++c) {
      float vv = tish[c * 128 + tt];
      sm += vv;
      mx = fmaxf(mx, vv);
    }
    emb[256 + tt] = sm * (1.f / (float)C);
    emb[384 + tt] = mx;
  }
  __syncthreads();
  float a = bc1[t];
#pragma unroll 4
  for (int kk = 0; kk < 512; ++kk) a = fmaf(emb[kk], Wc1t[kk * 256 + t], a);
  h1s[t] = fmaxf(a, 0.f);
  __syncthreads();
  if (t < 128) {
    float a2 = bc2[t];
#pragma unroll 4
    for (int kk = 0; kk < 256; ++kk) a2 = fmaf(h1s[kk], Wc2t[kk * 128 + t], a2);
    h2s[t] = fmaxf(a2, 0.f);
  }
  __syncthreads();
  if (t < 4) {
    float o = bc3[t];
    for (int kk = 0; kk < 128; ++kk) o = fmaf(h2s[kk], Wc3[t * 128 + kk], o);
    outp[t] = o;
  }
}

// ---------------- host launcher ----------------
extern "C" void kernel_launch(void* const* d_in, const int* in_sizes, int n_in,
                              void* d_out, int out_size, void* d_ws, size_t ws_size,
                              hipStream_t stream) {
  (void)in_sizes; (void)n_in; (void)out_size; (void)ws_size;
  const float* feat  = (const float*)d_in[0];
  const int*   eidx  = (const int*)d_in[1];
  const int*   lab   = (const int*)d_in[2];
  const int*   tidx  = (const int*)d_in[3];
  const float* Wcp   = (const float*)d_in[4];
  const float* bcp   = (const float*)d_in[5];
  const float* Wtp   = (const float*)d_in[6];
  const float* btp   = (const float*)d_in[7];
  const float* gatW  = (const float*)d_in[8];
  const float* gasrc = (const float*)d_in[9];
  const float* gadst = (const float*)d_in[10];
  const float* gatb  = (const float*)d_in[11];
  const float* gcnW  = (const float*)d_in[12];
  const float* gcnb  = (const float*)d_in[13];
  const float* buWq  = (const float*)d_in[14];
  const float* buWk  = (const float*)d_in[15];
  const float* buWv  = (const float*)d_in[16];
  const float* bubq  = (const float*)d_in[17];
  const float* bubk  = (const float*)d_in[18];
  const float* bubv  = (const float*)d_in[19];
  const float* buWo  = (const float*)d_in[20];
  const float* bubo  = (const float*)d_in[21];
  const float* tdWv  = (const float*)d_in[22];
  const float* tdbv  = (const float*)d_in[23];
  const float* tdWo  = (const float*)d_in[24];
  const float* tdbo  = (const float*)d_in[25];
  const float* Wih   = (const float*)d_in[26];
  const float* bih   = (const float*)d_in[27];
  const float* Whh   = (const float*)d_in[28];
  const float* bhh   = (const float*)d_in[29];
  const float* Wc1   = (const float*)d_in[30];
  const float* bc1   = (const float*)d_in[31];
  const float* Wc2   = (const float*)d_in[32];
  const float* bc2   = (const float*)d_in[33];
  const float* Wc3   = (const float*)d_in[34];
  const float* bc3   = (const float*)d_in[35];
  float* outp = (float*)d_out;

  const int* csrc = eidx;
  const int* cdst = eidx + E;
  const int* tsrc = tidx;
  const int* tdst = tidx + ET;

  char* w = (char*)d_ws;
  auto alloc = [&](size_t bytes) -> void* {
    void* p = (void*)w;
    w += (bytes + 255) & ~(size_t)255;
    return p;
  };
  char* cnt0 = w;
  int* deg_cell = (int*)alloc((size_t)N * 4);
  int* cur_cell = (int*)alloc((size_t)N * 4);
  int* clu_cnt  = (int*)alloc((size_t)C * 4);
  int* clu_cur  = (int*)alloc((size_t)C * 4);
  size_t cntBytes = (size_t)(w - cnt0);
  int* off_cell = (int*)alloc((size_t)(N + 1) * 4);
  int* csr      = (int*)alloc((size_t)E * 4);
  int* clu_off  = (int*)alloc((size_t)(C + 1) * 4);
  int* clu_list = (int*)alloc((size_t)N * 4);
  int* toff     = (int*)alloc((size_t)(C + 1) * 4);
  int* tlist    = (int*)alloc((size_t)ET * 4);
  float* dinv   = (float*)alloc((size_t)C * 4);
  float* buf1   = (float*)alloc((size_t)N * 128 * 4);
  float* buf2   = (float*)alloc((size_t)N * 128 * 4);
  float* a_s    = (float*)alloc((size_t)N * 8 * 4);
  float* a_d    = (float*)alloc((size_t)N * 8 * 4);
  float* s_att  = (float*)alloc((size_t)N * 8 * 4);
  float* tish   = (float*)alloc((size_t)C * 128 * 4);
  float* qb     = (float*)alloc((size_t)C * 128 * 4);
  float* ccell  = (float*)alloc((size_t)C * 128 * 4);
  float* hprojc = (float*)alloc((size_t)C * 128 * 4);
  float* a_sc   = (float*)alloc((size_t)C * 8 * 4);
  float* a_dc   = (float*)alloc((size_t)C * 8 * 4);
  float* A_td   = (float*)alloc(128 * 128 * 4);
  float* Wcat_t = (float*)alloc(128 * 896 * 4);
  float* bcat   = (float*)alloc(896 * 4);
  float* Wcompt = (float*)alloc(256 * 128 * 4);
  float* bcomp  = (float*)alloc(128 * 4);
  float* Wtpt   = (float*)alloc(256 * 128 * 4);
  float* g1t    = (float*)alloc(128 * 128 * 4);
  float* g2t    = (float*)alloc(128 * 128 * 4);
  float* Wqt    = (float*)alloc(128 * 128 * 4);
  float* Wkvt   = (float*)alloc(128 * 256 * 4);
  float* Wot    = (float*)alloc(128 * 128 * 4);
  float* gatW2t = (float*)alloc(128 * 128 * 4);
  float* Wc1t   = (float*)alloc(512 * 256 * 4);
  float* Wc2t   = (float*)alloc(256 * 128 * 4);

  hipMemsetAsync(cnt0, 0, cntBytes, stream);

  hg_hist<<<(E + 255) / 256, 256, 0, stream>>>(cdst, deg_cell, lab, clu_cnt);
  hg_scan_one<<<1, 1024, 0, stream>>>(deg_cell, off_cell, N);
  hg_cell_scatter<<<(E + 255) / 256, 256, 0, stream>>>(csrc, cdst, off_cell, cur_cell, csr);
  hg_setup256<<<2, 256, 0, stream>>>(clu_cnt, clu_off, tsrc, tdst, toff, tlist, dinv);
  hg_clu_scatter<<<(N + 255) / 256, 256, 0, stream>>>(lab, clu_off, clu_cur, clu_list);

  TArgs ta;
  ta.j[0] = {Wtp,            Wtpt,       128, 256, 128};
  ta.j[1] = {gcnW,           g1t,        128, 128, 128};
  ta.j[2] = {gcnW + 128*128, g2t,        128, 128, 128};
  ta.j[3] = {buWq,           Wqt,        128, 128, 128};
  ta.j[4] = {buWk,           Wkvt,       128, 128, 256};
  ta.j[5] = {buWv,           Wkvt + 128, 128, 128, 256};
  ta.j[6] = {buWo,           Wot,        128, 128, 128};
  ta.j[7] = {gatW + 128*128, gatW2t,     128, 128, 128};
  ta.j[8] = {Wc1,            Wc1t,       256, 512, 256};
  ta.j[9] = {Wc2,            Wc2t,       128, 256, 128};
  hg_transpose<<<dim3(32, 10), 256, 0, stream>>>(ta);

  hg_pc0<<<128, 256, 0, stream>>>(gatW, Wcp, bcp, Wcompt, bcomp);
  hg_pc1<<<128, 128, 0, stream>>>(tdWo, tdWv, tdbv, tdbo, A_td, Wcat_t, bcat);
  hg_pc2<<<768, 128, 0, stream>>>(Wih, bih, Whh, bhh, A_td, Wcat_t, bcat);

  hg_tissue_init<<<C, 256, 0, stream>>>(feat, clu_list, clu_off, Wtpt, btp, tish);

  const int RT = (N + 127) / 128;  // 469 row tiles
  // hproj_l1 = feat @ (gatW1*Wcp)^T + comp-bias, + GAT coef epilogue
  hg_gemm128<256, 1><<<dim3(RT, 1), 256, 0, stream>>>(feat, N, Wcompt, 128, bcomp, nullptr,
                                                      buf2, gasrc, gadst, nullptr, a_s, a_d);
  // ---- layer 1 ----
  hg_gat_agg<<<(N + 3) / 4, 256, 0, stream>>>(buf2, a_s, a_d, nullptr, off_cell, csr, gatb, buf1, N);
  hg_gcn_q<<<C, 128, 0, stream>>>(tish, toff, tlist, dinv, g1t, gcnb, Wqt, bubq, qb);
  hg_gemm128<128, 2><<<dim3(RT, 2), 256, 0, stream>>>(buf1, N, Wkvt, 256, bubk, bubv,
                                                      buf2, qb, nullptr, lab, s_att, nullptr);
  hg_bu_chain<<<C, 256, 0, stream>>>(s_att, buf2, clu_list, clu_off, Wot, bubo, Wcat_t, bcat,
                                     gatW2t, gasrc + 128, gadst + 128, tish, ccell, hprojc, a_sc, a_dc);
  // ---- layer 2 ----
  hg_gat_agg<<<(N + 3) / 4, 256, 0, stream>>>(hprojc, a_sc, a_dc, lab, off_cell, csr, gatb + 128, buf1, N);
  hg_gcn_q<<<C, 128, 0, stream>>>(tish, toff, tlist, dinv, g2t, gcnb + 128, Wqt, bubq, qb);
  hg_gemm128<128, 2><<<dim3(RT, 2), 256, 0, stream>>>(buf1, N, Wkvt, 256, bubk, bubv,
                                                      buf2, qb, nullptr, lab, s_att, nullptr);
  hg_bu_chain<<<C, 256, 0, stream>>>(s_att, buf2, clu_list, clu_off, Wot, bubo, Wcat_t, bcat,
                                     nullptr, nullptr, nullptr, tish, ccell, nullptr, nullptr, nullptr);

  hg_readout<<<1, 256, 0, stream>>>(ccell, tish, clu_cnt, Wc1t, bc1, Wc2t, bc2, Wc3, bc3, outp);
}

// Round 5
// 734.598 us; speedup vs baseline: 1.2978x; 1.1246x over previous
//
#include <hip/hip_runtime.h>
#include <math.h>

constexpr int N  = 60000;
constexpr int F  = 256;
constexpr int H  = 128;
constexpr int C  = 256;
constexpr int E  = 600000;
constexpr int ET = 1500;
constexpr int NB = (N + 1023) / 1024;  // 59 scan blocks

// ---------------- histograms (cell-dst degree + cluster counts) ----------------
__global__ void hg_hist(const int* __restrict__ cdst, int* __restrict__ deg,
                        const int* __restrict__ lab, int* __restrict__ ccnt) {
  int e = blockIdx.x * 256 + threadIdx.x;
  if (e < E) atomicAdd(&deg[cdst[e]], 1);
  if (e < N) atomicAdd(&ccnt[lab[e]], 1);
}

// ---------------- multi-block scan (3 kernels) ----------------
__global__ __launch_bounds__(256) void hg_scan1(const int* __restrict__ deg, int* __restrict__ off,
                                                int* __restrict__ btot, int n) {
  int b = blockIdx.x, t = threadIdx.x;
  int i0 = b * 1024 + t * 4;
  __shared__ int sums[256];
  int d0 = 0, d1 = 0, d2 = 0, d3 = 0;
  if (i0 + 3 < n) {
    int4 dd = *(const int4*)&deg[i0];
    d0 = dd.x; d1 = dd.y; d2 = dd.z; d3 = dd.w;
  } else {
    if (i0     < n) d0 = deg[i0];
    if (i0 + 1 < n) d1 = deg[i0 + 1];
    if (i0 + 2 < n) d2 = deg[i0 + 2];
    if (i0 + 3 < n) d3 = deg[i0 + 3];
  }
  int s = d0 + d1 + d2 + d3;
  sums[t] = s;
  __syncthreads();
  for (int ofs = 1; ofs < 256; ofs <<= 1) {
    int v = (t >= ofs) ? sums[t - ofs] : 0;
    __syncthreads();
    sums[t] += v;
    __syncthreads();
  }
  int excl = sums[t] - s;
  if (t == 255) btot[b] = sums[t];
  int run = excl;
  if (i0     < n) off[i0]     = run; run += d0;
  if (i0 + 1 < n) off[i0 + 1] = run; run += d1;
  if (i0 + 2 < n) off[i0 + 2] = run; run += d2;
  if (i0 + 3 < n) off[i0 + 3] = run;
}

__global__ void hg_scan2(int* __restrict__ btot, int* __restrict__ off) {
  __shared__ int s[64];
  int t = threadIdx.x;
  s[t] = (t < NB) ? btot[t] : 0;
  __syncthreads();
  if (t == 0) {
    int r = 0;
    for (int i = 0; i < NB; ++i) { int v = s[i]; s[i] = r; r += v; }
    off[N] = r;
  }
  __syncthreads();
  if (t < NB) btot[t] = s[t];
}

__global__ void hg_scan3(int* __restrict__ off, const int* __restrict__ btot, int n) {
  int b = blockIdx.x;
  int addv = btot[b];
  int i0 = b * 1024 + threadIdx.x * 4;
#pragma unroll
  for (int r = 0; r < 4; ++r)
    if (i0 + r < n) off[i0 + r] += addv;
}

__global__ void hg_cell_scatter(const int* __restrict__ csrc, const int* __restrict__ cdst,
                                const int* __restrict__ off, int* __restrict__ cur, int* __restrict__ csr) {
  int e = blockIdx.x * 256 + threadIdx.x;
  if (e < E) {
    int d = cdst[e];
    int p = atomicAdd(&cur[d], 1);
    csr[off[d] + p] = csrc[e];
  }
}

// block 0: cluster count scan; block 1: tissue CSR + dinv
__global__ __launch_bounds__(256) void hg_setup256(const int* __restrict__ cnt, int* __restrict__ coff,
                                                   const int* __restrict__ tsrc, const int* __restrict__ tdst,
                                                   int* __restrict__ toff, int* __restrict__ tlist,
                                                   float* __restrict__ dinv) {
  int t = threadIdx.x;
  if (blockIdx.x == 0) {
    __shared__ int s[256];
    int v0 = cnt[t];
    s[t] = v0;
    __syncthreads();
    for (int ofs = 1; ofs < 256; ofs <<= 1) {
      int v = (t >= ofs) ? s[t - ofs] : 0;
      __syncthreads();
      s[t] += v;
      __syncthreads();
    }
    coff[t + 1] = s[t];
    if (t == 0) coff[0] = 0;
  } else {
    __shared__ int hst[256], incl[256], pos[256];
    hst[t] = 0;
    __syncthreads();
    for (int e = t; e < ET; e += 256) atomicAdd(&hst[tdst[e]], 1);
    __syncthreads();
    int v = hst[t];
    dinv[t] = rsqrtf((float)(v + 1));
    incl[t] = v;
    __syncthreads();
    for (int ofs = 1; ofs < 256; ofs <<= 1) {
      int u = (t >= ofs) ? incl[t - ofs] : 0;
      __syncthreads();
      incl[t] += u;
      __syncthreads();
    }
    toff[t + 1] = incl[t];
    if (t == 0) toff[0] = 0;
    pos[t] = incl[t] - v;
    __syncthreads();
    for (int e = t; e < ET; e += 256) {
      int d = tdst[e];
      int p = atomicAdd(&pos[d], 1);
      tlist[p] = tsrc[e];
    }
  }
}

__global__ void hg_clu_scatter(const int* __restrict__ lab, const int* __restrict__ coff,
                               int* __restrict__ cur, int* __restrict__ list) {
  int i = blockIdx.x * 256 + threadIdx.x;
  if (i < N) {
    int c = lab[i];
    int p = atomicAdd(&cur[c], 1);
    list[coff[c] + p] = i;
  }
}

// ---------------- weight transposes: dst[c*dld + r] = src[r*SC + c] ----------------
struct TJob { const float* src; float* dst; int SR; int SC; int dld; };
struct TArgs { TJob j[8]; };

__global__ __launch_bounds__(256) void hg_transpose(TArgs a) {
  TJob jb = a.j[blockIdx.y];
  int total = jb.SR * jb.SC;
  for (int idx = blockIdx.x * 256 + threadIdx.x; idx < total; idx += gridDim.x * 256) {
    int r = idx / jb.SC, c = idx - r * jb.SC;
    jb.dst[(size_t)c * jb.dld + r] = jb.src[idx];
  }
}

// ---------------- composite weight precompute ----------------
__global__ __launch_bounds__(256) void hg_pc0(const float* __restrict__ gatW1, const float* __restrict__ Wcp,
                                              const float* __restrict__ bcp, float* __restrict__ Wcompt,
                                              float* __restrict__ bcomp) {
  int j = blockIdx.x, k = threadIdx.x;
  float a = 0.f;
#pragma unroll 4
  for (int m = 0; m < 128; ++m) a = fmaf(gatW1[j * 128 + m], Wcp[m * 256 + k], a);
  Wcompt[k * 128 + j] = a;
  if (k == 0) {
    float b = 0.f;
    for (int m = 0; m < 128; ++m) b = fmaf(gatW1[j * 128 + m], bcp[m], b);
    bcomp[j] = b;
  }
}

__global__ __launch_bounds__(128) void hg_pc1(const float* __restrict__ tdWo, const float* __restrict__ tdWv,
                                              const float* __restrict__ tdbv, const float* __restrict__ tdbo,
                                              float* __restrict__ A_td, float* __restrict__ Wcat_t,
                                              float* __restrict__ bcat) {
  int j = blockIdx.x, k = threadIdx.x;
  float a = 0.f;
#pragma unroll 4
  for (int p = 0; p < 128; ++p) a = fmaf(tdWo[j * 128 + p], tdWv[p * 128 + k], a);
  A_td[j * 128 + k] = a;
  Wcat_t[k * 896 + j] = a;
  if (k == 0) {
    float b = 0.f;
    for (int p = 0; p < 128; ++p) b = fmaf(tdWo[j * 128 + p], tdbv[p], b);
    bcat[j] = b + tdbo[j];
  }
}

__global__ __launch_bounds__(128) void hg_pc2(const float* __restrict__ Wih, const float* __restrict__ bih,
                                              const float* __restrict__ Whh, const float* __restrict__ bhh,
                                              const float* __restrict__ A_td, float* __restrict__ Wcat_t,
                                              float* __restrict__ bcat) {
  int jj = blockIdx.x, k = threadIdx.x;
  const float* coef;
  float extra, bb;
  int dcol;
  int j;
  if (jj < 384) {
    j = jj; coef = Wih + (size_t)j * 256; extra = Wih[(size_t)j * 256 + 128 + k]; dcol = 128 + j; bb = bih[j];
  } else {
    j = jj - 384; coef = Whh + (size_t)j * 128; extra = 0.f; dcol = 512 + j; bb = bhh[j];
  }
  float a = 0.f;
#pragma unroll 4
  for (int m = 0; m < 128; ++m) a = fmaf(coef[m], A_td[m * 128 + k], a);
  Wcat_t[k * 896 + dcol] = a + extra;
  if (k == 0) {
    float b = 0.f;
    for (int m = 0; m < 128; ++m) b = fmaf(coef[m], bcat[m], b);
    bcat[dcol] = b + bb;
  }
}

// ---------------- tissue init: per-cluster mean + projection ----------------
__global__ __launch_bounds__(256) void hg_tissue_init(const float* __restrict__ feat, const int* __restrict__ list,
                                                      const int* __restrict__ coff, const float* __restrict__ Wtpt,
                                                      const float* __restrict__ btp, float* __restrict__ tish) {
  int c = blockIdx.x, t = threadIdx.x;
  __shared__ float mrow[256];
  int s0 = coff[c], n = coff[c + 1] - s0;
  float acc = 0.f;
#pragma unroll 4
  for (int i = 0; i < n; ++i) acc += feat[(size_t)list[s0 + i] * F + t];
  mrow[t] = acc / fmaxf((float)n, 1.f);
  __syncthreads();
  if (t < 128) {
    float a = btp[t];
#pragma unroll 4
    for (int k = 0; k < 256; ++k) a = fmaf(mrow[k], Wtpt[k * 128 + t], a);
    tish[c * 128 + t] = a;
  }
}

// ---------------- 128x128-tile fp32 GEMM (K=256), 8x8 micro-tile, GAT-coef epilogue ----------------
__global__ __launch_bounds__(256, 3) void hg_gemm_coef(
    const float* __restrict__ A, int M,
    const float* __restrict__ Wt,
    const float* __restrict__ bias,
    float* __restrict__ outp,
    const float* __restrict__ avs, const float* __restrict__ avd,
    float* __restrict__ o_s, float* __restrict__ o_d) {
  __shared__ float Al[32][132];
  __shared__ float Wl[32][132];
  const int t = threadIdx.x;
  const int tx = t & 15, ty = t >> 4;
  const int m0 = blockIdx.x * 128;

  float acc[8][8];
#pragma unroll
  for (int r = 0; r < 8; ++r)
#pragma unroll
    for (int c = 0; c < 8; ++c) acc[r][c] = 0.f;

  const int arow = t & 127, akh = t >> 7;
  const int wkr = t >> 3, wc0 = (t & 7) * 4;
  const int agm = m0 + arow;

  for (int kc = 0; kc < 256; kc += 32) {
#pragma unroll
    for (int f = 0; f < 4; ++f) {
      int k_off = akh * 16 + f * 4;
      float4 a = make_float4(0.f, 0.f, 0.f, 0.f);
      if (agm < M) a = *(const float4*)&A[(size_t)agm * 256 + kc + k_off];
      Al[k_off][arow] = a.x;
      Al[k_off + 1][arow] = a.y;
      Al[k_off + 2][arow] = a.z;
      Al[k_off + 3][arow] = a.w;
    }
#pragma unroll
    for (int f = 0; f < 4; ++f) {
      *(float4*)&Wl[wkr][wc0 + f * 32] = *(const float4*)&Wt[(size_t)(kc + wkr) * 128 + wc0 + f * 32];
    }
    __syncthreads();
#pragma unroll 2
    for (int kk = 0; kk < 32; ++kk) {
      float4 a0 = *(const float4*)&Al[kk][ty * 4];
      float4 a1 = *(const float4*)&Al[kk][64 + ty * 4];
      float4 w0 = *(const float4*)&Wl[kk][tx * 4];
      float4 w1 = *(const float4*)&Wl[kk][64 + tx * 4];
      float ar[8] = {a0.x, a0.y, a0.z, a0.w, a1.x, a1.y, a1.z, a1.w};
      float wr[8] = {w0.x, w0.y, w0.z, w0.w, w1.x, w1.y, w1.z, w1.w};
#pragma unroll
      for (int r = 0; r < 8; ++r)
#pragma unroll
        for (int c = 0; c < 8; ++c) acc[r][c] = fmaf(ar[r], wr[c], acc[r][c]);
    }
    __syncthreads();
  }

  {
    float bA[8];
#pragma unroll
    for (int c = 0; c < 4; ++c) {
      bA[c] = bias[tx * 4 + c];
      bA[4 + c] = bias[64 + tx * 4 + c];
    }
#pragma unroll
    for (int r = 0; r < 8; ++r)
#pragma unroll
      for (int c = 0; c < 8; ++c) acc[r][c] += bA[c];
  }

#pragma unroll
  for (int r = 0; r < 8; ++r) {
    int gm = m0 + ((r < 4) ? (ty * 4 + r) : (64 + ty * 4 + r - 4));
    if (gm < M) {
      float* op = outp + (size_t)gm * 128 + tx * 4;
      *(float4*)op        = make_float4(acc[r][0], acc[r][1], acc[r][2], acc[r][3]);
      *(float4*)(op + 64) = make_float4(acc[r][4], acc[r][5], acc[r][6], acc[r][7]);
    }
  }

  {
    float4 s0 = *(const float4*)&avs[tx * 4], s1 = *(const float4*)&avs[64 + tx * 4];
    float4 d0 = *(const float4*)&avd[tx * 4], d1 = *(const float4*)&avd[64 + tx * 4];
#pragma unroll
    for (int r = 0; r < 8; ++r) {
      int gm = m0 + ((r < 4) ? (ty * 4 + r) : (64 + ty * 4 + r - 4));
      float psA = acc[r][0] * s0.x + acc[r][1] * s0.y + acc[r][2] * s0.z + acc[r][3] * s0.w;
      float psB = acc[r][4] * s1.x + acc[r][5] * s1.y + acc[r][6] * s1.z + acc[r][7] * s1.w;
      float pdA = acc[r][0] * d0.x + acc[r][1] * d0.y + acc[r][2] * d0.z + acc[r][3] * d0.w;
      float pdB = acc[r][4] * d1.x + acc[r][5] * d1.y + acc[r][6] * d1.z + acc[r][7] * d1.w;
      psA += __shfl_xor(psA, 1); psA += __shfl_xor(psA, 2);
      psB += __shfl_xor(psB, 1); psB += __shfl_xor(psB, 2);
      pdA += __shfl_xor(pdA, 1); pdA += __shfl_xor(pdA, 2);
      pdB += __shfl_xor(pdB, 1); pdB += __shfl_xor(pdB, 2);
      if ((tx & 3) == 0 && gm < M) {
        int h = tx >> 2;
        o_s[(size_t)gm * 8 + h] = psA;
        o_s[(size_t)gm * 8 + 4 + h] = psB;
        o_d[(size_t)gm * 8 + h] = pdA;
        o_d[(size_t)gm * 8 + 4 + h] = pdB;
      }
    }
  }
}

// ---------------- GAT aggregation: one WAVE per dst node, + s_att epilogue ----------------
#define GMAXE 64
__global__ __launch_bounds__(256) void hg_gat_agg(const float* __restrict__ hproj, const float* __restrict__ a_s,
                                                  const float* __restrict__ a_d, const int* __restrict__ remap,
                                                  const int* __restrict__ off, const int* __restrict__ csr,
                                                  const float* __restrict__ bias, float* __restrict__ outh,
                                                  const float* __restrict__ qk, const float* __restrict__ qb,
                                                  const int* __restrict__ lab,
                                                  float* __restrict__ satt, int nNodes) {
  const int wid = threadIdx.x >> 6;
  const int l = threadIdx.x & 63;
  const int node = blockIdx.x * 4 + wid;
  __shared__ int srcs_s[4][GMAXE];
  __shared__ float w_s[4][GMAXE][8];
  if (node >= nNodes) return;
  int* srcs = srcs_s[wid];
  float (*wls)[8] = w_s[wid];
  const int o0 = off[node], deg = off[node + 1] - o0;
  const int dl = remap ? remap[node] : node;
  const int cl = lab[node];
  const int hsc = l & 7;   // score-space head
  const int hf  = l >> 3;  // accumulate-space head (features 2l, 2l+1)
  const float adh = a_d[dl * 8 + hsc];
  const float ash = a_s[dl * 8 + hsc];
  float msc = -INFINITY, zsc = 0.f;
  float2 acc = make_float2(0.f, 0.f);
  const float2* hp2 = (const float2*)hproj;

  for (int cb = 0; cb < deg; cb += GMAXE) {
    const int len = min(GMAXE, deg - cb);
    if (l < len) {
      int s = csr[o0 + cb + l];
      srcs[l] = remap ? remap[s] : s;
    }
    asm volatile("s_waitcnt lgkmcnt(0)" ::: "memory");
    float lm = -INFINITY;
    for (int base = 0; base < len; base += 8) {
      int e = base + (l >> 3);
      if (e < len) {
        float sc = a_s[srcs[e] * 8 + hsc] + adh;
        sc = sc > 0.f ? sc : 0.2f * sc;
        wls[e][hsc] = sc;
        lm = fmaxf(lm, sc);
      }
    }
    lm = fmaxf(lm, __shfl_xor(lm, 8));
    lm = fmaxf(lm, __shfl_xor(lm, 16));
    lm = fmaxf(lm, __shfl_xor(lm, 32));
    float mnew = fmaxf(msc, lm);
    float rs = __expf(msc - mnew);
    float zc = 0.f;
    for (int base = 0; base < len; base += 8) {
      int e = base + (l >> 3);
      if (e < len) {
        float wv = __expf(wls[e][hsc] - mnew);
        wls[e][hsc] = wv;
        zc += wv;
      }
    }
    asm volatile("s_waitcnt lgkmcnt(0)" ::: "memory");
    zc += __shfl_xor(zc, 8); zc += __shfl_xor(zc, 16); zc += __shfl_xor(zc, 32);
    zsc = zsc * rs + zc;
    msc = mnew;
    float rsa = __shfl(rs, hf * 9);
    acc.x *= rsa; acc.y *= rsa;
#pragma unroll 4
    for (int e = 0; e < len; ++e) {
      float wv = wls[e][hf];
      float2 hv = hp2[(size_t)srcs[e] * 64 + l];
      acc.x = fmaf(wv, hv.x, acc.x);
      acc.y = fmaf(wv, hv.y, acc.y);
    }
  }
  float ssl = ash + adh;
  ssl = ssl > 0.f ? ssl : 0.2f * ssl;
  float mnew = fmaxf(msc, ssl);
  float rs = __expf(msc - mnew);
  float wsl = __expf(ssl - mnew);
  zsc = zsc * rs + wsl;
  float rsa = __shfl(rs, hf * 9);
  float wsa = __shfl(wsl, hf * 9);
  float2 hv = hp2[(size_t)dl * 64 + l];
  acc.x = acc.x * rsa + wsa * hv.x;
  acc.y = acc.y * rsa + wsa * hv.y;
  float zh = __shfl(zsc, hf * 9);
  float2 bv = *(const float2*)&bias[l * 2];
  float ox = acc.x / zh + bv.x;
  float oy = acc.y / zh + bv.y;
  ox = ox > 0.f ? ox : expm1f(ox);
  oy = oy > 0.f ? oy : expm1f(oy);
  ((float2*)outh)[(size_t)node * 64 + l] = make_float2(ox, oy);

  // s_att epilogue: s_att[node,h] = cell_h · qk[cl,h,:] + qb[cl,h]
  const float* qkc = qk + (size_t)cl * 8 * 128;
#pragma unroll
  for (int h = 0; h < 8; ++h) {
    float2 qv = *(const float2*)&qkc[h * 128 + 2 * l];
    float p = fmaf(oy, qv.y, ox * qv.x);
    p += __shfl_xor(p, 1); p += __shfl_xor(p, 2); p += __shfl_xor(p, 4);
    p += __shfl_xor(p, 8); p += __shfl_xor(p, 16); p += __shfl_xor(p, 32);
    if (l == h) satt[(size_t)node * 8 + h] = p + qb[cl * 8 + h];
  }
}

// ---------------- tissue GCN + q projection + qk/qb tables ----------------
__global__ __launch_bounds__(128) void hg_gcn_q(const float* __restrict__ tin, const int* __restrict__ toff,
                                                const int* __restrict__ tlist, const float* __restrict__ dinv,
                                                const float* __restrict__ gt, const float* __restrict__ gcnb,
                                                const float* __restrict__ Wqt, const float* __restrict__ bq,
                                                const float* __restrict__ Wk, const float* __restrict__ bk,
                                                float* __restrict__ qk, float* __restrict__ qb) {
  int c = blockIdx.x, t = threadIdx.x;
  __shared__ float xa[128], trow[128], qrow[128];
  float dc = dinv[c];
  float acc = tin[c * 128 + t] * dc * dc;
  int s0 = toff[c], s1 = toff[c + 1];
  for (int i = s0; i < s1; ++i) {
    int s = tlist[i];
    acc = fmaf(tin[s * 128 + t], dinv[s] * dc, acc);
  }
  xa[t] = acc;
  __syncthreads();
  float th = 0.f;
#pragma unroll 4
  for (int k = 0; k < 128; ++k) th = fmaf(xa[k], gt[k * 128 + t], th);
  float vv = fmaxf(th + gcnb[t], 0.f);
  trow[t] = vv;
  __syncthreads();
  float qa = bq[t];
#pragma unroll 4
  for (int k = 0; k < 128; ++k) qa = fmaf(trow[k], Wqt[k * 128 + t], qa);
  qrow[t] = qa * 0.25f;  // 1/sqrt(DH)
  __syncthreads();
  // qk[c,h,t] = sum_{j in head h} Wk[j,t] * qrow[j]
#pragma unroll
  for (int h = 0; h < 8; ++h) {
    float s = 0.f;
#pragma unroll
    for (int j = 0; j < 16; ++j) s = fmaf(Wk[(size_t)(h * 16 + j) * 128 + t], qrow[h * 16 + j], s);
    qk[((size_t)c * 8 + h) * 128 + t] = s;
  }
  if (t < 8) {
    float s = 0.f;
#pragma unroll
    for (int j = 0; j < 16; ++j) s = fmaf(qrow[t * 16 + j], bk[t * 16 + j], s);
    qb[c * 8 + t] = s;
  }
}

// ---------------- fused: per-cluster softmax head-means, Wv, Wo, td+GRU, gates, next GAT proj ----------------
__global__ __launch_bounds__(256) void hg_bu_chain(
    const float* __restrict__ s_att, const float* __restrict__ hcell,
    const int* __restrict__ list, const int* __restrict__ coff,
    const float* __restrict__ Wv, const float* __restrict__ bv,
    const float* __restrict__ Wot, const float* __restrict__ bo,
    const float* __restrict__ Wcat_t, const float* __restrict__ bcat,
    const float* __restrict__ gatWt, const float* __restrict__ avs, const float* __restrict__ avd,
    float* __restrict__ tish, float* __restrict__ ccell,
    float* __restrict__ hprojc, float* __restrict__ a_s2, float* __restrict__ a_d2) {
  int c = blockIdx.x, t = threadIdx.x;
  int s0 = coff[c], n = coff[c + 1] - s0;
  int tf = t & 127, half = t >> 7;
  __shared__ float red[32][8];
  __shared__ float mh[8], zh[8];
  __shared__ int cells[64];
  __shared__ float wl[64][8];
  __shared__ float msh[8][128];
  __shared__ float b0[128], b1[128], part[2][128], catv[896];
  // --- phase A: per-head max over cluster cells ---
  int g = t >> 3, h8 = t & 7;
  float lm = -INFINITY;
  for (int i = g; i < n; i += 32) lm = fmaxf(lm, s_att[(size_t)list[s0 + i] * 8 + h8]);
  red[g][h8] = lm;
  __syncthreads();
  if (t < 8) {
    float m2 = -INFINITY;
#pragma unroll
    for (int i = 0; i < 32; ++i) m2 = fmaxf(m2, red[i][t]);
    mh[t] = m2;
  }
  __syncthreads();
  // --- phase B: chunked weighted head-mean accumulation ---
  const float mloc = mh[t & 7];
  float zp = 0.f;
  float macc[8] = {0.f, 0.f, 0.f, 0.f, 0.f, 0.f, 0.f, 0.f};
  for (int cb = 0; cb < n; cb += 64) {
    int len = min(64, n - cb);
    if (t < len) cells[t] = list[s0 + cb + t];
    __syncthreads();
#pragma unroll
    for (int p = 0; p < 2; ++p) {
      int e = p * 32 + (t >> 3);
      if (e < len) {
        float w = __expf(s_att[(size_t)cells[e] * 8 + (t & 7)] - mloc);
        wl[e][t & 7] = w;
        zp += w;
      }
    }
    __syncthreads();
    for (int e = half; e < len; e += 2) {
      float x = hcell[(size_t)cells[e] * 128 + tf];
      float4 w0 = *(const float4*)&wl[e][0];
      float4 w1 = *(const float4*)&wl[e][4];
      macc[0] = fmaf(w0.x, x, macc[0]);
      macc[1] = fmaf(w0.y, x, macc[1]);
      macc[2] = fmaf(w0.z, x, macc[2]);
      macc[3] = fmaf(w0.w, x, macc[3]);
      macc[4] = fmaf(w1.x, x, macc[4]);
      macc[5] = fmaf(w1.y, x, macc[5]);
      macc[6] = fmaf(w1.z, x, macc[6]);
      macc[7] = fmaf(w1.w, x, macc[7]);
    }
    __syncthreads();
  }
  // z reduce
  red[t >> 3][t & 7] = zp;
  __syncthreads();
  if (t < 8) {
    float z = 0.f;
#pragma unroll
    for (int i = 0; i < 32; ++i) z += red[i][t];
    zh[t] = (n > 0) ? 1.f / z : 0.f;
  }
  if (half) {
#pragma unroll
    for (int h = 0; h < 8; ++h) msh[h][tf] = macc[h];
  }
  __syncthreads();
  if (!half) {
#pragma unroll
    for (int h = 0; h < 8; ++h) msh[h][tf] = (macc[h] + msh[h][tf]) * zh[h];
  }
  __syncthreads();
  // --- phase C: ctx[j] = Wv[j,:] · msh[j>>4,:] + bv[j]  (2-way k-split) ---
  {
    int h = tf >> 4;
    float ps = 0.f;
    const float* wp = Wv + (size_t)tf * 128 + half * 64;
    const float* mp = &msh[h][half * 64];
#pragma unroll 4
    for (int k = 0; k < 64; ++k) ps = fmaf(wp[k], mp[k], ps);
    part[half][tf] = ps;
  }
  __syncthreads();
  if (t < 128) b0[t] = part[0][t] + part[1][t] + bv[t];
  __syncthreads();
  // --- stage 1: tissue_h = ctx @ Wo^T + bo (2-way k-split) ---
  int ks = half;
  {
    float ps = 0.f;
    const float* wp = Wot + (size_t)ks * 64 * 128 + tf;
#pragma unroll 4
    for (int k = 0; k < 64; ++k) ps = fmaf(b0[ks * 64 + k], wp[k * 128], ps);
    part[ks][tf] = ps;
  }
  __syncthreads();
  if (t < 128) {
    float vv = part[0][t] + part[1][t] + bo[t];
    b1[t] = vv;
    tish[c * 128 + t] = vv;
  }
  __syncthreads();
  // --- stage 2: catv = b1 @ Wcat + bcat ---
  for (int j = t; j < 896; j += 256) {
    float a = bcat[j];
#pragma unroll 4
    for (int k = 0; k < 128; ++k) a = fmaf(b1[k], Wcat_t[k * 896 + j], a);
    catv[j] = a;
  }
  __syncthreads();
  // --- stage 3: GRU gates ---
  if (t < 128) {
    float td = catv[t];
    float r = 1.f / (1.f + expf(-(catv[128 + t] + catv[512 + t])));
    float zz = 1.f / (1.f + expf(-(catv[256 + t] + catv[640 + t])));
    float nn = tanhf(catv[384 + t] + r * catv[768 + t]);
    float cn = (1.f - zz) * nn + zz * td;
    ccell[c * 128 + t] = cn;
    b0[t] = cn;
  }
  __syncthreads();
  // --- stage 4: next-layer GAT projection + coefs ---
  if (gatWt) {
    float ps = 0.f;
    const float* wp = gatWt + (size_t)ks * 64 * 128 + tf;
#pragma unroll 4
    for (int k = 0; k < 64; ++k) ps = fmaf(b0[ks * 64 + k], wp[k * 128], ps);
    part[ks][tf] = ps;
    __syncthreads();
    if (t < 128) {
      float hp = part[0][t] + part[1][t];
      hprojc[c * 128 + t] = hp;
      float pss = hp * avs[t], pdd = hp * avd[t];
      pss += __shfl_xor(pss, 1); pss += __shfl_xor(pss, 2); pss += __shfl_xor(pss, 4); pss += __shfl_xor(pss, 8);
      pdd += __shfl_xor(pdd, 1); pdd += __shfl_xor(pdd, 2); pdd += __shfl_xor(pdd, 4); pdd += __shfl_xor(pdd, 8);
      if ((t & 15) == 0) {
        a_s2[c * 8 + (t >> 4)] = pss;
        a_d2[c * 8 + (t >> 4)] = pdd;
      }
    }
  }
}

// ---------------- readout + classifier ----------------
__global__ __launch_bounds__(256) void hg_readout(const float* __restrict__ ccell2, const float* __restrict__ tish,
                                                  const int* __restrict__ cnt, const float* __restrict__ Wc1t,
                                                  const float* __restrict__ bc1, const float* __restrict__ Wc2t,
                                                  const float* __restrict__ bc2, const float* __restrict__ Wc3,
                                                  const float* __restrict__ bc3, float* __restrict__ outp) {
  __shared__ float emb[512], h1s[256], h2s[128];
  int t = threadIdx.x;
  if (t < 128) {
    float sm = 0.f, mx = -INFINITY;
    for (int c = 0; c < C; ++c) {
      float vv = ccell2[c * 128 + t];
      int n = cnt[c];
      sm += (float)n * vv;
      if (n > 0) mx = fmaxf(mx, vv);
    }
    emb[t] = sm / (float)N;
    emb[128 + t] = mx;
  } else {
    int tt = t - 128;
    float sm = 0.f, mx = -INFINITY;
    for (int c = 0; c < C; ++c) {
      float vv = tish[c * 128 + tt];
      sm += vv;
      mx = fmaxf(mx, vv);
    }
    emb[256 + tt] = sm * (1.f / (float)C);
    emb[384 + tt] = mx;
  }
  __syncthreads();
  float a = bc1[t];
#pragma unroll 4
  for (int kk = 0; kk < 512; ++kk) a = fmaf(emb[kk], Wc1t[kk * 256 + t], a);
  h1s[t] = fmaxf(a, 0.f);
  __syncthreads();
  if (t < 128) {
    float a2 = bc2[t];
#pragma unroll 4
    for (int kk = 0; kk < 256; ++kk) a2 = fmaf(h1s[kk], Wc2t[kk * 128 + t], a2);
    h2s[t] = fmaxf(a2, 0.f);
  }
  __syncthreads();
  if (t < 4) {
    float o = bc3[t];
    for (int kk = 0; kk < 128; ++kk) o = fmaf(h2s[kk], Wc3[t * 128 + kk], o);
    outp[t] = o;
  }
}

// ---------------- host launcher ----------------
extern "C" void kernel_launch(void* const* d_in, const int* in_sizes, int n_in,
                              void* d_out, int out_size, void* d_ws, size_t ws_size,
                              hipStream_t stream) {
  (void)in_sizes; (void)n_in; (void)out_size; (void)ws_size;
  const float* feat  = (const float*)d_in[0];
  const int*   eidx  = (const int*)d_in[1];
  const int*   lab   = (const int*)d_in[2];
  const int*   tidx  = (const int*)d_in[3];
  const float* Wcp   = (const float*)d_in[4];
  const float* bcp   = (const float*)d_in[5];
  const float* Wtp   = (const float*)d_in[6];
  const float* btp   = (const float*)d_in[7];
  const float* gatW  = (const float*)d_in[8];
  const float* gasrc = (const float*)d_in[9];
  const float* gadst = (const float*)d_in[10];
  const float* gatb  = (const float*)d_in[11];
  const float* gcnW  = (const float*)d_in[12];
  const float* gcnb  = (const float*)d_in[13];
  const float* buWq  = (const float*)d_in[14];
  const float* buWk  = (const float*)d_in[15];
  const float* buWv  = (const float*)d_in[16];
  const float* bubq  = (const float*)d_in[17];
  const float* bubk  = (const float*)d_in[18];
  const float* bubv  = (const float*)d_in[19];
  const float* buWo  = (const float*)d_in[20];
  const float* bubo  = (const float*)d_in[21];
  const float* tdWv  = (const float*)d_in[22];
  const float* tdbv  = (const float*)d_in[23];
  const float* tdWo  = (const float*)d_in[24];
  const float* tdbo  = (const float*)d_in[25];
  const float* Wih   = (const float*)d_in[26];
  const float* bih   = (const float*)d_in[27];
  const float* Whh   = (const float*)d_in[28];
  const float* bhh   = (const float*)d_in[29];
  const float* Wc1   = (const float*)d_in[30];
  const float* bc1   = (const float*)d_in[31];
  const float* Wc2   = (const float*)d_in[32];
  const float* bc2   = (const float*)d_in[33];
  const float* Wc3   = (const float*)d_in[34];
  const float* bc3   = (const float*)d_in[35];
  float* outp = (float*)d_out;

  const int* csrc = eidx;
  const int* cdst = eidx + E;
  const int* tsrc = tidx;
  const int* tdst = tidx + ET;

  char* w = (char*)d_ws;
  auto alloc = [&](size_t bytes) -> void* {
    void* p = (void*)w;
    w += (bytes + 255) & ~(size_t)255;
    return p;
  };
  char* cnt0 = w;
  int* deg_cell = (int*)alloc((size_t)N * 4);
  int* cur_cell = (int*)alloc((size_t)N * 4);
  int* clu_cnt  = (int*)alloc((size_t)C * 4);
  int* clu_cur  = (int*)alloc((size_t)C * 4);
  size_t cntBytes = (size_t)(w - cnt0);
  int* off_cell = (int*)alloc((size_t)(N + 1) * 4);
  int* btot     = (int*)alloc(64 * 4);
  int* csr      = (int*)alloc((size_t)E * 4);
  int* clu_off  = (int*)alloc((size_t)(C + 1) * 4);
  int* clu_list = (int*)alloc((size_t)N * 4);
  int* toff     = (int*)alloc((size_t)(C + 1) * 4);
  int* tlist    = (int*)alloc((size_t)ET * 4);
  float* dinv   = (float*)alloc((size_t)C * 4);
  float* buf1   = (float*)alloc((size_t)N * 128 * 4);
  float* buf2   = (float*)alloc((size_t)N * 128 * 4);
  float* a_s    = (float*)alloc((size_t)N * 8 * 4);
  float* a_d    = (float*)alloc((size_t)N * 8 * 4);
  float* s_att  = (float*)alloc((size_t)N * 8 * 4);
  float* tish   = (float*)alloc((size_t)C * 128 * 4);
  float* qkb    = (float*)alloc((size_t)C * 8 * 128 * 4);
  float* qbb    = (float*)alloc((size_t)C * 8 * 4);
  float* ccell  = (float*)alloc((size_t)C * 128 * 4);
  float* hprojc = (float*)alloc((size_t)C * 128 * 4);
  float* a_sc   = (float*)alloc((size_t)C * 8 * 4);
  float* a_dc   = (float*)alloc((size_t)C * 8 * 4);
  float* A_td   = (float*)alloc(128 * 128 * 4);
  float* Wcat_t = (float*)alloc(128 * 896 * 4);
  float* bcat   = (float*)alloc(896 * 4);
  float* Wcompt = (float*)alloc(256 * 128 * 4);
  float* bcomp  = (float*)alloc(128 * 4);
  float* Wtpt   = (float*)alloc(256 * 128 * 4);
  float* g1t    = (float*)alloc(128 * 128 * 4);
  float* g2t    = (float*)alloc(128 * 128 * 4);
  float* Wqt    = (float*)alloc(128 * 128 * 4);
  float* Wot    = (float*)alloc(128 * 128 * 4);
  float* gatW2t = (float*)alloc(128 * 128 * 4);
  float* Wc1t   = (float*)alloc(512 * 256 * 4);
  float* Wc2t   = (float*)alloc(256 * 128 * 4);

  hipMemsetAsync(cnt0, 0, cntBytes, stream);

  hg_hist<<<(E + 255) / 256, 256, 0, stream>>>(cdst, deg_cell, lab, clu_cnt);
  hg_scan1<<<NB, 256, 0, stream>>>(deg_cell, off_cell, btot, N);
  hg_scan2<<<1, 64, 0, stream>>>(btot, off_cell);
  hg_scan3<<<NB, 256, 0, stream>>>(off_cell, btot, N);
  hg_cell_scatter<<<(E + 255) / 256, 256, 0, stream>>>(csrc, cdst, off_cell, cur_cell, csr);
  hg_setup256<<<2, 256, 0, stream>>>(clu_cnt, clu_off, tsrc, tdst, toff, tlist, dinv);
  hg_clu_scatter<<<(N + 255) / 256, 256, 0, stream>>>(lab, clu_off, clu_cur, clu_list);

  TArgs ta;
  ta.j[0] = {Wtp,            Wtpt,   128, 256, 128};
  ta.j[1] = {gcnW,           g1t,    128, 128, 128};
  ta.j[2] = {gcnW + 128*128, g2t,    128, 128, 128};
  ta.j[3] = {buWq,           Wqt,    128, 128, 128};
  ta.j[4] = {buWo,           Wot,    128, 128, 128};
  ta.j[5] = {gatW + 128*128, gatW2t, 128, 128, 128};
  ta.j[6] = {Wc1,            Wc1t,   256, 512, 256};
  ta.j[7] = {Wc2,            Wc2t,   128, 256, 128};
  hg_transpose<<<dim3(32, 8), 256, 0, stream>>>(ta);

  hg_pc0<<<128, 256, 0, stream>>>(gatW, Wcp, bcp, Wcompt, bcomp);
  hg_pc1<<<128, 128, 0, stream>>>(tdWo, tdWv, tdbv, tdbo, A_td, Wcat_t, bcat);
  hg_pc2<<<768, 128, 0, stream>>>(Wih, bih, Whh, bhh, A_td, Wcat_t, bcat);

  hg_tissue_init<<<C, 256, 0, stream>>>(feat, clu_list, clu_off, Wtpt, btp, tish);

  const int RT = (N + 127) / 128;  // 469 row tiles
  // hproj_l1 = feat @ (gatW1*Wcp)^T + comp-bias, + GAT coef epilogue
  hg_gemm_coef<<<RT, 256, 0, stream>>>(feat, N, Wcompt, bcomp, buf2, gasrc, gadst, a_s, a_d);
  // ---- layer 1 ----
  hg_gcn_q<<<C, 128, 0, stream>>>(tish, toff, tlist, dinv, g1t, gcnb, Wqt, bubq, buWk, bubk, qkb, qbb);
  hg_gat_agg<<<(N + 3) / 4, 256, 0, stream>>>(buf2, a_s, a_d, nullptr, off_cell, csr, gatb, buf1,
                                              qkb, qbb, lab, s_att, N);
  hg_bu_chain<<<C, 256, 0, stream>>>(s_att, buf1, clu_list, clu_off, buWv, bubv, Wot, bubo, Wcat_t, bcat,
                                     gatW2t, gasrc + 128, gadst + 128, tish, ccell, hprojc, a_sc, a_dc);
  // ---- layer 2 ----
  hg_gcn_q<<<C, 128, 0, stream>>>(tish, toff, tlist, dinv, g2t, gcnb + 128, Wqt, bubq, buWk, bubk, qkb, qbb);
  hg_gat_agg<<<(N + 3) / 4, 256, 0, stream>>>(hprojc, a_sc, a_dc, lab, off_cell, csr, gatb + 128, buf1,
                                              qkb, qbb, lab, s_att, N);
  hg_bu_chain<<<C, 256, 0, stream>>>(s_att, buf1, clu_list, clu_off, buWv, bubv, Wot, bubo, Wcat_t, bcat,
                                     nullptr, nullptr, nullptr, tish, ccell, nullptr, nullptr, nullptr);

  hg_readout<<<1, 256, 0, stream>>>(ccell, tish, clu_cnt, Wc1t, bc1, Wc2t, bc2, Wc3, bc3, outp);
}

// Round 6
// 615.607 us; speedup vs baseline: 1.5486x; 1.1933x over previous
//
#include <hip/hip_runtime.h>
#include <math.h>

constexpr int N  = 60000;
constexpr int F  = 256;
constexpr int H  = 128;
constexpr int C  = 256;
constexpr int E  = 600000;
constexpr int ET = 1500;
constexpr int NB = (N + 1023) / 1024;  // 59 scan blocks

// ---------------- histograms (cell-dst degree + cluster counts) ----------------
__global__ void hg_hist(const int* __restrict__ cdst, int* __restrict__ deg,
                        const int* __restrict__ lab, int* __restrict__ ccnt) {
  int e = blockIdx.x * 256 + threadIdx.x;
  if (e < E) atomicAdd(&deg[cdst[e]], 1);
  if (e < N) atomicAdd(&ccnt[lab[e]], 1);
}

// ---------------- multi-block scan ----------------
__global__ __launch_bounds__(256) void hg_scan1(const int* __restrict__ deg, int* __restrict__ off,
                                                int* __restrict__ btot, int n) {
  int b = blockIdx.x, t = threadIdx.x;
  int i0 = b * 1024 + t * 4;
  __shared__ int sums[256];
  int d0 = 0, d1 = 0, d2 = 0, d3 = 0;
  if (i0 + 3 < n) {
    int4 dd = *(const int4*)&deg[i0];
    d0 = dd.x; d1 = dd.y; d2 = dd.z; d3 = dd.w;
  } else {
    if (i0     < n) d0 = deg[i0];
    if (i0 + 1 < n) d1 = deg[i0 + 1];
    if (i0 + 2 < n) d2 = deg[i0 + 2];
    if (i0 + 3 < n) d3 = deg[i0 + 3];
  }
  int s = d0 + d1 + d2 + d3;
  sums[t] = s;
  __syncthreads();
  for (int ofs = 1; ofs < 256; ofs <<= 1) {
    int v = (t >= ofs) ? sums[t - ofs] : 0;
    __syncthreads();
    sums[t] += v;
    __syncthreads();
  }
  int excl = sums[t] - s;
  if (t == 255) btot[b] = sums[t];
  int run = excl;
  if (i0     < n) off[i0]     = run; run += d0;
  if (i0 + 1 < n) off[i0 + 1] = run; run += d1;
  if (i0 + 2 < n) off[i0 + 2] = run; run += d2;
  if (i0 + 3 < n) off[i0 + 3] = run;
}

// block0: scan of btot; block1: cluster-count scan; block2: tissue CSR + dinv
__global__ __launch_bounds__(256) void hg_scan2_setup(int* __restrict__ btot, int* __restrict__ off,
                                                      const int* __restrict__ ccnt, int* __restrict__ coff,
                                                      const int* __restrict__ tsrc, const int* __restrict__ tdst,
                                                      int* __restrict__ toff, int* __restrict__ tlist,
                                                      float* __restrict__ dinv) {
  __shared__ int sa[256], sb[256], sc2[256];
  int t = threadIdx.x;
  if (blockIdx.x == 0) {
    if (t < 64) sa[t] = (t < NB) ? btot[t] : 0;
    __syncthreads();
    if (t == 0) {
      int r = 0;
      for (int i = 0; i < NB; ++i) { int v = sa[i]; sa[i] = r; r += v; }
      off[N] = r;
    }
    __syncthreads();
    if (t < NB) btot[t] = sa[t];
  } else if (blockIdx.x == 1) {
    int v0 = ccnt[t];
    sa[t] = v0;
    __syncthreads();
    for (int ofs = 1; ofs < 256; ofs <<= 1) {
      int v = (t >= ofs) ? sa[t - ofs] : 0;
      __syncthreads();
      sa[t] += v;
      __syncthreads();
    }
    coff[t + 1] = sa[t];
    if (t == 0) coff[0] = 0;
  } else {
    sa[t] = 0;
    __syncthreads();
    for (int e = t; e < ET; e += 256) atomicAdd(&sa[tdst[e]], 1);
    __syncthreads();
    int v = sa[t];
    dinv[t] = rsqrtf((float)(v + 1));
    sb[t] = v;
    __syncthreads();
    for (int ofs = 1; ofs < 256; ofs <<= 1) {
      int u = (t >= ofs) ? sb[t - ofs] : 0;
      __syncthreads();
      sb[t] += u;
      __syncthreads();
    }
    toff[t + 1] = sb[t];
    if (t == 0) toff[0] = 0;
    sc2[t] = sb[t] - v;
    __syncthreads();
    for (int e = t; e < ET; e += 256) {
      int d = tdst[e];
      int p = atomicAdd(&sc2[d], 1);
      tlist[p] = tsrc[e];
    }
  }
}

__global__ void hg_scan3(int* __restrict__ off, const int* __restrict__ btot, int n) {
  int b = blockIdx.x;
  int addv = btot[b];
  int i0 = b * 1024 + threadIdx.x * 4;
#pragma unroll
  for (int r = 0; r < 4; ++r)
    if (i0 + r < n) off[i0 + r] += addv;
}

// merged: cell-edge CSR scatter + cluster-list scatter
__global__ void hg_scatter(const int* __restrict__ csrc, const int* __restrict__ cdst,
                           const int* __restrict__ off, int* __restrict__ cur, int* __restrict__ csr,
                           const int* __restrict__ lab, const int* __restrict__ coff,
                           int* __restrict__ ccur, int* __restrict__ list) {
  int e = blockIdx.x * 256 + threadIdx.x;
  if (e < E) {
    int d = cdst[e];
    int p = atomicAdd(&cur[d], 1);
    csr[off[d] + p] = csrc[e];
  }
  if (e < N) {
    int c = lab[e];
    int p = atomicAdd(&ccur[c], 1);
    list[coff[c] + p] = e;
  }
}

// ---------------- prep: 8 transposes + pc0 + pc1 (grid y = job) ----------------
struct TJob { const float* src; float* dst; int SR; int SC; int dld; };
struct PrepArgs {
  TJob j[8];
  const float* gatW1; const float* Wcp; const float* bcp; float* Wcompt; float* bcomp;
  const float* tdWo; const float* tdWv; const float* tdbv; const float* tdbo;
  float* A_td; float* Wcat_t; float* bcat;
};

__global__ __launch_bounds__(256) void hg_prep1(PrepArgs a) {
  int y = blockIdx.y, t = threadIdx.x;
  if (y < 8) {
    TJob jb = a.j[y];
    int total = jb.SR * jb.SC;
    for (int idx = blockIdx.x * 256 + t; idx < total; idx += gridDim.x * 256) {
      int r = idx / jb.SC, c = idx - r * jb.SC;
      jb.dst[(size_t)c * jb.dld + r] = jb.src[idx];
    }
  } else if (y == 8) {
    // pc0: Wcomp_t[k][j] = sum_m gatW1[j][m]*Wcp[m][k]
    int j = blockIdx.x, k = t;
    float acc = 0.f;
#pragma unroll 4
    for (int m = 0; m < 128; ++m) acc = fmaf(a.gatW1[j * 128 + m], a.Wcp[m * 256 + k], acc);
    a.Wcompt[k * 128 + j] = acc;
    if (k == 0) {
      float b = 0.f;
      for (int m = 0; m < 128; ++m) b = fmaf(a.gatW1[j * 128 + m], a.bcp[m], b);
      a.bcomp[j] = b;
    }
  } else if (blockIdx.x < 64) {
    // pc1: A_td = tdWo @ tdWv ; Wcat_t[:, 0:128] = A_td^T
    int j = blockIdx.x * 2 + (t >> 7), k = t & 127;
    float acc = 0.f;
#pragma unroll 4
    for (int p = 0; p < 128; ++p) acc = fmaf(a.tdWo[j * 128 + p], a.tdWv[p * 128 + k], acc);
    a.A_td[j * 128 + k] = acc;
    a.Wcat_t[k * 896 + j] = acc;
    if (k == 0) {
      float b = 0.f;
      for (int p = 0; p < 128; ++p) b = fmaf(a.tdWo[j * 128 + p], a.tdbv[p], b);
      a.bcat[j] = b + a.tdbo[j];
    }
  }
}

__global__ __launch_bounds__(256) void hg_pc2b(const float* __restrict__ Wih, const float* __restrict__ bih,
                                               const float* __restrict__ Whh, const float* __restrict__ bhh,
                                               const float* __restrict__ A_td, float* __restrict__ Wcat_t,
                                               float* __restrict__ bcat) {
  int jj = blockIdx.x * 2 + (threadIdx.x >> 7), k = threadIdx.x & 127;
  const float* coef;
  float extra, bb;
  int dcol, j;
  if (jj < 384) {
    j = jj; coef = Wih + (size_t)j * 256; extra = Wih[(size_t)j * 256 + 128 + k]; dcol = 128 + j; bb = bih[j];
  } else {
    j = jj - 384; coef = Whh + (size_t)j * 128; extra = 0.f; dcol = 512 + j; bb = bhh[j];
  }
  float a = 0.f;
#pragma unroll 4
  for (int m = 0; m < 128; ++m) a = fmaf(coef[m], A_td[m * 128 + k], a);
  Wcat_t[k * 896 + dcol] = a + extra;
  if (k == 0) {
    float b = 0.f;
    for (int m = 0; m < 128; ++m) b = fmaf(coef[m], bcat[m], b);
    bcat[dcol] = b + bb;
  }
}

// ---------------- 128x128-tile fp32 GEMM (K=256) + GAT-coef epilogue, + tissue_init tail blocks ----------------
__global__ __launch_bounds__(256, 3) void hg_gemm_coef(
    const float* __restrict__ A, int M, int rtiles,
    const float* __restrict__ Wt, const float* __restrict__ bias,
    float* __restrict__ outp,
    const float* __restrict__ avs, const float* __restrict__ avd,
    float* __restrict__ o_s, float* __restrict__ o_d,
    const int* __restrict__ list, const int* __restrict__ coff,
    const float* __restrict__ Wtpt, const float* __restrict__ btp, float* __restrict__ tish) {
  __shared__ float Al[32][132];
  __shared__ float Wl[32][132];
  const int t = threadIdx.x;

  if (blockIdx.x >= rtiles) {
    // ---- tissue init: per-cluster mean + projection ----
    int c = blockIdx.x - rtiles;
    float* mrow = (float*)Al;
    int s0 = coff[c], n = coff[c + 1] - s0;
    float acc = 0.f;
#pragma unroll 4
    for (int i = 0; i < n; ++i) acc += A[(size_t)list[s0 + i] * F + t];
    mrow[t] = acc / fmaxf((float)n, 1.f);
    __syncthreads();
    if (t < 128) {
      float a = btp[t];
#pragma unroll 4
      for (int k = 0; k < 256; ++k) a = fmaf(mrow[k], Wtpt[k * 128 + t], a);
      tish[c * 128 + t] = a;
    }
    return;
  }

  const int tx = t & 15, ty = t >> 4;
  const int m0 = blockIdx.x * 128;

  float acc[8][8];
#pragma unroll
  for (int r = 0; r < 8; ++r)
#pragma unroll
    for (int c = 0; c < 8; ++c) acc[r][c] = 0.f;

  const int arow = t & 127, akh = t >> 7;
  const int wkr = t >> 3, wc0 = (t & 7) * 4;
  const int agm = m0 + arow;

  for (int kc = 0; kc < 256; kc += 32) {
#pragma unroll
    for (int f = 0; f < 4; ++f) {
      int k_off = akh * 16 + f * 4;
      float4 a = make_float4(0.f, 0.f, 0.f, 0.f);
      if (agm < M) a = *(const float4*)&A[(size_t)agm * 256 + kc + k_off];
      Al[k_off][arow] = a.x;
      Al[k_off + 1][arow] = a.y;
      Al[k_off + 2][arow] = a.z;
      Al[k_off + 3][arow] = a.w;
    }
#pragma unroll
    for (int f = 0; f < 4; ++f) {
      *(float4*)&Wl[wkr][wc0 + f * 32] = *(const float4*)&Wt[(size_t)(kc + wkr) * 128 + wc0 + f * 32];
    }
    __syncthreads();
#pragma unroll 2
    for (int kk = 0; kk < 32; ++kk) {
      float4 a0 = *(const float4*)&Al[kk][ty * 4];
      float4 a1 = *(const float4*)&Al[kk][64 + ty * 4];
      float4 w0 = *(const float4*)&Wl[kk][tx * 4];
      float4 w1 = *(const float4*)&Wl[kk][64 + tx * 4];
      float ar[8] = {a0.x, a0.y, a0.z, a0.w, a1.x, a1.y, a1.z, a1.w};
      float wr[8] = {w0.x, w0.y, w0.z, w0.w, w1.x, w1.y, w1.z, w1.w};
#pragma unroll
      for (int r = 0; r < 8; ++r)
#pragma unroll
        for (int c = 0; c < 8; ++c) acc[r][c] = fmaf(ar[r], wr[c], acc[r][c]);
    }
    __syncthreads();
  }

  {
    float bA[8];
#pragma unroll
    for (int c = 0; c < 4; ++c) {
      bA[c] = bias[tx * 4 + c];
      bA[4 + c] = bias[64 + tx * 4 + c];
    }
#pragma unroll
    for (int r = 0; r < 8; ++r)
#pragma unroll
      for (int c = 0; c < 8; ++c) acc[r][c] += bA[c];
  }

#pragma unroll
  for (int r = 0; r < 8; ++r) {
    int gm = m0 + ((r < 4) ? (ty * 4 + r) : (64 + ty * 4 + r - 4));
    if (gm < M) {
      float* op = outp + (size_t)gm * 128 + tx * 4;
      *(float4*)op        = make_float4(acc[r][0], acc[r][1], acc[r][2], acc[r][3]);
      *(float4*)(op + 64) = make_float4(acc[r][4], acc[r][5], acc[r][6], acc[r][7]);
    }
  }

  {
    float4 s0 = *(const float4*)&avs[tx * 4], s1 = *(const float4*)&avs[64 + tx * 4];
    float4 d0 = *(const float4*)&avd[tx * 4], d1 = *(const float4*)&avd[64 + tx * 4];
#pragma unroll
    for (int r = 0; r < 8; ++r) {
      int gm = m0 + ((r < 4) ? (ty * 4 + r) : (64 + ty * 4 + r - 4));
      float psA = acc[r][0] * s0.x + acc[r][1] * s0.y + acc[r][2] * s0.z + acc[r][3] * s0.w;
      float psB = acc[r][4] * s1.x + acc[r][5] * s1.y + acc[r][6] * s1.z + acc[r][7] * s1.w;
      float pdA = acc[r][0] * d0.x + acc[r][1] * d0.y + acc[r][2] * d0.z + acc[r][3] * d0.w;
      float pdB = acc[r][4] * d1.x + acc[r][5] * d1.y + acc[r][6] * d1.z + acc[r][7] * d1.w;
      psA += __shfl_xor(psA, 1); psA += __shfl_xor(psA, 2);
      psB += __shfl_xor(psB, 1); psB += __shfl_xor(psB, 2);
      pdA += __shfl_xor(pdA, 1); pdA += __shfl_xor(pdA, 2);
      pdB += __shfl_xor(pdB, 1); pdB += __shfl_xor(pdB, 2);
      if ((tx & 3) == 0 && gm < M) {
        int h = tx >> 2;
        o_s[(size_t)gm * 8 + h] = psA;
        o_s[(size_t)gm * 8 + 4 + h] = psB;
        o_d[(size_t)gm * 8 + h] = pdA;
        o_d[(size_t)gm * 8 + 4 + h] = pdB;
      }
    }
  }
}

// ---------------- GAT aggregation: one WAVE per node (clu_list order), float4 2-edge gather ----------------
#define GMAXE 64
__global__ __launch_bounds__(256) void hg_gat_agg(
    const float* __restrict__ hproj, const float* __restrict__ a_s,
    const float* __restrict__ a_d, const int* __restrict__ remap,
    const int* __restrict__ off, const int* __restrict__ csr,
    const float* __restrict__ bias, float* __restrict__ outh,
    const float* __restrict__ qk, const float* __restrict__ qb,
    const int* __restrict__ lab, const int* __restrict__ nodelist,
    float* __restrict__ satt, int nNodes) {
  const int wid = threadIdx.x >> 6;
  const int l = threadIdx.x & 63;
  const int gid = blockIdx.x * 4 + wid;
  __shared__ int srcs_s[4][GMAXE];
  __shared__ float w_s[4][GMAXE][8];
  if (gid >= nNodes) return;
  const int node = nodelist[gid];
  int* srcs = srcs_s[wid];
  float (*wls)[8] = w_s[wid];
  const int o0 = off[node], deg = off[node + 1] - o0;
  const int cl = lab[node];
  const int dl = remap ? cl : node;   // remap == lab when used
  const int hsc = l & 7;              // score-space head
  const int q4 = l & 31;              // feature quad (features 4q4..4q4+3)
  const int sub = l >> 5;             // edge parity
  const int hq = q4 >> 2;             // head owning this quad
  const float adh = a_d[dl * 8 + hsc];
  const float ash = a_s[dl * 8 + hsc];
  float msc = -INFINITY, zsc = 0.f;
  float4 acc = make_float4(0.f, 0.f, 0.f, 0.f);
  const float4* hp4 = (const float4*)hproj;

  for (int cb = 0; cb < deg; cb += GMAXE) {
    const int len = min(GMAXE, deg - cb);
    if (l < len) {
      int s = csr[o0 + cb + l];
      srcs[l] = remap ? remap[s] : s;
    }
    asm volatile("s_waitcnt lgkmcnt(0)" ::: "memory");
    float lm = -INFINITY;
    for (int base = 0; base < len; base += 8) {
      int e = base + (l >> 3);
      if (e < len) {
        float sc = a_s[srcs[e] * 8 + hsc] + adh;
        sc = sc > 0.f ? sc : 0.2f * sc;  // leaky_relu(0.2)
        wls[e][hsc] = sc;
        lm = fmaxf(lm, sc);
      }
    }
    lm = fmaxf(lm, __shfl_xor(lm, 8));
    lm = fmaxf(lm, __shfl_xor(lm, 16));
    lm = fmaxf(lm, __shfl_xor(lm, 32));
    float mnew = fmaxf(msc, lm);
    float rs = __expf(msc - mnew);  // 0 on first chunk
    float zc = 0.f;
    asm volatile("s_waitcnt lgkmcnt(0)" ::: "memory");
    for (int base = 0; base < len; base += 8) {
      int e = base + (l >> 3);
      if (e < len) {
        float wv = __expf(wls[e][hsc] - mnew);
        wls[e][hsc] = wv;
        zc += wv;
      }
    }
    asm volatile("s_waitcnt lgkmcnt(0)" ::: "memory");
    zc += __shfl_xor(zc, 8); zc += __shfl_xor(zc, 16); zc += __shfl_xor(zc, 32);
    zsc = zsc * rs + zc;
    msc = mnew;
    float rsa = __shfl(rs, hq);
    acc.x *= rsa; acc.y *= rsa; acc.z *= rsa; acc.w *= rsa;
    for (int e = sub; e < len; e += 2) {
      float wv = wls[e][hq];
      float4 hv = hp4[(size_t)srcs[e] * 32 + q4];
      acc.x = fmaf(wv, hv.x, acc.x);
      acc.y = fmaf(wv, hv.y, acc.y);
      acc.z = fmaf(wv, hv.z, acc.z);
      acc.w = fmaf(wv, hv.w, acc.w);
    }
  }
  // self-loop (head-space per lane), applied once after combining halves
  float ssl = ash + adh;
  ssl = ssl > 0.f ? ssl : 0.2f * ssl;
  float mnew = fmaxf(msc, ssl);
  float rs = __expf(msc - mnew);
  float wsl = __expf(ssl - mnew);
  zsc = zsc * rs + wsl;
  float rsa = __shfl(rs, hq);
  float wsa = __shfl(wsl, hq);
  float zh = __shfl(zsc, hq);
  acc.x *= rsa; acc.y *= rsa; acc.z *= rsa; acc.w *= rsa;
  acc.x += __shfl_xor(acc.x, 32);
  acc.y += __shfl_xor(acc.y, 32);
  acc.z += __shfl_xor(acc.z, 32);
  acc.w += __shfl_xor(acc.w, 32);
  float4 hv = hp4[(size_t)dl * 32 + q4];
  acc.x = fmaf(wsa, hv.x, acc.x);
  acc.y = fmaf(wsa, hv.y, acc.y);
  acc.z = fmaf(wsa, hv.z, acc.z);
  acc.w = fmaf(wsa, hv.w, acc.w);
  float inv = 1.f / zh;
  float4 bv4 = *(const float4*)&bias[q4 * 4];
  float4 o;
  o.x = acc.x * inv + bv4.x;
  o.y = acc.y * inv + bv4.y;
  o.z = acc.z * inv + bv4.z;
  o.w = acc.w * inv + bv4.w;
  o.x = o.x > 0.f ? o.x : __expf(o.x) - 1.f;  // ELU
  o.y = o.y > 0.f ? o.y : __expf(o.y) - 1.f;
  o.z = o.z > 0.f ? o.z : __expf(o.z) - 1.f;
  o.w = o.w > 0.f ? o.w : __expf(o.w) - 1.f;
  if (sub == 0) ((float4*)outh)[(size_t)node * 32 + q4] = o;

  // s_att epilogue: 4 heads per half (L2-hot qk table thanks to clu_list ordering)
  const float4* qk4 = (const float4*)(qk + (size_t)cl * 1024);
  float p0, p1, p2, p3;
  {
    float4 qv0 = qk4[(sub * 4 + 0) * 32 + q4];
    float4 qv1 = qk4[(sub * 4 + 1) * 32 + q4];
    float4 qv2 = qk4[(sub * 4 + 2) * 32 + q4];
    float4 qv3 = qk4[(sub * 4 + 3) * 32 + q4];
    p0 = o.x * qv0.x + o.y * qv0.y + o.z * qv0.z + o.w * qv0.w;
    p1 = o.x * qv1.x + o.y * qv1.y + o.z * qv1.z + o.w * qv1.w;
    p2 = o.x * qv2.x + o.y * qv2.y + o.z * qv2.z + o.w * qv2.w;
    p3 = o.x * qv3.x + o.y * qv3.y + o.z * qv3.z + o.w * qv3.w;
  }
  int b4f = (l >> 4) & 1, b3f = (l >> 3) & 1;
  float snd0 = b4f ? p0 : p2, snd1 = b4f ? p1 : p3;
  float kp0  = b4f ? p2 : p0, kp1  = b4f ? p3 : p1;
  kp0 += __shfl_xor(snd0, 16);
  kp1 += __shfl_xor(snd1, 16);
  float snd = b3f ? kp0 : kp1;
  float kp  = b3f ? kp1 : kp0;
  kp += __shfl_xor(snd, 8);
  kp += __shfl_xor(kp, 4);
  kp += __shfl_xor(kp, 2);
  kp += __shfl_xor(kp, 1);
  int h = sub * 4 + b4f * 2 + b3f;
  if ((l & 7) == 0) satt[(size_t)node * 8 + h] = kp + qb[cl * 8 + h];
}

// ---------------- tissue GCN + q projection + qk/qb tables ----------------
__global__ __launch_bounds__(128) void hg_gcn_q(const float* __restrict__ tin, const int* __restrict__ toff,
                                                const int* __restrict__ tlist, const float* __restrict__ dinv,
                                                const float* __restrict__ gt, const float* __restrict__ gcnb,
                                                const float* __restrict__ Wqt, const float* __restrict__ bq,
                                                const float* __restrict__ Wk, const float* __restrict__ bk,
                                                float* __restrict__ qk, float* __restrict__ qb) {
  int c = blockIdx.x, t = threadIdx.x;
  __shared__ float xa[128], trow[128], qrow[128];
  float dc = dinv[c];
  float acc = tin[c * 128 + t] * dc * dc;
  int s0 = toff[c], s1 = toff[c + 1];
  for (int i = s0; i < s1; ++i) {
    int s = tlist[i];
    acc = fmaf(tin[s * 128 + t], dinv[s] * dc, acc);
  }
  xa[t] = acc;
  __syncthreads();
  float th = 0.f;
#pragma unroll 4
  for (int k = 0; k < 128; ++k) th = fmaf(xa[k], gt[k * 128 + t], th);
  float vv = fmaxf(th + gcnb[t], 0.f);
  trow[t] = vv;
  __syncthreads();
  float qa = bq[t];
#pragma unroll 4
  for (int k = 0; k < 128; ++k) qa = fmaf(trow[k], Wqt[k * 128 + t], qa);
  qrow[t] = qa * 0.25f;  // 1/sqrt(DH)
  __syncthreads();
#pragma unroll
  for (int h = 0; h < 8; ++h) {
    float s = 0.f;
#pragma unroll
    for (int j = 0; j < 16; ++j) s = fmaf(Wk[(size_t)(h * 16 + j) * 128 + t], qrow[h * 16 + j], s);
    qk[((size_t)c * 8 + h) * 128 + t] = s;
  }
  if (t < 8) {
    float s = 0.f;
#pragma unroll
    for (int j = 0; j < 16; ++j) s = fmaf(qrow[t * 16 + j], bk[t * 16 + j], s);
    qb[c * 8 + t] = s;
  }
}

// ---------------- fused: per-cluster softmax head-means, Wv, Wo, td+GRU, gates, next GAT proj ----------------
__global__ __launch_bounds__(256) void hg_bu_chain(
    const float* __restrict__ s_att, const float* __restrict__ hcell,
    const int* __restrict__ list, const int* __restrict__ coff,
    const float* __restrict__ Wv, const float* __restrict__ bv,
    const float* __restrict__ Wot, const float* __restrict__ bo,
    const float* __restrict__ Wcat_t, const float* __restrict__ bcat,
    const float* __restrict__ gatWt, const float* __restrict__ avs, const float* __restrict__ avd,
    float* __restrict__ tish, float* __restrict__ ccell,
    float* __restrict__ hprojc, float* __restrict__ a_s2, float* __restrict__ a_d2) {
  int c = blockIdx.x, t = threadIdx.x;
  int s0 = coff[c], n = coff[c + 1] - s0;
  int tf = t & 127, half = t >> 7;
  __shared__ float red[32][8];
  __shared__ float mh[8], zh[8];
  __shared__ int cells[64];
  __shared__ float wl[64][8];
  __shared__ float msh[8][128];
  __shared__ float b0[128], b1[128], part[2][128], catv[896];
  int g = t >> 3, h8 = t & 7;
  float lm = -INFINITY;
  for (int i = g; i < n; i += 32) lm = fmaxf(lm, s_att[(size_t)list[s0 + i] * 8 + h8]);
  red[g][h8] = lm;
  __syncthreads();
  if (t < 8) {
    float m2 = -INFINITY;
#pragma unroll
    for (int i = 0; i < 32; ++i) m2 = fmaxf(m2, red[i][t]);
    mh[t] = m2;
  }
  __syncthreads();
  const float mloc = mh[t & 7];
  float zp = 0.f;
  float macc[8] = {0.f, 0.f, 0.f, 0.f, 0.f, 0.f, 0.f, 0.f};
  for (int cb = 0; cb < n; cb += 64) {
    int len = min(64, n - cb);
    if (t < len) cells[t] = list[s0 + cb + t];
    __syncthreads();
#pragma unroll
    for (int p = 0; p < 2; ++p) {
      int e = p * 32 + (t >> 3);
      if (e < len) {
        float w = __expf(s_att[(size_t)cells[e] * 8 + (t & 7)] - mloc);
        wl[e][t & 7] = w;
        zp += w;
      }
    }
    __syncthreads();
    for (int e = half; e < len; e += 2) {
      float x = hcell[(size_t)cells[e] * 128 + tf];
      float4 w0 = *(const float4*)&wl[e][0];
      float4 w1 = *(const float4*)&wl[e][4];
      macc[0] = fmaf(w0.x, x, macc[0]);
      macc[1] = fmaf(w0.y, x, macc[1]);
      macc[2] = fmaf(w0.z, x, macc[2]);
      macc[3] = fmaf(w0.w, x, macc[3]);
      macc[4] = fmaf(w1.x, x, macc[4]);
      macc[5] = fmaf(w1.y, x, macc[5]);
      macc[6] = fmaf(w1.z, x, macc[6]);
      macc[7] = fmaf(w1.w, x, macc[7]);
    }
    __syncthreads();
  }
  red[t >> 3][t & 7] = zp;
  __syncthreads();
  if (t < 8) {
    float z = 0.f;
#pragma unroll
    for (int i = 0; i < 32; ++i) z += red[i][t];
    zh[t] = (n > 0) ? 1.f / z : 0.f;
  }
  if (half) {
#pragma unroll
    for (int h = 0; h < 8; ++h) msh[h][tf] = macc[h];
  }
  __syncthreads();
  if (!half) {
#pragma unroll
    for (int h = 0; h < 8; ++h) msh[h][tf] = (macc[h] + msh[h][tf]) * zh[h];
  }
  __syncthreads();
  {
    int h = tf >> 4;
    float ps = 0.f;
    const float* wp = Wv + (size_t)tf * 128 + half * 64;
    const float* mp = &msh[h][half * 64];
#pragma unroll 4
    for (int k = 0; k < 64; ++k) ps = fmaf(wp[k], mp[k], ps);
    part[half][tf] = ps;
  }
  __syncthreads();
  if (t < 128) b0[t] = part[0][t] + part[1][t] + bv[t];
  __syncthreads();
  int ks = half;
  {
    float ps = 0.f;
    const float* wp = Wot + (size_t)ks * 64 * 128 + tf;
#pragma unroll 4
    for (int k = 0; k < 64; ++k) ps = fmaf(b0[ks * 64 + k], wp[k * 128], ps);
    part[ks][tf] = ps;
  }
  __syncthreads();
  if (t < 128) {
    float vv = part[0][t] + part[1][t] + bo[t];
    b1[t] = vv;
    tish[c * 128 + t] = vv;
  }
  __syncthreads();
  for (int j = t; j < 896; j += 256) {
    float a = bcat[j];
#pragma unroll 4
    for (int k = 0; k < 128; ++k) a = fmaf(b1[k], Wcat_t[k * 896 + j], a);
    catv[j] = a;
  }
  __syncthreads();
  if (t < 128) {
    float td = catv[t];
    float r = 1.f / (1.f + expf(-(catv[128 + t] + catv[512 + t])));
    float zz = 1.f / (1.f + expf(-(catv[256 + t] + catv[640 + t])));
    float nn = tanhf(catv[384 + t] + r * catv[768 + t]);
    float cn = (1.f - zz) * nn + zz * td;
    ccell[c * 128 + t] = cn;
    b0[t] = cn;
  }
  __syncthreads();
  if (gatWt) {
    float ps = 0.f;
    const float* wp = gatWt + (size_t)ks * 64 * 128 + tf;
#pragma unroll 4
    for (int k = 0; k < 64; ++k) ps = fmaf(b0[ks * 64 + k], wp[k * 128], ps);
    part[ks][tf] = ps;
    __syncthreads();
    if (t < 128) {
      float hp = part[0][t] + part[1][t];
      hprojc[c * 128 + t] = hp;
      float pss = hp * avs[t], pdd = hp * avd[t];
      pss += __shfl_xor(pss, 1); pss += __shfl_xor(pss, 2); pss += __shfl_xor(pss, 4); pss += __shfl_xor(pss, 8);
      pdd += __shfl_xor(pdd, 1); pdd += __shfl_xor(pdd, 2); pdd += __shfl_xor(pdd, 4); pdd += __shfl_xor(pdd, 8);
      if ((t & 15) == 0) {
        a_s2[c * 8 + (t >> 4)] = pss;
        a_d2[c * 8 + (t >> 4)] = pdd;
      }
    }
  }
}

// ---------------- readout + classifier ----------------
__global__ __launch_bounds__(256) void hg_readout(const float* __restrict__ ccell2, const float* __restrict__ tish,
                                                  const int* __restrict__ cnt, const float* __restrict__ Wc1t,
                                                  const float* __restrict__ bc1, const float* __restrict__ Wc2t,
                                                  const float* __restrict__ bc2, const float* __restrict__ Wc3,
                                                  const float* __restrict__ bc3, float* __restrict__ outp) {
  __shared__ float emb[512], h1s[256], h2s[128];
  int t = threadIdx.x;
  if (t < 128) {
    float sm = 0.f, mx = -INFINITY;
    for (int c = 0; c < C; ++c) {
      float vv = ccell2[c * 128 + t];
      int n = cnt[c];
      sm += (float)n * vv;
      if (n > 0) mx = fmaxf(mx, vv);
    }
    emb[t] = sm / (float)N;
    emb[128 + t] = mx;
  } else {
    int tt = t - 128;
    float sm = 0.f, mx = -INFINITY;
    for (int c = 0; c < C; ++c) {
      float vv = tish[c * 128 + tt];
      sm += vv;
      mx = fmaxf(mx, vv);
    }
    emb[256 + tt] = sm * (1.f / (float)C);
    emb[384 + tt] = mx;
  }
  __syncthreads();
  float a = bc1[t];
#pragma unroll 4
  for (int kk = 0; kk < 512; ++kk) a = fmaf(emb[kk], Wc1t[kk * 256 + t], a);
  h1s[t] = fmaxf(a, 0.f);
  __syncthreads();
  if (t < 128) {
    float a2 = bc2[t];
#pragma unroll 4
    for (int kk = 0; kk < 256; ++kk) a2 = fmaf(h1s[kk], Wc2t[kk * 128 + t], a2);
    h2s[t] = fmaxf(a2, 0.f);
  }
  __syncthreads();
  if (t < 4) {
    float o = bc3[t];
    for (int kk = 0; kk < 128; ++kk) o = fmaf(h2s[kk], Wc3[t * 128 + kk], o);
    outp[t] = o;
  }
}

// ---------------- host launcher ----------------
extern "C" void kernel_launch(void* const* d_in, const int* in_sizes, int n_in,
                              void* d_out, int out_size, void* d_ws, size_t ws_size,
                              hipStream_t stream) {
  (void)in_sizes; (void)n_in; (void)out_size; (void)ws_size;
  const float* feat  = (const float*)d_in[0];
  const int*   eidx  = (const int*)d_in[1];
  const int*   lab   = (const int*)d_in[2];
  const int*   tidx  = (const int*)d_in[3];
  const float* Wcp   = (const float*)d_in[4];
  const float* bcp   = (const float*)d_in[5];
  const float* Wtp   = (const float*)d_in[6];
  const float* btp   = (const float*)d_in[7];
  const float* gatW  = (const float*)d_in[8];
  const float* gasrc = (const float*)d_in[9];
  const float* gadst = (const float*)d_in[10];
  const float* gatb  = (const float*)d_in[11];
  const float* gcnW  = (const float*)d_in[12];
  const float* gcnb  = (const float*)d_in[13];
  const float* buWq  = (const float*)d_in[14];
  const float* buWk  = (const float*)d_in[15];
  const float* buWv  = (const float*)d_in[16];
  const float* bubq  = (const float*)d_in[17];
  const float* bubk  = (const float*)d_in[18];
  const float* bubv  = (const float*)d_in[19];
  const float* buWo  = (const float*)d_in[20];
  const float* bubo  = (const float*)d_in[21];
  const float* tdWv  = (const float*)d_in[22];
  const float* tdbv  = (const float*)d_in[23];
  const float* tdWo  = (const float*)d_in[24];
  const float* tdbo  = (const float*)d_in[25];
  const float* Wih   = (const float*)d_in[26];
  const float* bih   = (const float*)d_in[27];
  const float* Whh   = (const float*)d_in[28];
  const float* bhh   = (const float*)d_in[29];
  const float* Wc1   = (const float*)d_in[30];
  const float* bc1   = (const float*)d_in[31];
  const float* Wc2   = (const float*)d_in[32];
  const float* bc2   = (const float*)d_in[33];
  const float* Wc3   = (const float*)d_in[34];
  const float* bc3   = (const float*)d_in[35];
  float* outp = (float*)d_out;

  const int* csrc = eidx;
  const int* cdst = eidx + E;
  const int* tsrc = tidx;
  const int* tdst = tidx + ET;

  char* w = (char*)d_ws;
  auto alloc = [&](size_t bytes) -> void* {
    void* p = (void*)w;
    w += (bytes + 255) & ~(size_t)255;
    return p;
  };
  char* cnt0 = w;
  int* deg_cell = (int*)alloc((size_t)N * 4);
  int* cur_cell = (int*)alloc((size_t)N * 4);
  int* clu_cnt  = (int*)alloc((size_t)C * 4);
  int* clu_cur  = (int*)alloc((size_t)C * 4);
  size_t cntBytes = (size_t)(w - cnt0);
  int* off_cell = (int*)alloc((size_t)(N + 1) * 4);
  int* btot     = (int*)alloc(64 * 4);
  int* csr      = (int*)alloc((size_t)E * 4);
  int* clu_off  = (int*)alloc((size_t)(C + 1) * 4);
  int* clu_list = (int*)alloc((size_t)N * 4);
  int* toff     = (int*)alloc((size_t)(C + 1) * 4);
  int* tlist    = (int*)alloc((size_t)ET * 4);
  float* dinv   = (float*)alloc((size_t)C * 4);
  float* buf1   = (float*)alloc((size_t)N * 128 * 4);
  float* buf2   = (float*)alloc((size_t)N * 128 * 4);
  float* a_s    = (float*)alloc((size_t)N * 8 * 4);
  float* a_d    = (float*)alloc((size_t)N * 8 * 4);
  float* s_att  = (float*)alloc((size_t)N * 8 * 4);
  float* tish   = (float*)alloc((size_t)C * 128 * 4);
  float* qkb    = (float*)alloc((size_t)C * 8 * 128 * 4);
  float* qbb    = (float*)alloc((size_t)C * 8 * 4);
  float* ccell  = (float*)alloc((size_t)C * 128 * 4);
  float* hprojc = (float*)alloc((size_t)C * 128 * 4);
  float* a_sc   = (float*)alloc((size_t)C * 8 * 4);
  float* a_dc   = (float*)alloc((size_t)C * 8 * 4);
  float* A_td   = (float*)alloc(128 * 128 * 4);
  float* Wcat_t = (float*)alloc(128 * 896 * 4);
  float* bcat   = (float*)alloc(896 * 4);
  float* Wcompt = (float*)alloc(256 * 128 * 4);
  float* bcomp  = (float*)alloc(128 * 4);
  float* Wtpt   = (float*)alloc(256 * 128 * 4);
  float* g1t    = (float*)alloc(128 * 128 * 4);
  float* g2t    = (float*)alloc(128 * 128 * 4);
  float* Wqt    = (float*)alloc(128 * 128 * 4);
  float* Wot    = (float*)alloc(128 * 128 * 4);
  float* gatW2t = (float*)alloc(128 * 128 * 4);
  float* Wc1t   = (float*)alloc(512 * 256 * 4);
  float* Wc2t   = (float*)alloc(256 * 128 * 4);

  hipMemsetAsync(cnt0, 0, cntBytes, stream);

  hg_hist<<<(E + 255) / 256, 256, 0, stream>>>(cdst, deg_cell, lab, clu_cnt);
  hg_scan1<<<NB, 256, 0, stream>>>(deg_cell, off_cell, btot, N);
  hg_scan2_setup<<<3, 256, 0, stream>>>(btot, off_cell, clu_cnt, clu_off, tsrc, tdst, toff, tlist, dinv);
  hg_scan3<<<NB, 256, 0, stream>>>(off_cell, btot, N);
  hg_scatter<<<(E + 255) / 256, 256, 0, stream>>>(csrc, cdst, off_cell, cur_cell, csr,
                                                  lab, clu_off, clu_cur, clu_list);

  PrepArgs pa;
  pa.j[0] = {Wtp,            Wtpt,   128, 256, 128};
  pa.j[1] = {gcnW,           g1t,    128, 128, 128};
  pa.j[2] = {gcnW + 128*128, g2t,    128, 128, 128};
  pa.j[3] = {buWq,           Wqt,    128, 128, 128};
  pa.j[4] = {buWo,           Wot,    128, 128, 128};
  pa.j[5] = {gatW + 128*128, gatW2t, 128, 128, 128};
  pa.j[6] = {Wc1,            Wc1t,   256, 512, 256};
  pa.j[7] = {Wc2,            Wc2t,   128, 256, 128};
  pa.gatW1 = gatW; pa.Wcp = Wcp; pa.bcp = bcp; pa.Wcompt = Wcompt; pa.bcomp = bcomp;
  pa.tdWo = tdWo; pa.tdWv = tdWv; pa.tdbv = tdbv; pa.tdbo = tdbo;
  pa.A_td = A_td; pa.Wcat_t = Wcat_t; pa.bcat = bcat;
  hg_prep1<<<dim3(128, 10), 256, 0, stream>>>(pa);
  hg_pc2b<<<384, 256, 0, stream>>>(Wih, bih, Whh, bhh, A_td, Wcat_t, bcat);

  const int RT = (N + 127) / 128;  // 469 row tiles
  // hproj_l1 GEMM + GAT coef epilogue + tissue_init tail blocks
  hg_gemm_coef<<<RT + C, 256, 0, stream>>>(feat, N, RT, Wcompt, bcomp, buf2, gasrc, gadst, a_s, a_d,
                                           clu_list, clu_off, Wtpt, btp, tish);
  // ---- layer 1 ----
  hg_gcn_q<<<C, 128, 0, stream>>>(tish, toff, tlist, dinv, g1t, gcnb, Wqt, bubq, buWk, bubk, qkb, qbb);
  hg_gat_agg<<<(N + 3) / 4, 256, 0, stream>>>(buf2, a_s, a_d, nullptr, off_cell, csr, gatb, buf1,
                                              qkb, qbb, lab, clu_list, s_att, N);
  hg_bu_chain<<<C, 256, 0, stream>>>(s_att, buf1, clu_list, clu_off, buWv, bubv, Wot, bubo, Wcat_t, bcat,
                                     gatW2t, gasrc + 128, gadst + 128, tish, ccell, hprojc, a_sc, a_dc);
  // ---- layer 2 ----
  hg_gcn_q<<<C, 128, 0, stream>>>(tish, toff, tlist, dinv, g2t, gcnb + 128, Wqt, bubq, buWk, bubk, qkb, qbb);
  hg_gat_agg<<<(N + 3) / 4, 256, 0, stream>>>(hprojc, a_sc, a_dc, lab, off_cell, csr, gatb + 128, buf1,
                                              qkb, qbb, lab, clu_list, s_att, N);
  hg_bu_chain<<<C, 256, 0, stream>>>(s_att, buf1, clu_list, clu_off, buWv, bubv, Wot, bubo, Wcat_t, bcat,
                                     nullptr, nullptr, nullptr, tish, ccell, nullptr, nullptr, nullptr);

  hg_readout<<<1, 256, 0, stream>>>(ccell, tish, clu_cnt, Wc1t, bc1, Wc2t, bc2, Wc3, bc3, outp);
}

// Round 7
// 570.264 us; speedup vs baseline: 1.6718x; 1.0795x over previous
//
#include <hip/hip_runtime.h>
#include <math.h>

constexpr int N  = 60000;
constexpr int F  = 256;
constexpr int H  = 128;
constexpr int C  = 256;
constexpr int E  = 600000;
constexpr int ET = 1500;
constexpr int NB = (N + 1023) / 1024;  // 59 scan blocks
constexpr int SPL = 8;                 // bu softmax splits per cluster

// ---------------- histograms (cell-dst degree + cluster counts) ----------------
__global__ void hg_hist(const int* __restrict__ cdst, int* __restrict__ deg,
                        const int* __restrict__ lab, int* __restrict__ ccnt) {
  int e = blockIdx.x * 256 + threadIdx.x;
  if (e < E) atomicAdd(&deg[cdst[e]], 1);
  if (e < N) atomicAdd(&ccnt[lab[e]], 1);
}

// ---------------- multi-block scan ----------------
__global__ __launch_bounds__(256) void hg_scan1(const int* __restrict__ deg, int* __restrict__ off,
                                                int* __restrict__ btot, int n) {
  int b = blockIdx.x, t = threadIdx.x;
  int i0 = b * 1024 + t * 4;
  __shared__ int sums[256];
  int d0 = 0, d1 = 0, d2 = 0, d3 = 0;
  if (i0 + 3 < n) {
    int4 dd = *(const int4*)&deg[i0];
    d0 = dd.x; d1 = dd.y; d2 = dd.z; d3 = dd.w;
  } else {
    if (i0     < n) d0 = deg[i0];
    if (i0 + 1 < n) d1 = deg[i0 + 1];
    if (i0 + 2 < n) d2 = deg[i0 + 2];
    if (i0 + 3 < n) d3 = deg[i0 + 3];
  }
  int s = d0 + d1 + d2 + d3;
  sums[t] = s;
  __syncthreads();
  for (int ofs = 1; ofs < 256; ofs <<= 1) {
    int v = (t >= ofs) ? sums[t - ofs] : 0;
    __syncthreads();
    sums[t] += v;
    __syncthreads();
  }
  int excl = sums[t] - s;
  if (t == 255) btot[b] = sums[t];
  int run = excl;
  if (i0     < n) off[i0]     = run; run += d0;
  if (i0 + 1 < n) off[i0 + 1] = run; run += d1;
  if (i0 + 2 < n) off[i0 + 2] = run; run += d2;
  if (i0 + 3 < n) off[i0 + 3] = run;
}

// block0: scan of btot; block1: cluster-count scan; block2: tissue CSR + dinv
__global__ __launch_bounds__(256) void hg_scan2_setup(int* __restrict__ btot, int* __restrict__ off,
                                                      const int* __restrict__ ccnt, int* __restrict__ coff,
                                                      const int* __restrict__ tsrc, const int* __restrict__ tdst,
                                                      int* __restrict__ toff, int* __restrict__ tlist,
                                                      float* __restrict__ dinv) {
  __shared__ int sa[256], sb[256], sc2[256];
  int t = threadIdx.x;
  if (blockIdx.x == 0) {
    if (t < 64) sa[t] = (t < NB) ? btot[t] : 0;
    __syncthreads();
    if (t == 0) {
      int r = 0;
      for (int i = 0; i < NB; ++i) { int v = sa[i]; sa[i] = r; r += v; }
      off[N] = r;
    }
    __syncthreads();
    if (t < NB) btot[t] = sa[t];
  } else if (blockIdx.x == 1) {
    int v0 = ccnt[t];
    sa[t] = v0;
    __syncthreads();
    for (int ofs = 1; ofs < 256; ofs <<= 1) {
      int v = (t >= ofs) ? sa[t - ofs] : 0;
      __syncthreads();
      sa[t] += v;
      __syncthreads();
    }
    coff[t + 1] = sa[t];
    if (t == 0) coff[0] = 0;
  } else {
    sa[t] = 0;
    __syncthreads();
    for (int e = t; e < ET; e += 256) atomicAdd(&sa[tdst[e]], 1);
    __syncthreads();
    int v = sa[t];
    dinv[t] = rsqrtf((float)(v + 1));
    sb[t] = v;
    __syncthreads();
    for (int ofs = 1; ofs < 256; ofs <<= 1) {
      int u = (t >= ofs) ? sb[t - ofs] : 0;
      __syncthreads();
      sb[t] += u;
      __syncthreads();
    }
    toff[t + 1] = sb[t];
    if (t == 0) toff[0] = 0;
    sc2[t] = sb[t] - v;
    __syncthreads();
    for (int e = t; e < ET; e += 256) {
      int d = tdst[e];
      int p = atomicAdd(&sc2[d], 1);
      tlist[p] = tsrc[e];
    }
  }
}

__global__ void hg_scan3(int* __restrict__ off, const int* __restrict__ btot, int n) {
  int b = blockIdx.x;
  int addv = btot[b];
  int i0 = b * 1024 + threadIdx.x * 4;
#pragma unroll
  for (int r = 0; r < 4; ++r)
    if (i0 + r < n) off[i0 + r] += addv;
}

// merged: cell-edge CSR scatter + cluster-list scatter
__global__ void hg_scatter(const int* __restrict__ csrc, const int* __restrict__ cdst,
                           const int* __restrict__ off, int* __restrict__ cur, int* __restrict__ csr,
                           const int* __restrict__ lab, const int* __restrict__ coff,
                           int* __restrict__ ccur, int* __restrict__ list) {
  int e = blockIdx.x * 256 + threadIdx.x;
  if (e < E) {
    int d = cdst[e];
    int p = atomicAdd(&cur[d], 1);
    csr[off[d] + p] = csrc[e];
  }
  if (e < N) {
    int c = lab[e];
    int p = atomicAdd(&ccur[c], 1);
    list[coff[c] + p] = e;
  }
}

// ---------------- prep: 8 transposes + pc0 + pc1 (grid y = job) ----------------
struct TJob { const float* src; float* dst; int SR; int SC; int dld; };
struct PrepArgs {
  TJob j[8];
  const float* gatW1; const float* Wcp; const float* bcp; float* Wcompt; float* bcomp;
  const float* tdWo; const float* tdWv; const float* tdbv; const float* tdbo;
  float* A_td; float* Wcat_t; float* bcat;
};

__global__ __launch_bounds__(256) void hg_prep1(PrepArgs a) {
  int y = blockIdx.y, t = threadIdx.x;
  if (y < 8) {
    TJob jb = a.j[y];
    int total = jb.SR * jb.SC;
    for (int idx = blockIdx.x * 256 + t; idx < total; idx += gridDim.x * 256) {
      int r = idx / jb.SC, c = idx - r * jb.SC;
      jb.dst[(size_t)c * jb.dld + r] = jb.src[idx];
    }
  } else if (y == 8) {
    int j = blockIdx.x, k = t;
    float acc = 0.f;
#pragma unroll 4
    for (int m = 0; m < 128; ++m) acc = fmaf(a.gatW1[j * 128 + m], a.Wcp[m * 256 + k], acc);
    a.Wcompt[k * 128 + j] = acc;
    if (k == 0) {
      float b = 0.f;
      for (int m = 0; m < 128; ++m) b = fmaf(a.gatW1[j * 128 + m], a.bcp[m], b);
      a.bcomp[j] = b;
    }
  } else if (blockIdx.x < 64) {
    int j = blockIdx.x * 2 + (t >> 7), k = t & 127;
    float acc = 0.f;
#pragma unroll 4
    for (int p = 0; p < 128; ++p) acc = fmaf(a.tdWo[j * 128 + p], a.tdWv[p * 128 + k], acc);
    a.A_td[j * 128 + k] = acc;
    a.Wcat_t[k * 896 + j] = acc;
    if (k == 0) {
      float b = 0.f;
      for (int p = 0; p < 128; ++p) b = fmaf(a.tdWo[j * 128 + p], a.tdbv[p], b);
      a.bcat[j] = b + a.tdbo[j];
    }
  }
}

__global__ __launch_bounds__(256) void hg_pc2b(const float* __restrict__ Wih, const float* __restrict__ bih,
                                               const float* __restrict__ Whh, const float* __restrict__ bhh,
                                               const float* __restrict__ A_td, float* __restrict__ Wcat_t,
                                               float* __restrict__ bcat) {
  int jj = blockIdx.x * 2 + (threadIdx.x >> 7), k = threadIdx.x & 127;
  const float* coef;
  float extra, bb;
  int dcol, j;
  if (jj < 384) {
    j = jj; coef = Wih + (size_t)j * 256; extra = Wih[(size_t)j * 256 + 128 + k]; dcol = 128 + j; bb = bih[j];
  } else {
    j = jj - 384; coef = Whh + (size_t)j * 128; extra = 0.f; dcol = 512 + j; bb = bhh[j];
  }
  float a = 0.f;
#pragma unroll 4
  for (int m = 0; m < 128; ++m) a = fmaf(coef[m], A_td[m * 128 + k], a);
  Wcat_t[k * 896 + dcol] = a + extra;
  if (k == 0) {
    float b = 0.f;
    for (int m = 0; m < 128; ++m) b = fmaf(coef[m], bcat[m], b);
    bcat[dcol] = b + bb;
  }
}

// ---------------- 128x128-tile fp32 GEMM (K=256) + GAT-coef epilogue, + tissue_init tail blocks ----------------
__global__ __launch_bounds__(256, 3) void hg_gemm_coef(
    const float* __restrict__ A, int M, int rtiles,
    const float* __restrict__ Wt, const float* __restrict__ bias,
    float* __restrict__ outp,
    const float* __restrict__ avs, const float* __restrict__ avd,
    float* __restrict__ o_s, float* __restrict__ o_d,
    const int* __restrict__ list, const int* __restrict__ coff,
    const float* __restrict__ Wtpt, const float* __restrict__ btp, float* __restrict__ tish) {
  __shared__ float Al[32][132];
  __shared__ float Wl[32][132];
  const int t = threadIdx.x;

  if (blockIdx.x >= rtiles) {
    int c = blockIdx.x - rtiles;
    float* mrow = (float*)Al;
    int s0 = coff[c], n = coff[c + 1] - s0;
    float acc = 0.f;
#pragma unroll 4
    for (int i = 0; i < n; ++i) acc += A[(size_t)list[s0 + i] * F + t];
    mrow[t] = acc / fmaxf((float)n, 1.f);
    __syncthreads();
    if (t < 128) {
      float a = btp[t];
#pragma unroll 4
      for (int k = 0; k < 256; ++k) a = fmaf(mrow[k], Wtpt[k * 128 + t], a);
      tish[c * 128 + t] = a;
    }
    return;
  }

  const int tx = t & 15, ty = t >> 4;
  const int m0 = blockIdx.x * 128;

  float acc[8][8];
#pragma unroll
  for (int r = 0; r < 8; ++r)
#pragma unroll
    for (int c = 0; c < 8; ++c) acc[r][c] = 0.f;

  const int arow = t & 127, akh = t >> 7;
  const int wkr = t >> 3, wc0 = (t & 7) * 4;
  const int agm = m0 + arow;

  for (int kc = 0; kc < 256; kc += 32) {
#pragma unroll
    for (int f = 0; f < 4; ++f) {
      int k_off = akh * 16 + f * 4;
      float4 a = make_float4(0.f, 0.f, 0.f, 0.f);
      if (agm < M) a = *(const float4*)&A[(size_t)agm * 256 + kc + k_off];
      Al[k_off][arow] = a.x;
      Al[k_off + 1][arow] = a.y;
      Al[k_off + 2][arow] = a.z;
      Al[k_off + 3][arow] = a.w;
    }
#pragma unroll
    for (int f = 0; f < 4; ++f) {
      *(float4*)&Wl[wkr][wc0 + f * 32] = *(const float4*)&Wt[(size_t)(kc + wkr) * 128 + wc0 + f * 32];
    }
    __syncthreads();
#pragma unroll 2
    for (int kk = 0; kk < 32; ++kk) {
      float4 a0 = *(const float4*)&Al[kk][ty * 4];
      float4 a1 = *(const float4*)&Al[kk][64 + ty * 4];
      float4 w0 = *(const float4*)&Wl[kk][tx * 4];
      float4 w1 = *(const float4*)&Wl[kk][64 + tx * 4];
      float ar[8] = {a0.x, a0.y, a0.z, a0.w, a1.x, a1.y, a1.z, a1.w};
      float wr[8] = {w0.x, w0.y, w0.z, w0.w, w1.x, w1.y, w1.z, w1.w};
#pragma unroll
      for (int r = 0; r < 8; ++r)
#pragma unroll
        for (int c = 0; c < 8; ++c) acc[r][c] = fmaf(ar[r], wr[c], acc[r][c]);
    }
    __syncthreads();
  }

  {
    float bA[8];
#pragma unroll
    for (int c = 0; c < 4; ++c) {
      bA[c] = bias[tx * 4 + c];
      bA[4 + c] = bias[64 + tx * 4 + c];
    }
#pragma unroll
    for (int r = 0; r < 8; ++r)
#pragma unroll
      for (int c = 0; c < 8; ++c) acc[r][c] += bA[c];
  }

#pragma unroll
  for (int r = 0; r < 8; ++r) {
    int gm = m0 + ((r < 4) ? (ty * 4 + r) : (64 + ty * 4 + r - 4));
    if (gm < M) {
      float* op = outp + (size_t)gm * 128 + tx * 4;
      *(float4*)op        = make_float4(acc[r][0], acc[r][1], acc[r][2], acc[r][3]);
      *(float4*)(op + 64) = make_float4(acc[r][4], acc[r][5], acc[r][6], acc[r][7]);
    }
  }

  {
    float4 s0 = *(const float4*)&avs[tx * 4], s1 = *(const float4*)&avs[64 + tx * 4];
    float4 d0 = *(const float4*)&avd[tx * 4], d1 = *(const float4*)&avd[64 + tx * 4];
#pragma unroll
    for (int r = 0; r < 8; ++r) {
      int gm = m0 + ((r < 4) ? (ty * 4 + r) : (64 + ty * 4 + r - 4));
      float psA = acc[r][0] * s0.x + acc[r][1] * s0.y + acc[r][2] * s0.z + acc[r][3] * s0.w;
      float psB = acc[r][4] * s1.x + acc[r][5] * s1.y + acc[r][6] * s1.z + acc[r][7] * s1.w;
      float pdA = acc[r][0] * d0.x + acc[r][1] * d0.y + acc[r][2] * d0.z + acc[r][3] * d0.w;
      float pdB = acc[r][4] * d1.x + acc[r][5] * d1.y + acc[r][6] * d1.z + acc[r][7] * d1.w;
      psA += __shfl_xor(psA, 1); psA += __shfl_xor(psA, 2);
      psB += __shfl_xor(psB, 1); psB += __shfl_xor(psB, 2);
      pdA += __shfl_xor(pdA, 1); pdA += __shfl_xor(pdA, 2);
      pdB += __shfl_xor(pdB, 1); pdB += __shfl_xor(pdB, 2);
      if ((tx & 3) == 0 && gm < M) {
        int h = tx >> 2;
        o_s[(size_t)gm * 8 + h] = psA;
        o_s[(size_t)gm * 8 + 4 + h] = psB;
        o_d[(size_t)gm * 8 + h] = pdA;
        o_d[(size_t)gm * 8 + 4 + h] = pdB;
      }
    }
  }
}

// ---------------- GAT aggregation: one WAVE per node (clu_list order), float4 2-edge gather ----------------
#define GMAXE 64
__global__ __launch_bounds__(256) void hg_gat_agg(
    const float* __restrict__ hproj, const float* __restrict__ a_s,
    const float* __restrict__ a_d, const int* __restrict__ remap,
    const int* __restrict__ off, const int* __restrict__ csr,
    const float* __restrict__ bias, float* __restrict__ outh,
    const float* __restrict__ qk, const float* __restrict__ qb,
    const int* __restrict__ lab, const int* __restrict__ nodelist,
    float* __restrict__ satt, int nNodes) {
  const int wid = threadIdx.x >> 6;
  const int l = threadIdx.x & 63;
  const int gid = blockIdx.x * 4 + wid;
  __shared__ int srcs_s[4][GMAXE];
  __shared__ float w_s[4][GMAXE][8];
  if (gid >= nNodes) return;
  const int node = nodelist[gid];
  int* srcs = srcs_s[wid];
  float (*wls)[8] = w_s[wid];
  const int o0 = off[node], deg = off[node + 1] - o0;
  const int cl = lab[node];
  const int dl = remap ? cl : node;
  const int hsc = l & 7;
  const int q4 = l & 31;
  const int sub = l >> 5;
  const int hq = q4 >> 2;
  const float adh = a_d[dl * 8 + hsc];
  const float ash = a_s[dl * 8 + hsc];
  float msc = -INFINITY, zsc = 0.f;
  float4 acc = make_float4(0.f, 0.f, 0.f, 0.f);
  const float4* hp4 = (const float4*)hproj;

  for (int cb = 0; cb < deg; cb += GMAXE) {
    const int len = min(GMAXE, deg - cb);
    if (l < len) {
      int s = csr[o0 + cb + l];
      srcs[l] = remap ? remap[s] : s;
    }
    asm volatile("s_waitcnt lgkmcnt(0)" ::: "memory");
    float lm = -INFINITY;
    for (int base = 0; base < len; base += 8) {
      int e = base + (l >> 3);
      if (e < len) {
        float sc = a_s[srcs[e] * 8 + hsc] + adh;
        sc = sc > 0.f ? sc : 0.2f * sc;
        wls[e][hsc] = sc;
        lm = fmaxf(lm, sc);
      }
    }
    lm = fmaxf(lm, __shfl_xor(lm, 8));
    lm = fmaxf(lm, __shfl_xor(lm, 16));
    lm = fmaxf(lm, __shfl_xor(lm, 32));
    float mnew = fmaxf(msc, lm);
    float rs = __expf(msc - mnew);
    float zc = 0.f;
    asm volatile("s_waitcnt lgkmcnt(0)" ::: "memory");
    for (int base = 0; base < len; base += 8) {
      int e = base + (l >> 3);
      if (e < len) {
        float wv = __expf(wls[e][hsc] - mnew);
        wls[e][hsc] = wv;
        zc += wv;
      }
    }
    asm volatile("s_waitcnt lgkmcnt(0)" ::: "memory");
    zc += __shfl_xor(zc, 8); zc += __shfl_xor(zc, 16); zc += __shfl_xor(zc, 32);
    zsc = zsc * rs + zc;
    msc = mnew;
    float rsa = __shfl(rs, hq);
    acc.x *= rsa; acc.y *= rsa; acc.z *= rsa; acc.w *= rsa;
    for (int e = sub; e < len; e += 2) {
      float wv = wls[e][hq];
      float4 hv = hp4[(size_t)srcs[e] * 32 + q4];
      acc.x = fmaf(wv, hv.x, acc.x);
      acc.y = fmaf(wv, hv.y, acc.y);
      acc.z = fmaf(wv, hv.z, acc.z);
      acc.w = fmaf(wv, hv.w, acc.w);
    }
  }
  float ssl = ash + adh;
  ssl = ssl > 0.f ? ssl : 0.2f * ssl;
  float mnew = fmaxf(msc, ssl);
  float rs = __expf(msc - mnew);
  float wsl = __expf(ssl - mnew);
  zsc = zsc * rs + wsl;
  float rsa = __shfl(rs, hq);
  float wsa = __shfl(wsl, hq);
  float zh = __shfl(zsc, hq);
  acc.x *= rsa; acc.y *= rsa; acc.z *= rsa; acc.w *= rsa;
  acc.x += __shfl_xor(acc.x, 32);
  acc.y += __shfl_xor(acc.y, 32);
  acc.z += __shfl_xor(acc.z, 32);
  acc.w += __shfl_xor(acc.w, 32);
  float4 hv = hp4[(size_t)dl * 32 + q4];
  acc.x = fmaf(wsa, hv.x, acc.x);
  acc.y = fmaf(wsa, hv.y, acc.y);
  acc.z = fmaf(wsa, hv.z, acc.z);
  acc.w = fmaf(wsa, hv.w, acc.w);
  float inv = 1.f / zh;
  float4 bv4 = *(const float4*)&bias[q4 * 4];
  float4 o;
  o.x = acc.x * inv + bv4.x;
  o.y = acc.y * inv + bv4.y;
  o.z = acc.z * inv + bv4.z;
  o.w = acc.w * inv + bv4.w;
  o.x = o.x > 0.f ? o.x : __expf(o.x) - 1.f;
  o.y = o.y > 0.f ? o.y : __expf(o.y) - 1.f;
  o.z = o.z > 0.f ? o.z : __expf(o.z) - 1.f;
  o.w = o.w > 0.f ? o.w : __expf(o.w) - 1.f;
  if (sub == 0) ((float4*)outh)[(size_t)node * 32 + q4] = o;

  const float4* qk4 = (const float4*)(qk + (size_t)cl * 1024);
  float p0, p1, p2, p3;
  {
    float4 qv0 = qk4[(sub * 4 + 0) * 32 + q4];
    float4 qv1 = qk4[(sub * 4 + 1) * 32 + q4];
    float4 qv2 = qk4[(sub * 4 + 2) * 32 + q4];
    float4 qv3 = qk4[(sub * 4 + 3) * 32 + q4];
    p0 = o.x * qv0.x + o.y * qv0.y + o.z * qv0.z + o.w * qv0.w;
    p1 = o.x * qv1.x + o.y * qv1.y + o.z * qv1.z + o.w * qv1.w;
    p2 = o.x * qv2.x + o.y * qv2.y + o.z * qv2.z + o.w * qv2.w;
    p3 = o.x * qv3.x + o.y * qv3.y + o.z * qv3.z + o.w * qv3.w;
  }
  int b4f = (l >> 4) & 1, b3f = (l >> 3) & 1;
  float snd0 = b4f ? p0 : p2, snd1 = b4f ? p1 : p3;
  float kp0  = b4f ? p2 : p0, kp1  = b4f ? p3 : p1;
  kp0 += __shfl_xor(snd0, 16);
  kp1 += __shfl_xor(snd1, 16);
  float snd = b3f ? kp0 : kp1;
  float kp  = b3f ? kp1 : kp0;
  kp += __shfl_xor(snd, 8);
  kp += __shfl_xor(kp, 4);
  kp += __shfl_xor(kp, 2);
  kp += __shfl_xor(kp, 1);
  int h = sub * 4 + b4f * 2 + b3f;
  if ((l & 7) == 0) satt[(size_t)node * 8 + h] = kp + qb[cl * 8 + h];
}

// ---------------- tissue GCN + q projection + qk/qb tables ----------------
__global__ __launch_bounds__(128) void hg_gcn_q(const float* __restrict__ tin, const int* __restrict__ toff,
                                                const int* __restrict__ tlist, const float* __restrict__ dinv,
                                                const float* __restrict__ gt, const float* __restrict__ gcnb,
                                                const float* __restrict__ Wqt, const float* __restrict__ bq,
                                                const float* __restrict__ Wk, const float* __restrict__ bk,
                                                float* __restrict__ qk, float* __restrict__ qb) {
  int c = blockIdx.x, t = threadIdx.x;
  __shared__ float xa[128], trow[128], qrow[128];
  float dc = dinv[c];
  float acc = tin[c * 128 + t] * dc * dc;
  int s0 = toff[c], s1 = toff[c + 1];
  for (int i = s0; i < s1; ++i) {
    int s = tlist[i];
    acc = fmaf(tin[s * 128 + t], dinv[s] * dc, acc);
  }
  xa[t] = acc;
  __syncthreads();
  float th = 0.f;
#pragma unroll 4
  for (int k = 0; k < 128; ++k) th = fmaf(xa[k], gt[k * 128 + t], th);
  float vv = fmaxf(th + gcnb[t], 0.f);
  trow[t] = vv;
  __syncthreads();
  float qa = bq[t];
#pragma unroll 4
  for (int k = 0; k < 128; ++k) qa = fmaf(trow[k], Wqt[k * 128 + t], qa);
  qrow[t] = qa * 0.25f;  // 1/sqrt(DH)
  __syncthreads();
#pragma unroll
  for (int h = 0; h < 8; ++h) {
    float s = 0.f;
#pragma unroll
    for (int j = 0; j < 16; ++j) s = fmaf(Wk[(size_t)(h * 16 + j) * 128 + t], qrow[h * 16 + j], s);
    qk[((size_t)c * 8 + h) * 128 + t] = s;
  }
  if (t < 8) {
    float s = 0.f;
#pragma unroll
    for (int j = 0; j < 16; ++j) s = fmaf(qrow[t * 16 + j], bk[t * 16 + j], s);
    qb[c * 8 + t] = s;
  }
}

// ---------------- bu softmax partials: grid (C, SPL) ----------------
__global__ __launch_bounds__(256) void hg_bu_part(
    const float* __restrict__ s_att, const float* __restrict__ hcell,
    const int* __restrict__ list, const int* __restrict__ coff,
    float* __restrict__ pm, float* __restrict__ pz, float* __restrict__ pmacc) {
  int c = blockIdx.x, sp = blockIdx.y, t = threadIdx.x;
  int s0 = coff[c], n = coff[c + 1] - s0;
  int chunk = (n + SPL - 1) / SPL;
  int b0 = min(n, sp * chunk), b1 = min(n, b0 + chunk);
  int cnt = b1 - b0;
  int tf = t & 127, half = t >> 7;
  __shared__ float red[32][8];
  __shared__ float mh[8];
  __shared__ int cells[64];
  __shared__ float wl[64][8];
  __shared__ float msh[8][128];
  int g = t >> 3, h8 = t & 7;
  float lm = -INFINITY;
  for (int i = g; i < cnt; i += 32) lm = fmaxf(lm, s_att[(size_t)list[s0 + b0 + i] * 8 + h8]);
  red[g][h8] = lm;
  __syncthreads();
  if (t < 8) {
    float m2 = -INFINITY;
#pragma unroll
    for (int i = 0; i < 32; ++i) m2 = fmaxf(m2, red[i][t]);
    mh[t] = m2;
  }
  __syncthreads();
  const float mloc = mh[t & 7];
  float zp = 0.f;
  float macc[8] = {0.f, 0.f, 0.f, 0.f, 0.f, 0.f, 0.f, 0.f};
  for (int cb = 0; cb < cnt; cb += 64) {
    int len = min(64, cnt - cb);
    if (t < len) cells[t] = list[s0 + b0 + cb + t];
    __syncthreads();
#pragma unroll
    for (int p = 0; p < 2; ++p) {
      int e = p * 32 + (t >> 3);
      if (e < len) {
        float w = __expf(s_att[(size_t)cells[e] * 8 + (t & 7)] - mloc);
        wl[e][t & 7] = w;
        zp += w;
      }
    }
    __syncthreads();
    for (int e = half; e < len; e += 2) {
      float x = hcell[(size_t)cells[e] * 128 + tf];
      float4 w0 = *(const float4*)&wl[e][0];
      float4 w1 = *(const float4*)&wl[e][4];
      macc[0] = fmaf(w0.x, x, macc[0]);
      macc[1] = fmaf(w0.y, x, macc[1]);
      macc[2] = fmaf(w0.z, x, macc[2]);
      macc[3] = fmaf(w0.w, x, macc[3]);
      macc[4] = fmaf(w1.x, x, macc[4]);
      macc[5] = fmaf(w1.y, x, macc[5]);
      macc[6] = fmaf(w1.z, x, macc[6]);
      macc[7] = fmaf(w1.w, x, macc[7]);
    }
    __syncthreads();
  }
  red[t >> 3][t & 7] = zp;
  __syncthreads();
  int pidx = (c * SPL + sp) * 8;
  if (t < 8) {
    float z = 0.f;
#pragma unroll
    for (int i = 0; i < 32; ++i) z += red[i][t];
    pz[pidx + t] = z;
    pm[pidx + t] = mh[t];
  }
  if (half) {
#pragma unroll
    for (int h = 0; h < 8; ++h) msh[h][tf] = macc[h];
  }
  __syncthreads();
  if (!half) {
#pragma unroll
    for (int h = 0; h < 8; ++h) pmacc[(size_t)(pidx + h) * 128 + tf] = macc[h] + msh[h][tf];
  }
}

// ---------------- fused cluster chain: merge partials, Wv, Wo, td+GRU, gates, next GAT proj ----------------
__global__ __launch_bounds__(256) void hg_bu_chain(
    const float* __restrict__ pm, const float* __restrict__ pz, const float* __restrict__ pmacc,
    const float* __restrict__ Wv, const float* __restrict__ bv,
    const float* __restrict__ Wot, const float* __restrict__ bo,
    const float* __restrict__ Wcat_t, const float* __restrict__ bcat,
    const float* __restrict__ gatWt, const float* __restrict__ avs, const float* __restrict__ avd,
    float* __restrict__ tish, float* __restrict__ ccell,
    float* __restrict__ hprojc, float* __restrict__ a_s2, float* __restrict__ a_d2) {
  int c = blockIdx.x, t = threadIdx.x;
  int tf = t & 127, half = t >> 7;
  __shared__ float mh[8], zh[8];
  __shared__ float sscale[SPL][8];
  __shared__ float msh[8][128];
  __shared__ float b0[128], b1[128], part[2][128], catv[896];
  const int pbase = c * SPL * 8;
  // merge per-split maxima
  if (t < 8) {
    float mg = -INFINITY;
#pragma unroll
    for (int s = 0; s < SPL; ++s) mg = fmaxf(mg, pm[pbase + s * 8 + t]);
    mh[t] = mg;
  }
  __syncthreads();
  if (t < SPL * 8) {
    int s = t >> 3, h = t & 7;
    float ms = pm[pbase + s * 8 + h];
    sscale[s][h] = (ms > -1e37f) ? __expf(ms - mh[h]) : 0.f;
  }
  __syncthreads();
  if (t < 8) {
    float z = 0.f;
#pragma unroll
    for (int s = 0; s < SPL; ++s) z += pz[pbase + s * 8 + t] * sscale[s][t];
    zh[t] = (z > 0.f) ? 1.f / z : 0.f;
  }
  __syncthreads();
#pragma unroll
  for (int hh = 0; hh < 4; ++hh) {
    int h = half * 4 + hh;
    float a = 0.f;
#pragma unroll
    for (int s = 0; s < SPL; ++s)
      a = fmaf(pmacc[(size_t)(pbase + s * 8 + h) * 128 + tf], sscale[s][h], a);
    msh[h][tf] = a * zh[h];
  }
  __syncthreads();
  // --- ctx = Wv · head-means + bv (2-way k-split) ---
  {
    int h = tf >> 4;
    float ps = 0.f;
    const float* wp = Wv + (size_t)tf * 128 + half * 64;
    const float* mp = &msh[h][half * 64];
#pragma unroll 4
    for (int k = 0; k < 64; ++k) ps = fmaf(wp[k], mp[k], ps);
    part[half][tf] = ps;
  }
  __syncthreads();
  if (t < 128) b0[t] = part[0][t] + part[1][t] + bv[t];
  __syncthreads();
  int ks = half;
  {
    float ps = 0.f;
    const float* wp = Wot + (size_t)ks * 64 * 128 + tf;
#pragma unroll 4
    for (int k = 0; k < 64; ++k) ps = fmaf(b0[ks * 64 + k], wp[k * 128], ps);
    part[ks][tf] = ps;
  }
  __syncthreads();
  if (t < 128) {
    float vv = part[0][t] + part[1][t] + bo[t];
    b1[t] = vv;
    tish[c * 128 + t] = vv;
  }
  __syncthreads();
  for (int j = t; j < 896; j += 256) {
    float a = bcat[j];
#pragma unroll 4
    for (int k = 0; k < 128; ++k) a = fmaf(b1[k], Wcat_t[k * 896 + j], a);
    catv[j] = a;
  }
  __syncthreads();
  if (t < 128) {
    float td = catv[t];
    float r = 1.f / (1.f + expf(-(catv[128 + t] + catv[512 + t])));
    float zz = 1.f / (1.f + expf(-(catv[256 + t] + catv[640 + t])));
    float nn = tanhf(catv[384 + t] + r * catv[768 + t]);
    float cn = (1.f - zz) * nn + zz * td;
    ccell[c * 128 + t] = cn;
    b0[t] = cn;
  }
  __syncthreads();
  if (gatWt) {
    float ps = 0.f;
    const float* wp = gatWt + (size_t)ks * 64 * 128 + tf;
#pragma unroll 4
    for (int k = 0; k < 64; ++k) ps = fmaf(b0[ks * 64 + k], wp[k * 128], ps);
    part[ks][tf] = ps;
    __syncthreads();
    if (t < 128) {
      float hp = part[0][t] + part[1][t];
      hprojc[c * 128 + t] = hp;
      float pss = hp * avs[t], pdd = hp * avd[t];
      pss += __shfl_xor(pss, 1); pss += __shfl_xor(pss, 2); pss += __shfl_xor(pss, 4); pss += __shfl_xor(pss, 8);
      pdd += __shfl_xor(pdd, 1); pdd += __shfl_xor(pdd, 2); pdd += __shfl_xor(pdd, 4); pdd += __shfl_xor(pdd, 8);
      if ((t & 15) == 0) {
        a_s2[c * 8 + (t >> 4)] = pss;
        a_d2[c * 8 + (t >> 4)] = pdd;
      }
    }
  }
}

// ---------------- readout + classifier ----------------
__global__ __launch_bounds__(256) void hg_readout(const float* __restrict__ ccell2, const float* __restrict__ tish,
                                                  const int* __restrict__ cnt, const float* __restrict__ Wc1t,
                                                  const float* __restrict__ bc1, const float* __restrict__ Wc2t,
                                                  const float* __restrict__ bc2, const float* __restrict__ Wc3,
                                                  const float* __restrict__ bc3, float* __restrict__ outp) {
  __shared__ float emb[512], h1s[256], h2s[128];
  int t = threadIdx.x;
  if (t < 128) {
    float sm = 0.f, mx = -INFINITY;
    for (int c = 0; c < C; ++c) {
      float vv = ccell2[c * 128 + t];
      int n = cnt[c];
      sm += (float)n * vv;
      if (n > 0) mx = fmaxf(mx, vv);
    }
    emb[t] = sm / (float)N;
    emb[128 + t] = mx;
  } else {
    int tt = t - 128;
    float sm = 0.f, mx = -INFINITY;
    for (int c = 0; c < C; ++c) {
      float vv = tish[c * 128 + tt];
      sm += vv;
      mx = fmaxf(mx, vv);
    }
    emb[256 + tt] = sm * (1.f / (float)C);
    emb[384 + tt] = mx;
  }
  __syncthreads();
  float a = bc1[t];
#pragma unroll 4
  for (int kk = 0; kk < 512; ++kk) a = fmaf(emb[kk], Wc1t[kk * 256 + t], a);
  h1s[t] = fmaxf(a, 0.f);
  __syncthreads();
  if (t < 128) {
    float a2 = bc2[t];
#pragma unroll 4
    for (int kk = 0; kk < 256; ++kk) a2 = fmaf(h1s[kk], Wc2t[kk * 128 + t], a2);
    h2s[t] = fmaxf(a2, 0.f);
  }
  __syncthreads();
  if (t < 4) {
    float o = bc3[t];
    for (int kk = 0; kk < 128; ++kk) o = fmaf(h2s[kk], Wc3[t * 128 + kk], o);
    outp[t] = o;
  }
}

// ---------------- host launcher ----------------
extern "C" void kernel_launch(void* const* d_in, const int* in_sizes, int n_in,
                              void* d_out, int out_size, void* d_ws, size_t ws_size,
                              hipStream_t stream) {
  (void)in_sizes; (void)n_in; (void)out_size; (void)ws_size;
  const float* feat  = (const float*)d_in[0];
  const int*   eidx  = (const int*)d_in[1];
  const int*   lab   = (const int*)d_in[2];
  const int*   tidx  = (const int*)d_in[3];
  const float* Wcp   = (const float*)d_in[4];
  const float* bcp   = (const float*)d_in[5];
  const float* Wtp   = (const float*)d_in[6];
  const float* btp   = (const float*)d_in[7];
  const float* gatW  = (const float*)d_in[8];
  const float* gasrc = (const float*)d_in[9];
  const float* gadst = (const float*)d_in[10];
  const float* gatb  = (const float*)d_in[11];
  const float* gcnW  = (const float*)d_in[12];
  const float* gcnb  = (const float*)d_in[13];
  const float* buWq  = (const float*)d_in[14];
  const float* buWk  = (const float*)d_in[15];
  const float* buWv  = (const float*)d_in[16];
  const float* bubq  = (const float*)d_in[17];
  const float* bubk  = (const float*)d_in[18];
  const float* bubv  = (const float*)d_in[19];
  const float* buWo  = (const float*)d_in[20];
  const float* bubo  = (const float*)d_in[21];
  const float* tdWv  = (const float*)d_in[22];
  const float* tdbv  = (const float*)d_in[23];
  const float* tdWo  = (const float*)d_in[24];
  const float* tdbo  = (const float*)d_in[25];
  const float* Wih   = (const float*)d_in[26];
  const float* bih   = (const float*)d_in[27];
  const float* Whh   = (const float*)d_in[28];
  const float* bhh   = (const float*)d_in[29];
  const float* Wc1   = (const float*)d_in[30];
  const float* bc1   = (const float*)d_in[31];
  const float* Wc2   = (const float*)d_in[32];
  const float* bc2   = (const float*)d_in[33];
  const float* Wc3   = (const float*)d_in[34];
  const float* bc3   = (const float*)d_in[35];
  float* outp = (float*)d_out;

  const int* csrc = eidx;
  const int* cdst = eidx + E;
  const int* tsrc = tidx;
  const int* tdst = tidx + ET;

  char* w = (char*)d_ws;
  auto alloc = [&](size_t bytes) -> void* {
    void* p = (void*)w;
    w += (bytes + 255) & ~(size_t)255;
    return p;
  };
  char* cnt0 = w;
  int* deg_cell = (int*)alloc((size_t)N * 4);
  int* cur_cell = (int*)alloc((size_t)N * 4);
  int* clu_cnt  = (int*)alloc((size_t)C * 4);
  int* clu_cur  = (int*)alloc((size_t)C * 4);
  size_t cntBytes = (size_t)(w - cnt0);
  int* off_cell = (int*)alloc((size_t)(N + 1) * 4);
  int* btot     = (int*)alloc(64 * 4);
  int* csr      = (int*)alloc((size_t)E * 4);
  int* clu_off  = (int*)alloc((size_t)(C + 1) * 4);
  int* clu_list = (int*)alloc((size_t)N * 4);
  int* toff     = (int*)alloc((size_t)(C + 1) * 4);
  int* tlist    = (int*)alloc((size_t)ET * 4);
  float* dinv   = (float*)alloc((size_t)C * 4);
  float* buf1   = (float*)alloc((size_t)N * 128 * 4);
  float* buf2   = (float*)alloc((size_t)N * 128 * 4);
  float* a_s    = (float*)alloc((size_t)N * 8 * 4);
  float* a_d    = (float*)alloc((size_t)N * 8 * 4);
  float* s_att  = (float*)alloc((size_t)N * 8 * 4);
  float* tish   = (float*)alloc((size_t)C * 128 * 4);
  float* qkb    = (float*)alloc((size_t)C * 8 * 128 * 4);
  float* qbb    = (float*)alloc((size_t)C * 8 * 4);
  float* ccell  = (float*)alloc((size_t)C * 128 * 4);
  float* hprojc = (float*)alloc((size_t)C * 128 * 4);
  float* a_sc   = (float*)alloc((size_t)C * 8 * 4);
  float* a_dc   = (float*)alloc((size_t)C * 8 * 4);
  float* pm     = (float*)alloc((size_t)C * SPL * 8 * 4);
  float* pz     = (float*)alloc((size_t)C * SPL * 8 * 4);
  float* pmacc  = (float*)alloc((size_t)C * SPL * 8 * 128 * 4);
  float* A_td   = (float*)alloc(128 * 128 * 4);
  float* Wcat_t = (float*)alloc(128 * 896 * 4);
  float* bcat   = (float*)alloc(896 * 4);
  float* Wcompt = (float*)alloc(256 * 128 * 4);
  float* bcomp  = (float*)alloc(128 * 4);
  float* Wtpt   = (float*)alloc(256 * 128 * 4);
  float* g1t    = (float*)alloc(128 * 128 * 4);
  float* g2t    = (float*)alloc(128 * 128 * 4);
  float* Wqt    = (float*)alloc(128 * 128 * 4);
  float* Wot    = (float*)alloc(128 * 128 * 4);
  float* gatW2t = (float*)alloc(128 * 128 * 4);
  float* Wc1t   = (float*)alloc(512 * 256 * 4);
  float* Wc2t   = (float*)alloc(256 * 128 * 4);

  hipMemsetAsync(cnt0, 0, cntBytes, stream);

  hg_hist<<<(E + 255) / 256, 256, 0, stream>>>(cdst, deg_cell, lab, clu_cnt);
  hg_scan1<<<NB, 256, 0, stream>>>(deg_cell, off_cell, btot, N);
  hg_scan2_setup<<<3, 256, 0, stream>>>(btot, off_cell, clu_cnt, clu_off, tsrc, tdst, toff, tlist, dinv);
  hg_scan3<<<NB, 256, 0, stream>>>(off_cell, btot, N);
  hg_scatter<<<(E + 255) / 256, 256, 0, stream>>>(csrc, cdst, off_cell, cur_cell, csr,
                                                  lab, clu_off, clu_cur, clu_list);

  PrepArgs pa;
  pa.j[0] = {Wtp,            Wtpt,   128, 256, 128};
  pa.j[1] = {gcnW,           g1t,    128, 128, 128};
  pa.j[2] = {gcnW + 128*128, g2t,    128, 128, 128};
  pa.j[3] = {buWq,           Wqt,    128, 128, 128};
  pa.j[4] = {buWo,           Wot,    128, 128, 128};
  pa.j[5] = {gatW + 128*128, gatW2t, 128, 128, 128};
  pa.j[6] = {Wc1,            Wc1t,   256, 512, 256};
  pa.j[7] = {Wc2,            Wc2t,   128, 256, 128};
  pa.gatW1 = gatW; pa.Wcp = Wcp; pa.bcp = bcp; pa.Wcompt = Wcompt; pa.bcomp = bcomp;
  pa.tdWo = tdWo; pa.tdWv = tdWv; pa.tdbv = tdbv; pa.tdbo = tdbo;
  pa.A_td = A_td; pa.Wcat_t = Wcat_t; pa.bcat = bcat;
  hg_prep1<<<dim3(128, 10), 256, 0, stream>>>(pa);
  hg_pc2b<<<384, 256, 0, stream>>>(Wih, bih, Whh, bhh, A_td, Wcat_t, bcat);

  const int RT = (N + 127) / 128;  // 469 row tiles
  hg_gemm_coef<<<RT + C, 256, 0, stream>>>(feat, N, RT, Wcompt, bcomp, buf2, gasrc, gadst, a_s, a_d,
                                           clu_list, clu_off, Wtpt, btp, tish);
  // ---- layer 1 ----
  hg_gcn_q<<<C, 128, 0, stream>>>(tish, toff, tlist, dinv, g1t, gcnb, Wqt, bubq, buWk, bubk, qkb, qbb);
  hg_gat_agg<<<(N + 3) / 4, 256, 0, stream>>>(buf2, a_s, a_d, nullptr, off_cell, csr, gatb, buf1,
                                              qkb, qbb, lab, clu_list, s_att, N);
  hg_bu_part<<<dim3(C, SPL), 256, 0, stream>>>(s_att, buf1, clu_list, clu_off, pm, pz, pmacc);
  hg_bu_chain<<<C, 256, 0, stream>>>(pm, pz, pmacc, buWv, bubv, Wot, bubo, Wcat_t, bcat,
                                     gatW2t, gasrc + 128, gadst + 128, tish, ccell, hprojc, a_sc, a_dc);
  // ---- layer 2 ----
  hg_gcn_q<<<C, 128, 0, stream>>>(tish, toff, tlist, dinv, g2t, gcnb + 128, Wqt, bubq, buWk, bubk, qkb, qbb);
  hg_gat_agg<<<(N + 3) / 4, 256, 0, stream>>>(hprojc, a_sc, a_dc, lab, off_cell, csr, gatb + 128, buf1,
                                              qkb, qbb, lab, clu_list, s_att, N);
  hg_bu_part<<<dim3(C, SPL), 256, 0, stream>>>(s_att, buf1, clu_list, clu_off, pm, pz, pmacc);
  hg_bu_chain<<<C, 256, 0, stream>>>(pm, pz, pmacc, buWv, bubv, Wot, bubo, Wcat_t, bcat,
                                     nullptr, nullptr, nullptr, tish, ccell, nullptr, nullptr, nullptr);

  hg_readout<<<1, 256, 0, stream>>>(ccell, tish, clu_cnt, Wc1t, bc1, Wc2t, bc2, Wc3, bc3, outp);
}

// Round 8
// 555.438 us; speedup vs baseline: 1.7164x; 1.0267x over previous
//
#include <hip/hip_runtime.h>
#include <math.h>

constexpr int N  = 60000;
constexpr int F  = 256;
constexpr int H  = 128;
constexpr int C  = 256;
constexpr int E  = 600000;
constexpr int ET = 1500;
constexpr int NB = (N + 1023) / 1024;  // 59 scan blocks
constexpr int SPL = 8;                 // bu softmax splits per cluster

typedef __attribute__((ext_vector_type(8))) short short8;
typedef __attribute__((ext_vector_type(4))) float f32x4;

__device__ __forceinline__ unsigned short f2b(float f) {  // fp32 -> bf16 (RNE)
  unsigned int u = __float_as_uint(f);
  return (unsigned short)((u + 0x7FFFu + ((u >> 16) & 1u)) >> 16);
}
__device__ __forceinline__ float b2f(unsigned short b) {
  return __uint_as_float(((unsigned int)b) << 16);
}

// ---------------- histograms (cell-dst degree + cluster counts) ----------------
__global__ void hg_hist(const int* __restrict__ cdst, int* __restrict__ deg,
                        const int* __restrict__ lab, int* __restrict__ ccnt) {
  int e = blockIdx.x * 256 + threadIdx.x;
  if (e < E) atomicAdd(&deg[cdst[e]], 1);
  if (e < N) atomicAdd(&ccnt[lab[e]], 1);
}

// ---------------- multi-block scan ----------------
__global__ __launch_bounds__(256) void hg_scan1(const int* __restrict__ deg, int* __restrict__ off,
                                                int* __restrict__ btot, int n) {
  int b = blockIdx.x, t = threadIdx.x;
  int i0 = b * 1024 + t * 4;
  __shared__ int sums[256];
  int d0 = 0, d1 = 0, d2 = 0, d3 = 0;
  if (i0 + 3 < n) {
    int4 dd = *(const int4*)&deg[i0];
    d0 = dd.x; d1 = dd.y; d2 = dd.z; d3 = dd.w;
  } else {
    if (i0     < n) d0 = deg[i0];
    if (i0 + 1 < n) d1 = deg[i0 + 1];
    if (i0 + 2 < n) d2 = deg[i0 + 2];
    if (i0 + 3 < n) d3 = deg[i0 + 3];
  }
  int s = d0 + d1 + d2 + d3;
  sums[t] = s;
  __syncthreads();
  for (int ofs = 1; ofs < 256; ofs <<= 1) {
    int v = (t >= ofs) ? sums[t - ofs] : 0;
    __syncthreads();
    sums[t] += v;
    __syncthreads();
  }
  int excl = sums[t] - s;
  if (t == 255) btot[b] = sums[t];
  int run = excl;
  if (i0     < n) off[i0]     = run; run += d0;
  if (i0 + 1 < n) off[i0 + 1] = run; run += d1;
  if (i0 + 2 < n) off[i0 + 2] = run; run += d2;
  if (i0 + 3 < n) off[i0 + 3] = run;
}

// block0: scan of btot; block1: cluster-count scan; block2: tissue CSR + dinv
__global__ __launch_bounds__(256) void hg_scan2_setup(int* __restrict__ btot, int* __restrict__ off,
                                                      const int* __restrict__ ccnt, int* __restrict__ coff,
                                                      const int* __restrict__ tsrc, const int* __restrict__ tdst,
                                                      int* __restrict__ toff, int* __restrict__ tlist,
                                                      float* __restrict__ dinv) {
  __shared__ int sa[256], sb[256], sc2[256];
  int t = threadIdx.x;
  if (blockIdx.x == 0) {
    if (t < 64) sa[t] = (t < NB) ? btot[t] : 0;
    __syncthreads();
    if (t == 0) {
      int r = 0;
      for (int i = 0; i < NB; ++i) { int v = sa[i]; sa[i] = r; r += v; }
      off[N] = r;
    }
    __syncthreads();
    if (t < NB) btot[t] = sa[t];
  } else if (blockIdx.x == 1) {
    int v0 = ccnt[t];
    sa[t] = v0;
    __syncthreads();
    for (int ofs = 1; ofs < 256; ofs <<= 1) {
      int v = (t >= ofs) ? sa[t - ofs] : 0;
      __syncthreads();
      sa[t] += v;
      __syncthreads();
    }
    coff[t + 1] = sa[t];
    if (t == 0) coff[0] = 0;
  } else {
    sa[t] = 0;
    __syncthreads();
    for (int e = t; e < ET; e += 256) atomicAdd(&sa[tdst[e]], 1);
    __syncthreads();
    int v = sa[t];
    dinv[t] = rsqrtf((float)(v + 1));
    sb[t] = v;
    __syncthreads();
    for (int ofs = 1; ofs < 256; ofs <<= 1) {
      int u = (t >= ofs) ? sb[t - ofs] : 0;
      __syncthreads();
      sb[t] += u;
      __syncthreads();
    }
    toff[t + 1] = sb[t];
    if (t == 0) toff[0] = 0;
    sc2[t] = sb[t] - v;
    __syncthreads();
    for (int e = t; e < ET; e += 256) {
      int d = tdst[e];
      int p = atomicAdd(&sc2[d], 1);
      tlist[p] = tsrc[e];
    }
  }
}

__global__ void hg_scan3(int* __restrict__ off, const int* __restrict__ btot, int n) {
  int b = blockIdx.x;
  int addv = btot[b];
  int i0 = b * 1024 + threadIdx.x * 4;
#pragma unroll
  for (int r = 0; r < 4; ++r)
    if (i0 + r < n) off[i0 + r] += addv;
}

// merged: cell-edge CSR scatter + cluster-list scatter
__global__ void hg_scatter(const int* __restrict__ csrc, const int* __restrict__ cdst,
                           const int* __restrict__ off, int* __restrict__ cur, int* __restrict__ csr,
                           const int* __restrict__ lab, const int* __restrict__ coff,
                           int* __restrict__ ccur, int* __restrict__ list) {
  int e = blockIdx.x * 256 + threadIdx.x;
  if (e < E) {
    int d = cdst[e];
    int p = atomicAdd(&cur[d], 1);
    csr[off[d] + p] = csrc[e];
  }
  if (e < N) {
    int c = lab[e];
    int p = atomicAdd(&ccur[c], 1);
    list[coff[c] + p] = e;
  }
}

// ---------------- prep: 8 transposes + pc0(bf16) + pc1 (grid y = job) ----------------
struct TJob { const float* src; float* dst; int SR; int SC; int dld; };
struct PrepArgs {
  TJob j[8];
  const float* gatW1; const float* Wcp; const float* bcp; short* Wcompb; float* bcomp;
  const float* tdWo; const float* tdWv; const float* tdbv; const float* tdbo;
  float* A_td; float* Wcat_t; float* bcat;
};

__global__ __launch_bounds__(256) void hg_prep1(PrepArgs a) {
  int y = blockIdx.y, t = threadIdx.x;
  if (y < 8) {
    TJob jb = a.j[y];
    int total = jb.SR * jb.SC;
    for (int idx = blockIdx.x * 256 + t; idx < total; idx += gridDim.x * 256) {
      int r = idx / jb.SC, c = idx - r * jb.SC;
      jb.dst[(size_t)c * jb.dld + r] = jb.src[idx];
    }
  } else if (y == 8) {
    // pc0: Wcomp[j][k] = sum_m gatW1[j][m]*Wcp[m][k]  (bf16, j-major for MFMA B frags)
    int j = blockIdx.x, k = t;
    float acc = 0.f;
#pragma unroll 4
    for (int m = 0; m < 128; ++m) acc = fmaf(a.gatW1[j * 128 + m], a.Wcp[m * 256 + k], acc);
    a.Wcompb[(size_t)j * 256 + k] = (short)f2b(acc);
    if (k == 0) {
      float b = 0.f;
      for (int m = 0; m < 128; ++m) b = fmaf(a.gatW1[j * 128 + m], a.bcp[m], b);
      a.bcomp[j] = b;
    }
  } else if (blockIdx.x < 64) {
    int j = blockIdx.x * 2 + (t >> 7), k = t & 127;
    float acc = 0.f;
#pragma unroll 4
    for (int p = 0; p < 128; ++p) acc = fmaf(a.tdWo[j * 128 + p], a.tdWv[p * 128 + k], acc);
    a.A_td[j * 128 + k] = acc;
    a.Wcat_t[k * 896 + j] = acc;
    if (k == 0) {
      float b = 0.f;
      for (int p = 0; p < 128; ++p) b = fmaf(a.tdWo[j * 128 + p], a.tdbv[p], b);
      a.bcat[j] = b + a.tdbo[j];
    }
  }
}

__global__ __launch_bounds__(256) void hg_pc2b(const float* __restrict__ Wih, const float* __restrict__ bih,
                                               const float* __restrict__ Whh, const float* __restrict__ bhh,
                                               const float* __restrict__ A_td, float* __restrict__ Wcat_t,
                                               float* __restrict__ bcat) {
  int jj = blockIdx.x * 2 + (threadIdx.x >> 7), k = threadIdx.x & 127;
  const float* coef;
  float extra, bb;
  int dcol, j;
  if (jj < 384) {
    j = jj; coef = Wih + (size_t)j * 256; extra = Wih[(size_t)j * 256 + 128 + k]; dcol = 128 + j; bb = bih[j];
  } else {
    j = jj - 384; coef = Whh + (size_t)j * 128; extra = 0.f; dcol = 512 + j; bb = bhh[j];
  }
  float a = 0.f;
#pragma unroll 4
  for (int m = 0; m < 128; ++m) a = fmaf(coef[m], A_td[m * 128 + k], a);
  Wcat_t[k * 896 + dcol] = a + extra;
  if (k == 0) {
    float b = 0.f;
    for (int m = 0; m < 128; ++m) b = fmaf(coef[m], bcat[m], b);
    bcat[dcol] = b + bb;
  }
}

// ---------------- MFMA bf16 GEMM (K=256, tile 128x128, no LDS) + GAT-coef epilogue ----------------
__global__ __launch_bounds__(256, 2) void hg_gemm_coef(
    const float* __restrict__ A, int M, int rtiles,
    const short* __restrict__ Wb,          // bf16 [128][256] j-major
    const float* __restrict__ bias,
    unsigned short* __restrict__ outp,     // bf16 [M][128]
    const float* __restrict__ avs, const float* __restrict__ avd,
    float* __restrict__ o_s, float* __restrict__ o_d,
    const int* __restrict__ list, const int* __restrict__ coff,
    const float* __restrict__ Wtpt, const float* __restrict__ btp, float* __restrict__ tish) {
  __shared__ float mrow[256];
  const int t = threadIdx.x;

  if (blockIdx.x >= rtiles) {
    // ---- tissue init: per-cluster mean + projection (fp32) ----
    int c = blockIdx.x - rtiles;
    int s0 = coff[c], n = coff[c + 1] - s0;
    float acc = 0.f;
#pragma unroll 4
    for (int i = 0; i < n; ++i) acc += A[(size_t)list[s0 + i] * F + t];
    mrow[t] = acc / fmaxf((float)n, 1.f);
    __syncthreads();
    if (t < 128) {
      float a = btp[t];
#pragma unroll 4
      for (int k = 0; k < 256; ++k) a = fmaf(mrow[k], Wtpt[k * 128 + t], a);
      tish[c * 128 + t] = a;
    }
    return;
  }

  const int w = t >> 6, l = t & 63;
  const int li = l & 15, lk = l >> 4;   // li: row/col within 16-tile, lk: k-group
  const int m0 = blockIdx.x * 128 + w * 32;

  f32x4 zero = {0.f, 0.f, 0.f, 0.f};
  f32x4 acc[2][8];
#pragma unroll
  for (int rt = 0; rt < 2; ++rt)
#pragma unroll
    for (int ct = 0; ct < 8; ++ct) acc[rt][ct] = zero;

  const int r0 = m0 + li, r1 = m0 + 16 + li;
  const bool v0 = r0 < M, v1 = r1 < M;
  const float* a0p = A + (size_t)r0 * 256 + lk * 8;
  const float* a1p = A + (size_t)r1 * 256 + lk * 8;

  for (int kc = 0; kc < 256; kc += 32) {
    short8 bf[8];
#pragma unroll
    for (int ct = 0; ct < 8; ++ct)
      bf[ct] = *(const short8*)&Wb[(size_t)(ct * 16 + li) * 256 + kc + lk * 8];
    short8 af0 = {0, 0, 0, 0, 0, 0, 0, 0};
    short8 af1 = {0, 0, 0, 0, 0, 0, 0, 0};
    if (v0) {
      float4 x = *(const float4*)(a0p + kc);
      float4 y = *(const float4*)(a0p + kc + 4);
      af0[0] = (short)f2b(x.x); af0[1] = (short)f2b(x.y); af0[2] = (short)f2b(x.z); af0[3] = (short)f2b(x.w);
      af0[4] = (short)f2b(y.x); af0[5] = (short)f2b(y.y); af0[6] = (short)f2b(y.z); af0[7] = (short)f2b(y.w);
    }
    if (v1) {
      float4 x = *(const float4*)(a1p + kc);
      float4 y = *(const float4*)(a1p + kc + 4);
      af1[0] = (short)f2b(x.x); af1[1] = (short)f2b(x.y); af1[2] = (short)f2b(x.z); af1[3] = (short)f2b(x.w);
      af1[4] = (short)f2b(y.x); af1[5] = (short)f2b(y.y); af1[6] = (short)f2b(y.z); af1[7] = (short)f2b(y.w);
    }
#pragma unroll
    for (int ct = 0; ct < 8; ++ct) {
      acc[0][ct] = __builtin_amdgcn_mfma_f32_16x16x32_bf16(af0, bf[ct], acc[0][ct], 0, 0, 0);
      acc[1][ct] = __builtin_amdgcn_mfma_f32_16x16x32_bf16(af1, bf[ct], acc[1][ct], 0, 0, 0);
    }
  }

  // epilogue: bias, bf16 store, per-head coef dots (o_s/o_d)
#pragma unroll
  for (int ct = 0; ct < 8; ++ct) {
    float bj = bias[ct * 16 + li];
    float as = avs[ct * 16 + li];
    float ad = avd[ct * 16 + li];
#pragma unroll
    for (int rt = 0; rt < 2; ++rt) {
#pragma unroll
      for (int r = 0; r < 4; ++r) {
        int gm = m0 + rt * 16 + lk * 4 + r;
        float v = acc[rt][ct][r] + bj;
        if (gm < M) outp[(size_t)gm * 128 + ct * 16 + li] = f2b(v);
        float ps = v * as, pd = v * ad;
        ps += __shfl_xor(ps, 1); ps += __shfl_xor(ps, 2); ps += __shfl_xor(ps, 4); ps += __shfl_xor(ps, 8);
        pd += __shfl_xor(pd, 1); pd += __shfl_xor(pd, 2); pd += __shfl_xor(pd, 4); pd += __shfl_xor(pd, 8);
        if (li == 0 && gm < M) {
          o_s[(size_t)gm * 8 + ct] = ps;
          o_d[(size_t)gm * 8 + ct] = pd;
        }
      }
    }
  }
}

// ---------------- GAT aggregation: one WAVE per node, bf16 gathers ----------------
#define GMAXE 64
__global__ __launch_bounds__(256) void hg_gat_agg(
    const unsigned short* __restrict__ hproj, const float* __restrict__ a_s,
    const float* __restrict__ a_d, const int* __restrict__ remap,
    const int* __restrict__ off, const int* __restrict__ csr,
    const float* __restrict__ bias, unsigned short* __restrict__ outh,
    const float* __restrict__ qk, const float* __restrict__ qb,
    const int* __restrict__ lab, const int* __restrict__ nodelist,
    float* __restrict__ satt, int nNodes) {
  const int wid = threadIdx.x >> 6;
  const int l = threadIdx.x & 63;
  const int gid = blockIdx.x * 4 + wid;
  __shared__ int srcs_s[4][GMAXE];
  __shared__ float w_s[4][GMAXE][8];
  if (gid >= nNodes) return;
  const int node = nodelist[gid];
  int* srcs = srcs_s[wid];
  float (*wls)[8] = w_s[wid];
  const int o0 = off[node], deg = off[node + 1] - o0;
  const int cl = lab[node];
  const int dl = remap ? cl : node;
  const int hsc = l & 7;
  const int q4 = l & 31;
  const int sub = l >> 5;
  const int hq = q4 >> 2;
  const float adh = a_d[dl * 8 + hsc];
  const float ash = a_s[dl * 8 + hsc];
  float msc = -INFINITY, zsc = 0.f;
  float4 acc = make_float4(0.f, 0.f, 0.f, 0.f);
  const ushort4* hp4 = (const ushort4*)hproj;  // 4 bf16 per element

  for (int cb = 0; cb < deg; cb += GMAXE) {
    const int len = min(GMAXE, deg - cb);
    if (l < len) {
      int s = csr[o0 + cb + l];
      srcs[l] = remap ? remap[s] : s;
    }
    asm volatile("s_waitcnt lgkmcnt(0)" ::: "memory");
    float lm = -INFINITY;
    for (int base = 0; base < len; base += 8) {
      int e = base + (l >> 3);
      if (e < len) {
        float sc = a_s[srcs[e] * 8 + hsc] + adh;
        sc = sc > 0.f ? sc : 0.2f * sc;
        wls[e][hsc] = sc;
        lm = fmaxf(lm, sc);
      }
    }
    lm = fmaxf(lm, __shfl_xor(lm, 8));
    lm = fmaxf(lm, __shfl_xor(lm, 16));
    lm = fmaxf(lm, __shfl_xor(lm, 32));
    float mnew = fmaxf(msc, lm);
    float rs = __expf(msc - mnew);
    float zc = 0.f;
    asm volatile("s_waitcnt lgkmcnt(0)" ::: "memory");
    for (int base = 0; base < len; base += 8) {
      int e = base + (l >> 3);
      if (e < len) {
        float wv = __expf(wls[e][hsc] - mnew);
        wls[e][hsc] = wv;
        zc += wv;
      }
    }
    asm volatile("s_waitcnt lgkmcnt(0)" ::: "memory");
    zc += __shfl_xor(zc, 8); zc += __shfl_xor(zc, 16); zc += __shfl_xor(zc, 32);
    zsc = zsc * rs + zc;
    msc = mnew;
    float rsa = __shfl(rs, hq);
    acc.x *= rsa; acc.y *= rsa; acc.z *= rsa; acc.w *= rsa;
    for (int e = sub; e < len; e += 2) {
      float wv = wls[e][hq];
      ushort4 hv = hp4[(size_t)srcs[e] * 32 + q4];
      acc.x = fmaf(wv, b2f(hv.x), acc.x);
      acc.y = fmaf(wv, b2f(hv.y), acc.y);
      acc.z = fmaf(wv, b2f(hv.z), acc.z);
      acc.w = fmaf(wv, b2f(hv.w), acc.w);
    }
  }
  float ssl = ash + adh;
  ssl = ssl > 0.f ? ssl : 0.2f * ssl;
  float mnew = fmaxf(msc, ssl);
  float rs = __expf(msc - mnew);
  float wsl = __expf(ssl - mnew);
  zsc = zsc * rs + wsl;
  float rsa = __shfl(rs, hq);
  float wsa = __shfl(wsl, hq);
  float zh = __shfl(zsc, hq);
  acc.x *= rsa; acc.y *= rsa; acc.z *= rsa; acc.w *= rsa;
  acc.x += __shfl_xor(acc.x, 32);
  acc.y += __shfl_xor(acc.y, 32);
  acc.z += __shfl_xor(acc.z, 32);
  acc.w += __shfl_xor(acc.w, 32);
  ushort4 hvs = hp4[(size_t)dl * 32 + q4];
  acc.x = fmaf(wsa, b2f(hvs.x), acc.x);
  acc.y = fmaf(wsa, b2f(hvs.y), acc.y);
  acc.z = fmaf(wsa, b2f(hvs.z), acc.z);
  acc.w = fmaf(wsa, b2f(hvs.w), acc.w);
  float inv = 1.f / zh;
  float4 bv4 = *(const float4*)&bias[q4 * 4];
  float4 o;
  o.x = acc.x * inv + bv4.x;
  o.y = acc.y * inv + bv4.y;
  o.z = acc.z * inv + bv4.z;
  o.w = acc.w * inv + bv4.w;
  o.x = o.x > 0.f ? o.x : __expf(o.x) - 1.f;
  o.y = o.y > 0.f ? o.y : __expf(o.y) - 1.f;
  o.z = o.z > 0.f ? o.z : __expf(o.z) - 1.f;
  o.w = o.w > 0.f ? o.w : __expf(o.w) - 1.f;
  if (sub == 0) {
    ushort4 ov = make_ushort4(f2b(o.x), f2b(o.y), f2b(o.z), f2b(o.w));
    ((ushort4*)outh)[(size_t)node * 32 + q4] = ov;
  }

  // s_att epilogue (qk L2-hot via clu_list ordering)
  const float4* qk4 = (const float4*)(qk + (size_t)cl * 1024);
  float p0, p1, p2, p3;
  {
    float4 qv0 = qk4[(sub * 4 + 0) * 32 + q4];
    float4 qv1 = qk4[(sub * 4 + 1) * 32 + q4];
    float4 qv2 = qk4[(sub * 4 + 2) * 32 + q4];
    float4 qv3 = qk4[(sub * 4 + 3) * 32 + q4];
    p0 = o.x * qv0.x + o.y * qv0.y + o.z * qv0.z + o.w * qv0.w;
    p1 = o.x * qv1.x + o.y * qv1.y + o.z * qv1.z + o.w * qv1.w;
    p2 = o.x * qv2.x + o.y * qv2.y + o.z * qv2.z + o.w * qv2.w;
    p3 = o.x * qv3.x + o.y * qv3.y + o.z * qv3.z + o.w * qv3.w;
  }
  int b4f = (l >> 4) & 1, b3f = (l >> 3) & 1;
  float snd0 = b4f ? p0 : p2, snd1 = b4f ? p1 : p3;
  float kp0  = b4f ? p2 : p0, kp1  = b4f ? p3 : p1;
  kp0 += __shfl_xor(snd0, 16);
  kp1 += __shfl_xor(snd1, 16);
  float snd = b3f ? kp0 : kp1;
  float kp  = b3f ? kp1 : kp0;
  kp += __shfl_xor(snd, 8);
  kp += __shfl_xor(kp, 4);
  kp += __shfl_xor(kp, 2);
  kp += __shfl_xor(kp, 1);
  int h = sub * 4 + b4f * 2 + b3f;
  if ((l & 7) == 0) satt[(size_t)node * 8 + h] = kp + qb[cl * 8 + h];
}

// ---------------- tissue GCN + q projection + qk/qb tables ----------------
__global__ __launch_bounds__(128) void hg_gcn_q(const float* __restrict__ tin, const int* __restrict__ toff,
                                                const int* __restrict__ tlist, const float* __restrict__ dinv,
                                                const float* __restrict__ gt, const float* __restrict__ gcnb,
                                                const float* __restrict__ Wqt, const float* __restrict__ bq,
                                                const float* __restrict__ Wk, const float* __restrict__ bk,
                                                float* __restrict__ qk, float* __restrict__ qb) {
  int c = blockIdx.x, t = threadIdx.x;
  __shared__ float xa[128], trow[128], qrow[128];
  float dc = dinv[c];
  float acc = tin[c * 128 + t] * dc * dc;
  int s0 = toff[c], s1 = toff[c + 1];
  for (int i = s0; i < s1; ++i) {
    int s = tlist[i];
    acc = fmaf(tin[s * 128 + t], dinv[s] * dc, acc);
  }
  xa[t] = acc;
  __syncthreads();
  float th = 0.f;
#pragma unroll 4
  for (int k = 0; k < 128; ++k) th = fmaf(xa[k], gt[k * 128 + t], th);
  float vv = fmaxf(th + gcnb[t], 0.f);
  trow[t] = vv;
  __syncthreads();
  float qa = bq[t];
#pragma unroll 4
  for (int k = 0; k < 128; ++k) qa = fmaf(trow[k], Wqt[k * 128 + t], qa);
  qrow[t] = qa * 0.25f;  // 1/sqrt(DH)
  __syncthreads();
#pragma unroll
  for (int h = 0; h < 8; ++h) {
    float s = 0.f;
#pragma unroll
    for (int j = 0; j < 16; ++j) s = fmaf(Wk[(size_t)(h * 16 + j) * 128 + t], qrow[h * 16 + j], s);
    qk[((size_t)c * 8 + h) * 128 + t] = s;
  }
  if (t < 8) {
    float s = 0.f;
#pragma unroll
    for (int j = 0; j < 16; ++j) s = fmaf(qrow[t * 16 + j], bk[t * 16 + j], s);
    qb[c * 8 + t] = s;
  }
}

// ---------------- bu softmax partials: grid (C, SPL), bf16 gathers ----------------
__global__ __launch_bounds__(256) void hg_bu_part(
    const float* __restrict__ s_att, const unsigned short* __restrict__ hcell,
    const int* __restrict__ list, const int* __restrict__ coff,
    float* __restrict__ pm, float* __restrict__ pz, float* __restrict__ pmacc) {
  int c = blockIdx.x, sp = blockIdx.y, t = threadIdx.x;
  int s0 = coff[c], n = coff[c + 1] - s0;
  int chunk = (n + SPL - 1) / SPL;
  int b0 = min(n, sp * chunk), b1 = min(n, b0 + chunk);
  int cnt = b1 - b0;
  int tf = t & 127, half = t >> 7;
  __shared__ float red[32][8];
  __shared__ float mh[8];
  __shared__ int cells[64];
  __shared__ float wl[64][8];
  __shared__ float msh[8][128];
  int g = t >> 3, h8 = t & 7;
  float lm = -INFINITY;
  for (int i = g; i < cnt; i += 32) lm = fmaxf(lm, s_att[(size_t)list[s0 + b0 + i] * 8 + h8]);
  red[g][h8] = lm;
  __syncthreads();
  if (t < 8) {
    float m2 = -INFINITY;
#pragma unroll
    for (int i = 0; i < 32; ++i) m2 = fmaxf(m2, red[i][t]);
    mh[t] = m2;
  }
  __syncthreads();
  const float mloc = mh[t & 7];
  float zp = 0.f;
  float macc[8] = {0.f, 0.f, 0.f, 0.f, 0.f, 0.f, 0.f, 0.f};
  for (int cb = 0; cb < cnt; cb += 64) {
    int len = min(64, cnt - cb);
    if (t < len) cells[t] = list[s0 + b0 + cb + t];
    __syncthreads();
#pragma unroll
    for (int p = 0; p < 2; ++p) {
      int e = p * 32 + (t >> 3);
      if (e < len) {
        float w = __expf(s_att[(size_t)cells[e] * 8 + (t & 7)] - mloc);
        wl[e][t & 7] = w;
        zp += w;
      }
    }
    __syncthreads();
    for (int e = half; e < len; e += 2) {
      float x = b2f(hcell[(size_t)cells[e] * 128 + tf]);
      float4 w0 = *(const float4*)&wl[e][0];
      float4 w1 = *(const float4*)&wl[e][4];
      macc[0] = fmaf(w0.x, x, macc[0]);
      macc[1] = fmaf(w0.y, x, macc[1]);
      macc[2] = fmaf(w0.z, x, macc[2]);
      macc[3] = fmaf(w0.w, x, macc[3]);
      macc[4] = fmaf(w1.x, x, macc[4]);
      macc[5] = fmaf(w1.y, x, macc[5]);
      macc[6] = fmaf(w1.z, x, macc[6]);
      macc[7] = fmaf(w1.w, x, macc[7]);
    }
    __syncthreads();
  }
  red[t >> 3][t & 7] = zp;
  __syncthreads();
  int pidx = (c * SPL + sp) * 8;
  if (t < 8) {
    float z = 0.f;
#pragma unroll
    for (int i = 0; i < 32; ++i) z += red[i][t];
    pz[pidx + t] = z;
    pm[pidx + t] = mh[t];
  }
  if (half) {
#pragma unroll
    for (int h = 0; h < 8; ++h) msh[h][tf] = macc[h];
  }
  __syncthreads();
  if (!half) {
#pragma unroll
    for (int h = 0; h < 8; ++h) pmacc[(size_t)(pidx + h) * 128 + tf] = macc[h] + msh[h][tf];
  }
}

// ---------------- fused cluster chain: merge partials, Wv, Wo, td+GRU, gates, next GAT proj ----------------
__global__ __launch_bounds__(256) void hg_bu_chain(
    const float* __restrict__ pm, const float* __restrict__ pz, const float* __restrict__ pmacc,
    const float* __restrict__ Wv, const float* __restrict__ bv,
    const float* __restrict__ Wot, const float* __restrict__ bo,
    const float* __restrict__ Wcat_t, const float* __restrict__ bcat,
    const float* __restrict__ gatWt, const float* __restrict__ avs, const float* __restrict__ avd,
    float* __restrict__ tish, float* __restrict__ ccell,
    unsigned short* __restrict__ hprojc, float* __restrict__ a_s2, float* __restrict__ a_d2) {
  int c = blockIdx.x, t = threadIdx.x;
  int tf = t & 127, half = t >> 7;
  __shared__ float mh[8], zh[8];
  __shared__ float sscale[SPL][8];
  __shared__ float msh[8][128];
  __shared__ float b0[128], b1[128], part[2][128], catv[896];
  const int pbase = c * SPL * 8;
  if (t < 8) {
    float mg = -INFINITY;
#pragma unroll
    for (int s = 0; s < SPL; ++s) mg = fmaxf(mg, pm[pbase + s * 8 + t]);
    mh[t] = mg;
  }
  __syncthreads();
  if (t < SPL * 8) {
    int s = t >> 3, h = t & 7;
    float ms = pm[pbase + s * 8 + h];
    sscale[s][h] = (ms > -1e37f) ? __expf(ms - mh[h]) : 0.f;
  }
  __syncthreads();
  if (t < 8) {
    float z = 0.f;
#pragma unroll
    for (int s = 0; s < SPL; ++s) z += pz[pbase + s * 8 + t] * sscale[s][t];
    zh[t] = (z > 0.f) ? 1.f / z : 0.f;
  }
  __syncthreads();
#pragma unroll
  for (int hh = 0; hh < 4; ++hh) {
    int h = half * 4 + hh;
    float a = 0.f;
#pragma unroll
    for (int s = 0; s < SPL; ++s)
      a = fmaf(pmacc[(size_t)(pbase + s * 8 + h) * 128 + tf], sscale[s][h], a);
    msh[h][tf] = a * zh[h];
  }
  __syncthreads();
  {
    int h = tf >> 4;
    float ps = 0.f;
    const float* wp = Wv + (size_t)tf * 128 + half * 64;
    const float* mp = &msh[h][half * 64];
#pragma unroll 4
    for (int k = 0; k < 64; ++k) ps = fmaf(wp[k], mp[k], ps);
    part[half][tf] = ps;
  }
  __syncthreads();
  if (t < 128) b0[t] = part[0][t] + part[1][t] + bv[t];
  __syncthreads();
  int ks = half;
  {
    float ps = 0.f;
    const float* wp = Wot + (size_t)ks * 64 * 128 + tf;
#pragma unroll 4
    for (int k = 0; k < 64; ++k) ps = fmaf(b0[ks * 64 + k], wp[k * 128], ps);
    part[ks][tf] = ps;
  }
  __syncthreads();
  if (t < 128) {
    float vv = part[0][t] + part[1][t] + bo[t];
    b1[t] = vv;
    tish[c * 128 + t] = vv;
  }
  __syncthreads();
  for (int j = t; j < 896; j += 256) {
    float a = bcat[j];
#pragma unroll 4
    for (int k = 0; k < 128; ++k) a = fmaf(b1[k], Wcat_t[k * 896 + j], a);
    catv[j] = a;
  }
  __syncthreads();
  if (t < 128) {
    float td = catv[t];
    float r = 1.f / (1.f + expf(-(catv[128 + t] + catv[512 + t])));
    float zz = 1.f / (1.f + expf(-(catv[256 + t] + catv[640 + t])));
    float nn = tanhf(catv[384 + t] + r * catv[768 + t]);
    float cn = (1.f - zz) * nn + zz * td;
    ccell[c * 128 + t] = cn;
    b0[t] = cn;
  }
  __syncthreads();
  if (gatWt) {
    float ps = 0.f;
    const float* wp = gatWt + (size_t)ks * 64 * 128 + tf;
#pragma unroll 4
    for (int k = 0; k < 64; ++k) ps = fmaf(b0[ks * 64 + k], wp[k * 128], ps);
    part[ks][tf] = ps;
    __syncthreads();
    if (t < 128) {
      float hp = part[0][t] + part[1][t];
      hprojc[c * 128 + t] = f2b(hp);
      float pss = hp * avs[t], pdd = hp * avd[t];
      pss += __shfl_xor(pss, 1); pss += __shfl_xor(pss, 2); pss += __shfl_xor(pss, 4); pss += __shfl_xor(pss, 8);
      pdd += __shfl_xor(pdd, 1); pdd += __shfl_xor(pdd, 2); pdd += __shfl_xor(pdd, 4); pdd += __shfl_xor(pdd, 8);
      if ((t & 15) == 0) {
        a_s2[c * 8 + (t >> 4)] = pss;
        a_d2[c * 8 + (t >> 4)] = pdd;
      }
    }
  }
}

// ---------------- readout + classifier ----------------
__global__ __launch_bounds__(256) void hg_readout(const float* __restrict__ ccell2, const float* __restrict__ tish,
                                                  const int* __restrict__ cnt, const float* __restrict__ Wc1t,
                                                  const float* __restrict__ bc1, const float* __restrict__ Wc2t,
                                                  const float* __restrict__ bc2, const float* __restrict__ Wc3,
                                                  const float* __restrict__ bc3, float* __restrict__ outp) {
  __shared__ float emb[512], h1s[256], h2s[128];
  int t = threadIdx.x;
  if (t < 128) {
    float sm = 0.f, mx = -INFINITY;
    for (int c = 0; c < C; ++c) {
      float vv = ccell2[c * 128 + t];
      int n = cnt[c];
      sm += (float)n * vv;
      if (n > 0) mx = fmaxf(mx, vv);
    }
    emb[t] = sm / (float)N;
    emb[128 + t] = mx;
  } else {
    int tt = t - 128;
    float sm = 0.f, mx = -INFINITY;
    for (int c = 0; c < C; ++c) {
      float vv = tish[c * 128 + tt];
      sm += vv;
      mx = fmaxf(mx, vv);
    }
    emb[256 + tt] = sm * (1.f / (float)C);
    emb[384 + tt] = mx;
  }
  __syncthreads();
  float a = bc1[t];
#pragma unroll 4
  for (int kk = 0; kk < 512; ++kk) a = fmaf(emb[kk], Wc1t[kk * 256 + t], a);
  h1s[t] = fmaxf(a, 0.f);
  __syncthreads();
  if (t < 128) {
    float a2 = bc2[t];
#pragma unroll 4
    for (int kk = 0; kk < 256; ++kk) a2 = fmaf(h1s[kk], Wc2t[kk * 128 + t], a2);
    h2s[t] = fmaxf(a2, 0.f);
  }
  __syncthreads();
  if (t < 4) {
    float o = bc3[t];
    for (int kk = 0; kk < 128; ++kk) o = fmaf(h2s[kk], Wc3[t * 128 + kk], o);
    outp[t] = o;
  }
}

// ---------------- host launcher ----------------
extern "C" void kernel_launch(void* const* d_in, const int* in_sizes, int n_in,
                              void* d_out, int out_size, void* d_ws, size_t ws_size,
                              hipStream_t stream) {
  (void)in_sizes; (void)n_in; (void)out_size; (void)ws_size;
  const float* feat  = (const float*)d_in[0];
  const int*   eidx  = (const int*)d_in[1];
  const int*   lab   = (const int*)d_in[2];
  const int*   tidx  = (const int*)d_in[3];
  const float* Wcp   = (const float*)d_in[4];
  const float* bcp   = (const float*)d_in[5];
  const float* Wtp   = (const float*)d_in[6];
  const float* btp   = (const float*)d_in[7];
  const float* gatW  = (const float*)d_in[8];
  const float* gasrc = (const float*)d_in[9];
  const float* gadst = (const float*)d_in[10];
  const float* gatb  = (const float*)d_in[11];
  const float* gcnW  = (const float*)d_in[12];
  const float* gcnb  = (const float*)d_in[13];
  const float* buWq  = (const float*)d_in[14];
  const float* buWk  = (const float*)d_in[15];
  const float* buWv  = (const float*)d_in[16];
  const float* bubq  = (const float*)d_in[17];
  const float* bubk  = (const float*)d_in[18];
  const float* bubv  = (const float*)d_in[19];
  const float* buWo  = (const float*)d_in[20];
  const float* bubo  = (const float*)d_in[21];
  const float* tdWv  = (const float*)d_in[22];
  const float* tdbv  = (const float*)d_in[23];
  const float* tdWo  = (const float*)d_in[24];
  const float* tdbo  = (const float*)d_in[25];
  const float* Wih   = (const float*)d_in[26];
  const float* bih   = (const float*)d_in[27];
  const float* Whh   = (const float*)d_in[28];
  const float* bhh   = (const float*)d_in[29];
  const float* Wc1   = (const float*)d_in[30];
  const float* bc1   = (const float*)d_in[31];
  const float* Wc2   = (const float*)d_in[32];
  const float* bc2   = (const float*)d_in[33];
  const float* Wc3   = (const float*)d_in[34];
  const float* bc3   = (const float*)d_in[35];
  float* outp = (float*)d_out;

  const int* csrc = eidx;
  const int* cdst = eidx + E;
  const int* tsrc = tidx;
  const int* tdst = tidx + ET;

  char* w = (char*)d_ws;
  auto alloc = [&](size_t bytes) -> void* {
    void* p = (void*)w;
    w += (bytes + 255) & ~(size_t)255;
    return p;
  };
  char* cnt0 = w;
  int* deg_cell = (int*)alloc((size_t)N * 4);
  int* cur_cell = (int*)alloc((size_t)N * 4);
  int* clu_cnt  = (int*)alloc((size_t)C * 4);
  int* clu_cur  = (int*)alloc((size_t)C * 4);
  size_t cntBytes = (size_t)(w - cnt0);
  int* off_cell = (int*)alloc((size_t)(N + 1) * 4);
  int* btot     = (int*)alloc(64 * 4);
  int* csr      = (int*)alloc((size_t)E * 4);
  int* clu_off  = (int*)alloc((size_t)(C + 1) * 4);
  int* clu_list = (int*)alloc((size_t)N * 4);
  int* toff     = (int*)alloc((size_t)(C + 1) * 4);
  int* tlist    = (int*)alloc((size_t)ET * 4);
  float* dinv   = (float*)alloc((size_t)C * 4);
  unsigned short* buf1 = (unsigned short*)alloc((size_t)N * 128 * 2);  // bf16 cell_h
  unsigned short* buf2 = (unsigned short*)alloc((size_t)N * 128 * 2);  // bf16 hproj
  float* a_s    = (float*)alloc((size_t)N * 8 * 4);
  float* a_d    = (float*)alloc((size_t)N * 8 * 4);
  float* s_att  = (float*)alloc((size_t)N * 8 * 4);
  float* tish   = (float*)alloc((size_t)C * 128 * 4);
  float* qkb    = (float*)alloc((size_t)C * 8 * 128 * 4);
  float* qbb    = (float*)alloc((size_t)C * 8 * 4);
  float* ccell  = (float*)alloc((size_t)C * 128 * 4);
  unsigned short* hprojc = (unsigned short*)alloc((size_t)C * 128 * 2);
  float* a_sc   = (float*)alloc((size_t)C * 8 * 4);
  float* a_dc   = (float*)alloc((size_t)C * 8 * 4);
  float* pm     = (float*)alloc((size_t)C * SPL * 8 * 4);
  float* pz     = (float*)alloc((size_t)C * SPL * 8 * 4);
  float* pmacc  = (float*)alloc((size_t)C * SPL * 8 * 128 * 4);
  float* A_td   = (float*)alloc(128 * 128 * 4);
  float* Wcat_t = (float*)alloc(128 * 896 * 4);
  float* bcat   = (float*)alloc(896 * 4);
  short* Wcompb = (short*)alloc(128 * 256 * 2);   // bf16 composite weight [j][k]
  float* bcomp  = (float*)alloc(128 * 4);
  float* Wtpt   = (float*)alloc(256 * 128 * 4);
  float* g1t    = (float*)alloc(128 * 128 * 4);
  float* g2t    = (float*)alloc(128 * 128 * 4);
  float* Wqt    = (float*)alloc(128 * 128 * 4);
  float* Wot    = (float*)alloc(128 * 128 * 4);
  float* gatW2t = (float*)alloc(128 * 128 * 4);
  float* Wc1t   = (float*)alloc(512 * 256 * 4);
  float* Wc2t   = (float*)alloc(256 * 128 * 4);

  hipMemsetAsync(cnt0, 0, cntBytes, stream);

  hg_hist<<<(E + 255) / 256, 256, 0, stream>>>(cdst, deg_cell, lab, clu_cnt);
  hg_scan1<<<NB, 256, 0, stream>>>(deg_cell, off_cell, btot, N);
  hg_scan2_setup<<<3, 256, 0, stream>>>(btot, off_cell, clu_cnt, clu_off, tsrc, tdst, toff, tlist, dinv);
  hg_scan3<<<NB, 256, 0, stream>>>(off_cell, btot, N);
  hg_scatter<<<(E + 255) / 256, 256, 0, stream>>>(csrc, cdst, off_cell, cur_cell, csr,
                                                  lab, clu_off, clu_cur, clu_list);

  PrepArgs pa;
  pa.j[0] = {Wtp,            Wtpt,   128, 256, 128};
  pa.j[1] = {gcnW,           g1t,    128, 128, 128};
  pa.j[2] = {gcnW + 128*128, g2t,    128, 128, 128};
  pa.j[3] = {buWq,           Wqt,    128, 128, 128};
  pa.j[4] = {buWo,           Wot,    128, 128, 128};
  pa.j[5] = {gatW + 128*128, gatW2t, 128, 128, 128};
  pa.j[6] = {Wc1,            Wc1t,   256, 512, 256};
  pa.j[7] = {Wc2,            Wc2t,   128, 256, 128};
  pa.gatW1 = gatW; pa.Wcp = Wcp; pa.bcp = bcp; pa.Wcompb = Wcompb; pa.bcomp = bcomp;
  pa.tdWo = tdWo; pa.tdWv = tdWv; pa.tdbv = tdbv; pa.tdbo = tdbo;
  pa.A_td = A_td; pa.Wcat_t = Wcat_t; pa.bcat = bcat;
  hg_prep1<<<dim3(128, 10), 256, 0, stream>>>(pa);
  hg_pc2b<<<384, 256, 0, stream>>>(Wih, bih, Whh, bhh, A_td, Wcat_t, bcat);

  const int RT = (N + 127) / 128;  // 469 row tiles
  hg_gemm_coef<<<RT + C, 256, 0, stream>>>(feat, N, RT, Wcompb, bcomp, buf2, gasrc, gadst, a_s, a_d,
                                           clu_list, clu_off, Wtpt, btp, tish);
  // ---- layer 1 ----
  hg_gcn_q<<<C, 128, 0, stream>>>(tish, toff, tlist, dinv, g1t, gcnb, Wqt, bubq, buWk, bubk, qkb, qbb);
  hg_gat_agg<<<(N + 3) / 4, 256, 0, stream>>>(buf2, a_s, a_d, nullptr, off_cell, csr, gatb, buf1,
                                              qkb, qbb, lab, clu_list, s_att, N);
  hg_bu_part<<<dim3(C, SPL), 256, 0, stream>>>(s_att, buf1, clu_list, clu_off, pm, pz, pmacc);
  hg_bu_chain<<<C, 256, 0, stream>>>(pm, pz, pmacc, buWv, bubv, Wot, bubo, Wcat_t, bcat,
                                     gatW2t, gasrc + 128, gadst + 128, tish, ccell, hprojc, a_sc, a_dc);
  // ---- layer 2 ----
  hg_gcn_q<<<C, 128, 0, stream>>>(tish, toff, tlist, dinv, g2t, gcnb + 128, Wqt, bubq, buWk, bubk, qkb, qbb);
  hg_gat_agg<<<(N + 3) / 4, 256, 0, stream>>>(hprojc, a_sc, a_dc, lab, off_cell, csr, gatb + 128, buf1,
                                              qkb, qbb, lab, clu_list, s_att, N);
  hg_bu_part<<<dim3(C, SPL), 256, 0, stream>>>(s_att, buf1, clu_list, clu_off, pm, pz, pmacc);
  hg_bu_chain<<<C, 256, 0, stream>>>(pm, pz, pmacc, buWv, bubv, Wot, bubo, Wcat_t, bcat,
                                     nullptr, nullptr, nullptr, tish, ccell, nullptr, nullptr, nullptr);

  hg_readout<<<1, 256, 0, stream>>>(ccell, tish, clu_cnt, Wc1t, bc1, Wc2t, bc2, Wc3, bc3, outp);
}

// Round 9
// 546.013 us; speedup vs baseline: 1.7460x; 1.0173x over previous
//
#include <hip/hip_runtime.h>
#include <math.h>

constexpr int N  = 60000;
constexpr int F  = 256;
constexpr int H  = 128;
constexpr int C  = 256;
constexpr int E  = 600000;
constexpr int ET = 1500;
constexpr int NB = (N + 1023) / 1024;  // 59 scan blocks
constexpr int SPL = 8;                 // bu softmax splits per cluster
constexpr int PB  = 16;                // pooling blocks

typedef __attribute__((ext_vector_type(8))) short short8;
typedef __attribute__((ext_vector_type(4))) float f32x4;

__device__ __forceinline__ unsigned short f2b(float f) {  // fp32 -> bf16 (RNE)
  unsigned int u = __float_as_uint(f);
  return (unsigned short)((u + 0x7FFFu + ((u >> 16) & 1u)) >> 16);
}
__device__ __forceinline__ float b2f(unsigned short b) {
  return __uint_as_float(((unsigned int)b) << 16);
}

// ---------------- histograms (cell-dst degree + cluster counts) ----------------
__global__ void hg_hist(const int* __restrict__ cdst, int* __restrict__ deg,
                        const int* __restrict__ lab, int* __restrict__ ccnt) {
  int e = blockIdx.x * 256 + threadIdx.x;
  if (e < E) atomicAdd(&deg[cdst[e]], 1);
  if (e < N) atomicAdd(&ccnt[lab[e]], 1);
}

// ---------------- multi-block scan ----------------
__global__ __launch_bounds__(256) void hg_scan1(const int* __restrict__ deg, int* __restrict__ off,
                                                int* __restrict__ btot, int n) {
  int b = blockIdx.x, t = threadIdx.x;
  int i0 = b * 1024 + t * 4;
  __shared__ int sums[256];
  int d0 = 0, d1 = 0, d2 = 0, d3 = 0;
  if (i0 + 3 < n) {
    int4 dd = *(const int4*)&deg[i0];
    d0 = dd.x; d1 = dd.y; d2 = dd.z; d3 = dd.w;
  } else {
    if (i0     < n) d0 = deg[i0];
    if (i0 + 1 < n) d1 = deg[i0 + 1];
    if (i0 + 2 < n) d2 = deg[i0 + 2];
    if (i0 + 3 < n) d3 = deg[i0 + 3];
  }
  int s = d0 + d1 + d2 + d3;
  sums[t] = s;
  __syncthreads();
  for (int ofs = 1; ofs < 256; ofs <<= 1) {
    int v = (t >= ofs) ? sums[t - ofs] : 0;
    __syncthreads();
    sums[t] += v;
    __syncthreads();
  }
  int excl = sums[t] - s;
  if (t == 255) btot[b] = sums[t];
  int run = excl;
  if (i0     < n) off[i0]     = run; run += d0;
  if (i0 + 1 < n) off[i0 + 1] = run; run += d1;
  if (i0 + 2 < n) off[i0 + 2] = run; run += d2;
  if (i0 + 3 < n) off[i0 + 3] = run;
}

// block0: scan of btot; block1: cluster-count scan; block2: tissue CSR + dinv
__global__ __launch_bounds__(256) void hg_scan2_setup(int* __restrict__ btot, int* __restrict__ off,
                                                      const int* __restrict__ ccnt, int* __restrict__ coff,
                                                      const int* __restrict__ tsrc, const int* __restrict__ tdst,
                                                      int* __restrict__ toff, int* __restrict__ tlist,
                                                      float* __restrict__ dinv) {
  __shared__ int sa[256], sb[256], sc2[256];
  int t = threadIdx.x;
  if (blockIdx.x == 0) {
    if (t < 64) sa[t] = (t < NB) ? btot[t] : 0;
    __syncthreads();
    if (t == 0) {
      int r = 0;
      for (int i = 0; i < NB; ++i) { int v = sa[i]; sa[i] = r; r += v; }
      off[N] = r;
    }
    __syncthreads();
    if (t < NB) btot[t] = sa[t];
  } else if (blockIdx.x == 1) {
    int v0 = ccnt[t];
    sa[t] = v0;
    __syncthreads();
    for (int ofs = 1; ofs < 256; ofs <<= 1) {
      int v = (t >= ofs) ? sa[t - ofs] : 0;
      __syncthreads();
      sa[t] += v;
      __syncthreads();
    }
    coff[t + 1] = sa[t];
    if (t == 0) coff[0] = 0;
  } else {
    sa[t] = 0;
    __syncthreads();
    for (int e = t; e < ET; e += 256) atomicAdd(&sa[tdst[e]], 1);
    __syncthreads();
    int v = sa[t];
    dinv[t] = rsqrtf((float)(v + 1));
    sb[t] = v;
    __syncthreads();
    for (int ofs = 1; ofs < 256; ofs <<= 1) {
      int u = (t >= ofs) ? sb[t - ofs] : 0;
      __syncthreads();
      sb[t] += u;
      __syncthreads();
    }
    toff[t + 1] = sb[t];
    if (t == 0) toff[0] = 0;
    sc2[t] = sb[t] - v;
    __syncthreads();
    for (int e = t; e < ET; e += 256) {
      int d = tdst[e];
      int p = atomicAdd(&sc2[d], 1);
      tlist[p] = tsrc[e];
    }
  }
}

__global__ void hg_scan3(int* __restrict__ off, const int* __restrict__ btot, int n) {
  int b = blockIdx.x;
  int addv = btot[b];
  int i0 = b * 1024 + threadIdx.x * 4;
#pragma unroll
  for (int r = 0; r < 4; ++r)
    if (i0 + r < n) off[i0 + r] += addv;
}

// merged: cell-edge CSR scatter + cluster-list scatter
__global__ void hg_scatter(const int* __restrict__ csrc, const int* __restrict__ cdst,
                           const int* __restrict__ off, int* __restrict__ cur, int* __restrict__ csr,
                           const int* __restrict__ lab, const int* __restrict__ coff,
                           int* __restrict__ ccur, int* __restrict__ list) {
  int e = blockIdx.x * 256 + threadIdx.x;
  if (e < E) {
    int d = cdst[e];
    int p = atomicAdd(&cur[d], 1);
    csr[off[d] + p] = csrc[e];
  }
  if (e < N) {
    int c = lab[e];
    int p = atomicAdd(&ccur[c], 1);
    list[coff[c] + p] = e;
  }
}

// ---------------- prep: 8 transposes + pc0(bf16) + pc1 (grid y = job) ----------------
struct TJob { const float* src; float* dst; int SR; int SC; int dld; };
struct PrepArgs {
  TJob j[8];
  const float* gatW1; const float* Wcp; const float* bcp; short* Wcompb; float* bcomp;
  const float* tdWo; const float* tdWv; const float* tdbv; const float* tdbo;
  float* A_td; float* Wcat_t; float* bcat;
};

__global__ __launch_bounds__(256) void hg_prep1(PrepArgs a) {
  int y = blockIdx.y, t = threadIdx.x;
  if (y < 8) {
    TJob jb = a.j[y];
    int total = jb.SR * jb.SC;
    for (int idx = blockIdx.x * 256 + t; idx < total; idx += gridDim.x * 256) {
      int r = idx / jb.SC, c = idx - r * jb.SC;
      jb.dst[(size_t)c * jb.dld + r] = jb.src[idx];
    }
  } else if (y == 8) {
    // pc0: Wcomp[j][k] = sum_m gatW1[j][m]*Wcp[m][k]  (bf16, j-major for MFMA B frags)
    int j = blockIdx.x, k = t;
    float acc = 0.f;
#pragma unroll 4
    for (int m = 0; m < 128; ++m) acc = fmaf(a.gatW1[j * 128 + m], a.Wcp[m * 256 + k], acc);
    a.Wcompb[(size_t)j * 256 + k] = (short)f2b(acc);
    if (k == 0) {
      float b = 0.f;
      for (int m = 0; m < 128; ++m) b = fmaf(a.gatW1[j * 128 + m], a.bcp[m], b);
      a.bcomp[j] = b;
    }
  } else if (blockIdx.x < 64) {
    int j = blockIdx.x * 2 + (t >> 7), k = t & 127;
    float acc = 0.f;
#pragma unroll 4
    for (int p = 0; p < 128; ++p) acc = fmaf(a.tdWo[j * 128 + p], a.tdWv[p * 128 + k], acc);
    a.A_td[j * 128 + k] = acc;
    a.Wcat_t[k * 896 + j] = acc;
    if (k == 0) {
      float b = 0.f;
      for (int p = 0; p < 128; ++p) b = fmaf(a.tdWo[j * 128 + p], a.tdbv[p], b);
      a.bcat[j] = b + a.tdbo[j];
    }
  }
}

__global__ __launch_bounds__(256) void hg_pc2b(const float* __restrict__ Wih, const float* __restrict__ bih,
                                               const float* __restrict__ Whh, const float* __restrict__ bhh,
                                               const float* __restrict__ A_td, float* __restrict__ Wcat_t,
                                               float* __restrict__ bcat) {
  int jj = blockIdx.x * 2 + (threadIdx.x >> 7), k = threadIdx.x & 127;
  const float* coef;
  float extra, bb;
  int dcol, j;
  if (jj < 384) {
    j = jj; coef = Wih + (size_t)j * 256; extra = Wih[(size_t)j * 256 + 128 + k]; dcol = 128 + j; bb = bih[j];
  } else {
    j = jj - 384; coef = Whh + (size_t)j * 128; extra = 0.f; dcol = 512 + j; bb = bhh[j];
  }
  float a = 0.f;
#pragma unroll 4
  for (int m = 0; m < 128; ++m) a = fmaf(coef[m], A_td[m * 128 + k], a);
  Wcat_t[k * 896 + dcol] = a + extra;
  if (k == 0) {
    float b = 0.f;
    for (int m = 0; m < 128; ++m) b = fmaf(coef[m], bcat[m], b);
    bcat[dcol] = b + bb;
  }
}

// ---------------- MFMA bf16 GEMM (K=256, tile 128x128, no LDS) + GAT-coef epilogue ----------------
__global__ __launch_bounds__(256, 2) void hg_gemm_coef(
    const float* __restrict__ A, int M, int rtiles,
    const short* __restrict__ Wb,          // bf16 [128][256] j-major
    const float* __restrict__ bias,
    unsigned short* __restrict__ outp,     // bf16 [M][128]
    const float* __restrict__ avs, const float* __restrict__ avd,
    float* __restrict__ o_s, float* __restrict__ o_d,
    const int* __restrict__ list, const int* __restrict__ coff,
    const float* __restrict__ Wtpt, const float* __restrict__ btp, float* __restrict__ tish) {
  __shared__ float mrow[256];
  const int t = threadIdx.x;

  if (blockIdx.x >= rtiles) {
    // ---- tissue init: per-cluster mean + projection (fp32) ----
    int c = blockIdx.x - rtiles;
    int s0 = coff[c], n = coff[c + 1] - s0;
    float acc = 0.f;
#pragma unroll 4
    for (int i = 0; i < n; ++i) acc += A[(size_t)list[s0 + i] * F + t];
    mrow[t] = acc / fmaxf((float)n, 1.f);
    __syncthreads();
    if (t < 128) {
      float a = btp[t];
#pragma unroll 4
      for (int k = 0; k < 256; ++k) a = fmaf(mrow[k], Wtpt[k * 128 + t], a);
      tish[c * 128 + t] = a;
    }
    return;
  }

  const int w = t >> 6, l = t & 63;
  const int li = l & 15, lk = l >> 4;   // li: row/col within 16-tile, lk: k-group
  const int m0 = blockIdx.x * 128 + w * 32;

  f32x4 zero = {0.f, 0.f, 0.f, 0.f};
  f32x4 acc[2][8];
#pragma unroll
  for (int rt = 0; rt < 2; ++rt)
#pragma unroll
    for (int ct = 0; ct < 8; ++ct) acc[rt][ct] = zero;

  const int r0 = m0 + li, r1 = m0 + 16 + li;
  const bool v0 = r0 < M, v1 = r1 < M;
  const float* a0p = A + (size_t)r0 * 256 + lk * 8;
  const float* a1p = A + (size_t)r1 * 256 + lk * 8;

  for (int kc = 0; kc < 256; kc += 32) {
    short8 bf[8];
#pragma unroll
    for (int ct = 0; ct < 8; ++ct)
      bf[ct] = *(const short8*)&Wb[(size_t)(ct * 16 + li) * 256 + kc + lk * 8];
    short8 af0 = {0, 0, 0, 0, 0, 0, 0, 0};
    short8 af1 = {0, 0, 0, 0, 0, 0, 0, 0};
    if (v0) {
      float4 x = *(const float4*)(a0p + kc);
      float4 y = *(const float4*)(a0p + kc + 4);
      af0[0] = (short)f2b(x.x); af0[1] = (short)f2b(x.y); af0[2] = (short)f2b(x.z); af0[3] = (short)f2b(x.w);
      af0[4] = (short)f2b(y.x); af0[5] = (short)f2b(y.y); af0[6] = (short)f2b(y.z); af0[7] = (short)f2b(y.w);
    }
    if (v1) {
      float4 x = *(const float4*)(a1p + kc);
      float4 y = *(const float4*)(a1p + kc + 4);
      af1[0] = (short)f2b(x.x); af1[1] = (short)f2b(x.y); af1[2] = (short)f2b(x.z); af1[3] = (short)f2b(x.w);
      af1[4] = (short)f2b(y.x); af1[5] = (short)f2b(y.y); af1[6] = (short)f2b(y.z); af1[7] = (short)f2b(y.w);
    }
#pragma unroll
    for (int ct = 0; ct < 8; ++ct) {
      acc[0][ct] = __builtin_amdgcn_mfma_f32_16x16x32_bf16(af0, bf[ct], acc[0][ct], 0, 0, 0);
      acc[1][ct] = __builtin_amdgcn_mfma_f32_16x16x32_bf16(af1, bf[ct], acc[1][ct], 0, 0, 0);
    }
  }

  // epilogue: bias, bf16 store, per-head coef dots (o_s/o_d)
#pragma unroll
  for (int ct = 0; ct < 8; ++ct) {
    float bj = bias[ct * 16 + li];
    float as = avs[ct * 16 + li];
    float ad = avd[ct * 16 + li];
#pragma unroll
    for (int rt = 0; rt < 2; ++rt) {
#pragma unroll
      for (int r = 0; r < 4; ++r) {
        int gm = m0 + rt * 16 + lk * 4 + r;
        float v = acc[rt][ct][r] + bj;
        if (gm < M) outp[(size_t)gm * 128 + ct * 16 + li] = f2b(v);
        float ps = v * as, pd = v * ad;
        ps += __shfl_xor(ps, 1); ps += __shfl_xor(ps, 2); ps += __shfl_xor(ps, 4); ps += __shfl_xor(ps, 8);
        pd += __shfl_xor(pd, 1); pd += __shfl_xor(pd, 2); pd += __shfl_xor(pd, 4); pd += __shfl_xor(pd, 8);
        if (li == 0 && gm < M) {
          o_s[(size_t)gm * 8 + ct] = ps;
          o_d[(size_t)gm * 8 + ct] = pd;
        }
      }
    }
  }
}

// ---------------- GAT aggregation: one WAVE per node, bf16 gathers ----------------
#define GMAXE 64
__global__ __launch_bounds__(256) void hg_gat_agg(
    const unsigned short* __restrict__ hproj, const float* __restrict__ a_s,
    const float* __restrict__ a_d, const int* __restrict__ remap,
    const int* __restrict__ off, const int* __restrict__ csr,
    const float* __restrict__ bias, unsigned short* __restrict__ outh,
    const float* __restrict__ qk, const float* __restrict__ qb,
    const int* __restrict__ lab, const int* __restrict__ nodelist,
    float* __restrict__ satt, int nNodes) {
  const int wid = threadIdx.x >> 6;
  const int l = threadIdx.x & 63;
  const int gid = blockIdx.x * 4 + wid;
  __shared__ int srcs_s[4][GMAXE];
  __shared__ float w_s[4][GMAXE][8];
  if (gid >= nNodes) return;
  const int node = nodelist[gid];
  int* srcs = srcs_s[wid];
  float (*wls)[8] = w_s[wid];
  const int o0 = off[node], deg = off[node + 1] - o0;
  const int cl = lab[node];
  const int dl = remap ? cl : node;
  const int hsc = l & 7;
  const int q4 = l & 31;
  const int sub = l >> 5;
  const int hq = q4 >> 2;
  const float adh = a_d[dl * 8 + hsc];
  const float ash = a_s[dl * 8 + hsc];
  float msc = -INFINITY, zsc = 0.f;
  float4 acc = make_float4(0.f, 0.f, 0.f, 0.f);
  const ushort4* hp4 = (const ushort4*)hproj;  // 4 bf16 per element

  for (int cb = 0; cb < deg; cb += GMAXE) {
    const int len = min(GMAXE, deg - cb);
    if (l < len) {
      int s = csr[o0 + cb + l];
      srcs[l] = remap ? remap[s] : s;
    }
    asm volatile("s_waitcnt lgkmcnt(0)" ::: "memory");
    float lm = -INFINITY;
    for (int base = 0; base < len; base += 8) {
      int e = base + (l >> 3);
      if (e < len) {
        float sc = a_s[srcs[e] * 8 + hsc] + adh;
        sc = sc > 0.f ? sc : 0.2f * sc;
        wls[e][hsc] = sc;
        lm = fmaxf(lm, sc);
      }
    }
    lm = fmaxf(lm, __shfl_xor(lm, 8));
    lm = fmaxf(lm, __shfl_xor(lm, 16));
    lm = fmaxf(lm, __shfl_xor(lm, 32));
    float mnew = fmaxf(msc, lm);
    float rs = __expf(msc - mnew);
    float zc = 0.f;
    asm volatile("s_waitcnt lgkmcnt(0)" ::: "memory");
    for (int base = 0; base < len; base += 8) {
      int e = base + (l >> 3);
      if (e < len) {
        float wv = __expf(wls[e][hsc] - mnew);
        wls[e][hsc] = wv;
        zc += wv;
      }
    }
    asm volatile("s_waitcnt lgkmcnt(0)" ::: "memory");
    zc += __shfl_xor(zc, 8); zc += __shfl_xor(zc, 16); zc += __shfl_xor(zc, 32);
    zsc = zsc * rs + zc;
    msc = mnew;
    float rsa = __shfl(rs, hq);
    acc.x *= rsa; acc.y *= rsa; acc.z *= rsa; acc.w *= rsa;
    for (int e = sub; e < len; e += 2) {
      float wv = wls[e][hq];
      ushort4 hv = hp4[(size_t)srcs[e] * 32 + q4];
      acc.x = fmaf(wv, b2f(hv.x), acc.x);
      acc.y = fmaf(wv, b2f(hv.y), acc.y);
      acc.z = fmaf(wv, b2f(hv.z), acc.z);
      acc.w = fmaf(wv, b2f(hv.w), acc.w);
    }
  }
  float ssl = ash + adh;
  ssl = ssl > 0.f ? ssl : 0.2f * ssl;
  float mnew = fmaxf(msc, ssl);
  float rs = __expf(msc - mnew);
  float wsl = __expf(ssl - mnew);
  zsc = zsc * rs + wsl;
  float rsa = __shfl(rs, hq);
  float wsa = __shfl(wsl, hq);
  float zh = __shfl(zsc, hq);
  acc.x *= rsa; acc.y *= rsa; acc.z *= rsa; acc.w *= rsa;
  acc.x += __shfl_xor(acc.x, 32);
  acc.y += __shfl_xor(acc.y, 32);
  acc.z += __shfl_xor(acc.z, 32);
  acc.w += __shfl_xor(acc.w, 32);
  ushort4 hvs = hp4[(size_t)dl * 32 + q4];
  acc.x = fmaf(wsa, b2f(hvs.x), acc.x);
  acc.y = fmaf(wsa, b2f(hvs.y), acc.y);
  acc.z = fmaf(wsa, b2f(hvs.z), acc.z);
  acc.w = fmaf(wsa, b2f(hvs.w), acc.w);
  float inv = 1.f / zh;
  float4 bv4 = *(const float4*)&bias[q4 * 4];
  float4 o;
  o.x = acc.x * inv + bv4.x;
  o.y = acc.y * inv + bv4.y;
  o.z = acc.z * inv + bv4.z;
  o.w = acc.w * inv + bv4.w;
  o.x = o.x > 0.f ? o.x : __expf(o.x) - 1.f;
  o.y = o.y > 0.f ? o.y : __expf(o.y) - 1.f;
  o.z = o.z > 0.f ? o.z : __expf(o.z) - 1.f;
  o.w = o.w > 0.f ? o.w : __expf(o.w) - 1.f;
  if (sub == 0) {
    ushort4 ov = make_ushort4(f2b(o.x), f2b(o.y), f2b(o.z), f2b(o.w));
    ((ushort4*)outh)[(size_t)node * 32 + q4] = ov;
  }

  // s_att epilogue (qk L2-hot via clu_list ordering)
  const float4* qk4 = (const float4*)(qk + (size_t)cl * 1024);
  float p0, p1, p2, p3;
  {
    float4 qv0 = qk4[(sub * 4 + 0) * 32 + q4];
    float4 qv1 = qk4[(sub * 4 + 1) * 32 + q4];
    float4 qv2 = qk4[(sub * 4 + 2) * 32 + q4];
    float4 qv3 = qk4[(sub * 4 + 3) * 32 + q4];
    p0 = o.x * qv0.x + o.y * qv0.y + o.z * qv0.z + o.w * qv0.w;
    p1 = o.x * qv1.x + o.y * qv1.y + o.z * qv1.z + o.w * qv1.w;
    p2 = o.x * qv2.x + o.y * qv2.y + o.z * qv2.z + o.w * qv2.w;
    p3 = o.x * qv3.x + o.y * qv3.y + o.z * qv3.z + o.w * qv3.w;
  }
  int b4f = (l >> 4) & 1, b3f = (l >> 3) & 1;
  float snd0 = b4f ? p0 : p2, snd1 = b4f ? p1 : p3;
  float kp0  = b4f ? p2 : p0, kp1  = b4f ? p3 : p1;
  kp0 += __shfl_xor(snd0, 16);
  kp1 += __shfl_xor(snd1, 16);
  float snd = b3f ? kp0 : kp1;
  float kp  = b3f ? kp1 : kp0;
  kp += __shfl_xor(snd, 8);
  kp += __shfl_xor(kp, 4);
  kp += __shfl_xor(kp, 2);
  kp += __shfl_xor(kp, 1);
  int h = sub * 4 + b4f * 2 + b3f;
  if ((l & 7) == 0) satt[(size_t)node * 8 + h] = kp + qb[cl * 8 + h];
}

// ---------------- tissue GCN + q projection + qk/qb tables ----------------
__global__ __launch_bounds__(128) void hg_gcn_q(const float* __restrict__ tin, const int* __restrict__ toff,
                                                const int* __restrict__ tlist, const float* __restrict__ dinv,
                                                const float* __restrict__ gt, const float* __restrict__ gcnb,
                                                const float* __restrict__ Wqt, const float* __restrict__ bq,
                                                const float* __restrict__ Wk, const float* __restrict__ bk,
                                                float* __restrict__ qk, float* __restrict__ qb) {
  int c = blockIdx.x, t = threadIdx.x;
  __shared__ float xa[128], trow[128], qrow[128];
  float dc = dinv[c];
  float acc = tin[c * 128 + t] * dc * dc;
  int s0 = toff[c], s1 = toff[c + 1];
  for (int i = s0; i < s1; ++i) {
    int s = tlist[i];
    acc = fmaf(tin[s * 128 + t], dinv[s] * dc, acc);
  }
  xa[t] = acc;
  __syncthreads();
  float th = 0.f;
#pragma unroll 4
  for (int k = 0; k < 128; ++k) th = fmaf(xa[k], gt[k * 128 + t], th);
  float vv = fmaxf(th + gcnb[t], 0.f);
  trow[t] = vv;
  __syncthreads();
  float qa = bq[t];
#pragma unroll 4
  for (int k = 0; k < 128; ++k) qa = fmaf(trow[k], Wqt[k * 128 + t], qa);
  qrow[t] = qa * 0.25f;  // 1/sqrt(DH)
  __syncthreads();
#pragma unroll
  for (int h = 0; h < 8; ++h) {
    float s = 0.f;
#pragma unroll
    for (int j = 0; j < 16; ++j) s = fmaf(Wk[(size_t)(h * 16 + j) * 128 + t], qrow[h * 16 + j], s);
    qk[((size_t)c * 8 + h) * 128 + t] = s;
  }
  if (t < 8) {
    float s = 0.f;
#pragma unroll
    for (int j = 0; j < 16; ++j) s = fmaf(qrow[t * 16 + j], bk[t * 16 + j], s);
    qb[c * 8 + t] = s;
  }
}

// ---------------- bu softmax partials: grid (C, SPL), bf16 gathers ----------------
__global__ __launch_bounds__(256) void hg_bu_part(
    const float* __restrict__ s_att, const unsigned short* __restrict__ hcell,
    const int* __restrict__ list, const int* __restrict__ coff,
    float* __restrict__ pm, float* __restrict__ pz, float* __restrict__ pmacc) {
  int c = blockIdx.x, sp = blockIdx.y, t = threadIdx.x;
  int s0 = coff[c], n = coff[c + 1] - s0;
  int chunk = (n + SPL - 1) / SPL;
  int b0 = min(n, sp * chunk), b1 = min(n, b0 + chunk);
  int cnt = b1 - b0;
  int tf = t & 127, half = t >> 7;
  __shared__ float red[32][8];
  __shared__ float mh[8];
  __shared__ int cells[64];
  __shared__ float wl[64][8];
  __shared__ float msh[8][128];
  int g = t >> 3, h8 = t & 7;
  float lm = -INFINITY;
  for (int i = g; i < cnt; i += 32) lm = fmaxf(lm, s_att[(size_t)list[s0 + b0 + i] * 8 + h8]);
  red[g][h8] = lm;
  __syncthreads();
  if (t < 8) {
    float m2 = -INFINITY;
#pragma unroll
    for (int i = 0; i < 32; ++i) m2 = fmaxf(m2, red[i][t]);
    mh[t] = m2;
  }
  __syncthreads();
  const float mloc = mh[t & 7];
  float zp = 0.f;
  float macc[8] = {0.f, 0.f, 0.f, 0.f, 0.f, 0.f, 0.f, 0.f};
  for (int cb = 0; cb < cnt; cb += 64) {
    int len = min(64, cnt - cb);
    if (t < len) cells[t] = list[s0 + b0 + cb + t];
    __syncthreads();
#pragma unroll
    for (int p = 0; p < 2; ++p) {
      int e = p * 32 + (t >> 3);
      if (e < len) {
        float w = __expf(s_att[(size_t)cells[e] * 8 + (t & 7)] - mloc);
        wl[e][t & 7] = w;
        zp += w;
      }
    }
    __syncthreads();
    for (int e = half; e < len; e += 2) {
      float x = b2f(hcell[(size_t)cells[e] * 128 + tf]);
      float4 w0 = *(const float4*)&wl[e][0];
      float4 w1 = *(const float4*)&wl[e][4];
      macc[0] = fmaf(w0.x, x, macc[0]);
      macc[1] = fmaf(w0.y, x, macc[1]);
      macc[2] = fmaf(w0.z, x, macc[2]);
      macc[3] = fmaf(w0.w, x, macc[3]);
      macc[4] = fmaf(w1.x, x, macc[4]);
      macc[5] = fmaf(w1.y, x, macc[5]);
      macc[6] = fmaf(w1.z, x, macc[6]);
      macc[7] = fmaf(w1.w, x, macc[7]);
    }
    __syncthreads();
  }
  red[t >> 3][t & 7] = zp;
  __syncthreads();
  int pidx = (c * SPL + sp) * 8;
  if (t < 8) {
    float z = 0.f;
#pragma unroll
    for (int i = 0; i < 32; ++i) z += red[i][t];
    pz[pidx + t] = z;
    pm[pidx + t] = mh[t];
  }
  if (half) {
#pragma unroll
    for (int h = 0; h < 8; ++h) msh[h][tf] = macc[h];
  }
  __syncthreads();
  if (!half) {
#pragma unroll
    for (int h = 0; h < 8; ++h) pmacc[(size_t)(pidx + h) * 128 + tf] = macc[h] + msh[h][tf];
  }
}

// ---------------- fused cluster chain: merge partials, Wv, Wo, td+GRU, gates, next GAT proj ----------------
__global__ __launch_bounds__(256) void hg_bu_chain(
    const float* __restrict__ pm, const float* __restrict__ pz, const float* __restrict__ pmacc,
    const float* __restrict__ Wv, const float* __restrict__ bv,
    const float* __restrict__ Wot, const float* __restrict__ bo,
    const float* __restrict__ Wcat_t, const float* __restrict__ bcat,
    const float* __restrict__ gatWt, const float* __restrict__ avs, const float* __restrict__ avd,
    float* __restrict__ tish, float* __restrict__ ccell,
    unsigned short* __restrict__ hprojc, float* __restrict__ a_s2, float* __restrict__ a_d2) {
  int c = blockIdx.x, t = threadIdx.x;
  int tf = t & 127, half = t >> 7;
  __shared__ float mh[8], zh[8];
  __shared__ float sscale[SPL][8];
  __shared__ float msh[8][128];
  __shared__ float b0[128], b1[128], part[2][128], catv[896];
  const int pbase = c * SPL * 8;
  if (t < 8) {
    float mg = -INFINITY;
#pragma unroll
    for (int s = 0; s < SPL; ++s) mg = fmaxf(mg, pm[pbase + s * 8 + t]);
    mh[t] = mg;
  }
  __syncthreads();
  if (t < SPL * 8) {
    int s = t >> 3, h = t & 7;
    float ms = pm[pbase + s * 8 + h];
    sscale[s][h] = (ms > -1e37f) ? __expf(ms - mh[h]) : 0.f;
  }
  __syncthreads();
  if (t < 8) {
    float z = 0.f;
#pragma unroll
    for (int s = 0; s < SPL; ++s) z += pz[pbase + s * 8 + t] * sscale[s][t];
    zh[t] = (z > 0.f) ? 1.f / z : 0.f;
  }
  __syncthreads();
#pragma unroll
  for (int hh = 0; hh < 4; ++hh) {
    int h = half * 4 + hh;
    float a = 0.f;
#pragma unroll
    for (int s = 0; s < SPL; ++s)
      a = fmaf(pmacc[(size_t)(pbase + s * 8 + h) * 128 + tf], sscale[s][h], a);
    msh[h][tf] = a * zh[h];
  }
  __syncthreads();
  {
    int h = tf >> 4;
    float ps = 0.f;
    const float* wp = Wv + (size_t)tf * 128 + half * 64;
    const float* mp = &msh[h][half * 64];
#pragma unroll 4
    for (int k = 0; k < 64; ++k) ps = fmaf(wp[k], mp[k], ps);
    part[half][tf] = ps;
  }
  __syncthreads();
  if (t < 128) b0[t] = part[0][t] + part[1][t] + bv[t];
  __syncthreads();
  int ks = half;
  {
    float ps = 0.f;
    const float* wp = Wot + (size_t)ks * 64 * 128 + tf;
#pragma unroll 4
    for (int k = 0; k < 64; ++k) ps = fmaf(b0[ks * 64 + k], wp[k * 128], ps);
    part[ks][tf] = ps;
  }
  __syncthreads();
  if (t < 128) {
    float vv = part[0][t] + part[1][t] + bo[t];
    b1[t] = vv;
    tish[c * 128 + t] = vv;
  }
  __syncthreads();
  for (int j = t; j < 896; j += 256) {
    float a = bcat[j];
#pragma unroll 4
    for (int k = 0; k < 128; ++k) a = fmaf(b1[k], Wcat_t[k * 896 + j], a);
    catv[j] = a;
  }
  __syncthreads();
  if (t < 128) {
    float td = catv[t];
    float r = 1.f / (1.f + expf(-(catv[128 + t] + catv[512 + t])));
    float zz = 1.f / (1.f + expf(-(catv[256 + t] + catv[640 + t])));
    float nn = tanhf(catv[384 + t] + r * catv[768 + t]);
    float cn = (1.f - zz) * nn + zz * td;
    ccell[c * 128 + t] = cn;
    b0[t] = cn;
  }
  __syncthreads();
  if (gatWt) {
    float ps = 0.f;
    const float* wp = gatWt + (size_t)ks * 64 * 128 + tf;
#pragma unroll 4
    for (int k = 0; k < 64; ++k) ps = fmaf(b0[ks * 64 + k], wp[k * 128], ps);
    part[ks][tf] = ps;
    __syncthreads();
    if (t < 128) {
      float hp = part[0][t] + part[1][t];
      hprojc[c * 128 + t] = f2b(hp);
      float pss = hp * avs[t], pdd = hp * avd[t];
      pss += __shfl_xor(pss, 1); pss += __shfl_xor(pss, 2); pss += __shfl_xor(pss, 4); pss += __shfl_xor(pss, 8);
      pdd += __shfl_xor(pdd, 1); pdd += __shfl_xor(pdd, 2); pdd += __shfl_xor(pdd, 4); pdd += __shfl_xor(pdd, 8);
      if ((t & 15) == 0) {
        a_s2[c * 8 + (t >> 4)] = pss;
        a_d2[c * 8 + (t >> 4)] = pdd;
      }
    }
  }
}

// ---------------- parallel dual-pool partials: grid PB blocks ----------------
__global__ __launch_bounds__(256) void hg_pool(const float* __restrict__ ccell2, const float* __restrict__ tish,
                                               const int* __restrict__ cnt, float* __restrict__ part) {
  int b = blockIdx.x, t = threadIdx.x;
  int c0 = b * (C / PB);
  if (t < 128) {
    float sm = 0.f, mx = -INFINITY;
#pragma unroll 4
    for (int i = 0; i < C / PB; ++i) {
      int c = c0 + i;
      float vv = ccell2[c * 128 + t];
      int n = cnt[c];
      sm += (float)n * vv;
      if (n > 0) mx = fmaxf(mx, vv);
    }
    part[b * 512 + t] = sm;
    part[b * 512 + 128 + t] = mx;
  } else {
    int tt = t - 128;
    float sm = 0.f, mx = -INFINITY;
#pragma unroll 4
    for (int i = 0; i < C / PB; ++i) {
      int c = c0 + i;
      float vv = tish[c * 128 + tt];
      sm += vv;
      mx = fmaxf(mx, vv);
    }
    part[b * 512 + 256 + tt] = sm;
    part[b * 512 + 384 + tt] = mx;
  }
}

// ---------------- classifier MLP (merges pool partials) ----------------
__global__ __launch_bounds__(256) void hg_mlp(const float* __restrict__ part, const float* __restrict__ Wc1t,
                                              const float* __restrict__ bc1, const float* __restrict__ Wc2t,
                                              const float* __restrict__ bc2, const float* __restrict__ Wc3,
                                              const float* __restrict__ bc3, float* __restrict__ outp) {
  __shared__ float emb[512], h1s[256], h2s[128];
  int t = threadIdx.x;
  if (t < 128) {
    float sm = 0.f, mx = -INFINITY;
#pragma unroll
    for (int b = 0; b < PB; ++b) {
      sm += part[b * 512 + t];
      mx = fmaxf(mx, part[b * 512 + 128 + t]);
    }
    emb[t] = sm / (float)N;
    emb[128 + t] = mx;
  } else {
    int tt = t - 128;
    float sm = 0.f, mx = -INFINITY;
#pragma unroll
    for (int b = 0; b < PB; ++b) {
      sm += part[b * 512 + 256 + tt];
      mx = fmaxf(mx, part[b * 512 + 384 + tt]);
    }
    emb[256 + tt] = sm * (1.f / (float)C);
    emb[384 + tt] = mx;
  }
  __syncthreads();
  float a = bc1[t];
#pragma unroll 4
  for (int kk = 0; kk < 512; ++kk) a = fmaf(emb[kk], Wc1t[kk * 256 + t], a);
  h1s[t] = fmaxf(a, 0.f);
  __syncthreads();
  if (t < 128) {
    float a2 = bc2[t];
#pragma unroll 4
    for (int kk = 0; kk < 256; ++kk) a2 = fmaf(h1s[kk], Wc2t[kk * 128 + t], a2);
    h2s[t] = fmaxf(a2, 0.f);
  }
  __syncthreads();
  if (t < 4) {
    float o = bc3[t];
    for (int kk = 0; kk < 128; ++kk) o = fmaf(h2s[kk], Wc3[t * 128 + kk], o);
    outp[t] = o;
  }
}

// ---------------- host launcher ----------------
extern "C" void kernel_launch(void* const* d_in, const int* in_sizes, int n_in,
                              void* d_out, int out_size, void* d_ws, size_t ws_size,
                              hipStream_t stream) {
  (void)in_sizes; (void)n_in; (void)out_size; (void)ws_size;
  const float* feat  = (const float*)d_in[0];
  const int*   eidx  = (const int*)d_in[1];
  const int*   lab   = (const int*)d_in[2];
  const int*   tidx  = (const int*)d_in[3];
  const float* Wcp   = (const float*)d_in[4];
  const float* bcp   = (const float*)d_in[5];
  const float* Wtp   = (const float*)d_in[6];
  const float* btp   = (const float*)d_in[7];
  const float* gatW  = (const float*)d_in[8];
  const float* gasrc = (const float*)d_in[9];
  const float* gadst = (const float*)d_in[10];
  const float* gatb  = (const float*)d_in[11];
  const float* gcnW  = (const float*)d_in[12];
  const float* gcnb  = (const float*)d_in[13];
  const float* buWq  = (const float*)d_in[14];
  const float* buWk  = (const float*)d_in[15];
  const float* buWv  = (const float*)d_in[16];
  const float* bubq  = (const float*)d_in[17];
  const float* bubk  = (const float*)d_in[18];
  const float* bubv  = (const float*)d_in[19];
  const float* buWo  = (const float*)d_in[20];
  const float* bubo  = (const float*)d_in[21];
  const float* tdWv  = (const float*)d_in[22];
  const float* tdbv  = (const float*)d_in[23];
  const float* tdWo  = (const float*)d_in[24];
  const float* tdbo  = (const float*)d_in[25];
  const float* Wih   = (const float*)d_in[26];
  const float* bih   = (const float*)d_in[27];
  const float* Whh   = (const float*)d_in[28];
  const float* bhh   = (const float*)d_in[29];
  const float* Wc1   = (const float*)d_in[30];
  const float* bc1   = (const float*)d_in[31];
  const float* Wc2   = (const float*)d_in[32];
  const float* bc2   = (const float*)d_in[33];
  const float* Wc3   = (const float*)d_in[34];
  const float* bc3   = (const float*)d_in[35];
  float* outp = (float*)d_out;

  const int* csrc = eidx;
  const int* cdst = eidx + E;
  const int* tsrc = tidx;
  const int* tdst = tidx + ET;

  char* w = (char*)d_ws;
  auto alloc = [&](size_t bytes) -> void* {
    void* p = (void*)w;
    w += (bytes + 255) & ~(size_t)255;
    return p;
  };
  char* cnt0 = w;
  int* deg_cell = (int*)alloc((size_t)N * 4);
  int* cur_cell = (int*)alloc((size_t)N * 4);
  int* clu_cnt  = (int*)alloc((size_t)C * 4);
  int* clu_cur  = (int*)alloc((size_t)C * 4);
  size_t cntBytes = (size_t)(w - cnt0);
  int* off_cell = (int*)alloc((size_t)(N + 1) * 4);
  int* btot     = (int*)alloc(64 * 4);
  int* csr      = (int*)alloc((size_t)E * 4);
  int* clu_off  = (int*)alloc((size_t)(C + 1) * 4);
  int* clu_list = (int*)alloc((size_t)N * 4);
  int* toff     = (int*)alloc((size_t)(C + 1) * 4);
  int* tlist    = (int*)alloc((size_t)ET * 4);
  float* dinv   = (float*)alloc((size_t)C * 4);
  unsigned short* buf1 = (unsigned short*)alloc((size_t)N * 128 * 2);  // bf16 cell_h
  unsigned short* buf2 = (unsigned short*)alloc((size_t)N * 128 * 2);  // bf16 hproj
  float* a_s    = (float*)alloc((size_t)N * 8 * 4);
  float* a_d    = (float*)alloc((size_t)N * 8 * 4);
  float* s_att  = (float*)alloc((size_t)N * 8 * 4);
  float* tish   = (float*)alloc((size_t)C * 128 * 4);
  float* qkb    = (float*)alloc((size_t)C * 8 * 128 * 4);
  float* qbb    = (float*)alloc((size_t)C * 8 * 4);
  float* ccell  = (float*)alloc((size_t)C * 128 * 4);
  unsigned short* hprojc = (unsigned short*)alloc((size_t)C * 128 * 2);
  float* a_sc   = (float*)alloc((size_t)C * 8 * 4);
  float* a_dc   = (float*)alloc((size_t)C * 8 * 4);
  float* pm     = (float*)alloc((size_t)C * SPL * 8 * 4);
  float* pz     = (float*)alloc((size_t)C * SPL * 8 * 4);
  float* pmacc  = (float*)alloc((size_t)C * SPL * 8 * 128 * 4);
  float* poolp  = (float*)alloc((size_t)PB * 512 * 4);
  float* A_td   = (float*)alloc(128 * 128 * 4);
  float* Wcat_t = (float*)alloc(128 * 896 * 4);
  float* bcat   = (float*)alloc(896 * 4);
  short* Wcompb = (short*)alloc(128 * 256 * 2);   // bf16 composite weight [j][k]
  float* bcomp  = (float*)alloc(128 * 4);
  float* Wtpt   = (float*)alloc(256 * 128 * 4);
  float* g1t    = (float*)alloc(128 * 128 * 4);
  float* g2t    = (float*)alloc(128 * 128 * 4);
  float* Wqt    = (float*)alloc(128 * 128 * 4);
  float* Wot    = (float*)alloc(128 * 128 * 4);
  float* gatW2t = (float*)alloc(128 * 128 * 4);
  float* Wc1t   = (float*)alloc(512 * 256 * 4);
  float* Wc2t   = (float*)alloc(256 * 128 * 4);

  hipMemsetAsync(cnt0, 0, cntBytes, stream);

  hg_hist<<<(E + 255) / 256, 256, 0, stream>>>(cdst, deg_cell, lab, clu_cnt);
  hg_scan1<<<NB, 256, 0, stream>>>(deg_cell, off_cell, btot, N);
  hg_scan2_setup<<<3, 256, 0, stream>>>(btot, off_cell, clu_cnt, clu_off, tsrc, tdst, toff, tlist, dinv);
  hg_scan3<<<NB, 256, 0, stream>>>(off_cell, btot, N);
  hg_scatter<<<(E + 255) / 256, 256, 0, stream>>>(csrc, cdst, off_cell, cur_cell, csr,
                                                  lab, clu_off, clu_cur, clu_list);

  PrepArgs pa;
  pa.j[0] = {Wtp,            Wtpt,   128, 256, 128};
  pa.j[1] = {gcnW,           g1t,    128, 128, 128};
  pa.j[2] = {gcnW + 128*128, g2t,    128, 128, 128};
  pa.j[3] = {buWq,           Wqt,    128, 128, 128};
  pa.j[4] = {buWo,           Wot,    128, 128, 128};
  pa.j[5] = {gatW + 128*128, gatW2t, 128, 128, 128};
  pa.j[6] = {Wc1,            Wc1t,   256, 512, 256};
  pa.j[7] = {Wc2,            Wc2t,   128, 256, 128};
  pa.gatW1 = gatW; pa.Wcp = Wcp; pa.bcp = bcp; pa.Wcompb = Wcompb; pa.bcomp = bcomp;
  pa.tdWo = tdWo; pa.tdWv = tdWv; pa.tdbv = tdbv; pa.tdbo = tdbo;
  pa.A_td = A_td; pa.Wcat_t = Wcat_t; pa.bcat = bcat;
  hg_prep1<<<dim3(128, 10), 256, 0, stream>>>(pa);
  hg_pc2b<<<384, 256, 0, stream>>>(Wih, bih, Whh, bhh, A_td, Wcat_t, bcat);

  const int RT = (N + 127) / 128;  // 469 row tiles
  hg_gemm_coef<<<RT + C, 256, 0, stream>>>(feat, N, RT, Wcompb, bcomp, buf2, gasrc, gadst, a_s, a_d,
                                           clu_list, clu_off, Wtpt, btp, tish);
  // ---- layer 1 ----
  hg_gcn_q<<<C, 128, 0, stream>>>(tish, toff, tlist, dinv, g1t, gcnb, Wqt, bubq, buWk, bubk, qkb, qbb);
  hg_gat_agg<<<(N + 3) / 4, 256, 0, stream>>>(buf2, a_s, a_d, nullptr, off_cell, csr, gatb, buf1,
                                              qkb, qbb, lab, clu_list, s_att, N);
  hg_bu_part<<<dim3(C, SPL), 256, 0, stream>>>(s_att, buf1, clu_list, clu_off, pm, pz, pmacc);
  hg_bu_chain<<<C, 256, 0, stream>>>(pm, pz, pmacc, buWv, bubv, Wot, bubo, Wcat_t, bcat,
                                     gatW2t, gasrc + 128, gadst + 128, tish, ccell, hprojc, a_sc, a_dc);
  // ---- layer 2 ----
  hg_gcn_q<<<C, 128, 0, stream>>>(tish, toff, tlist, dinv, g2t, gcnb + 128, Wqt, bubq, buWk, bubk, qkb, qbb);
  hg_gat_agg<<<(N + 3) / 4, 256, 0, stream>>>(hprojc, a_sc, a_dc, lab, off_cell, csr, gatb + 128, buf1,
                                              qkb, qbb, lab, clu_list, s_att, N);
  hg_bu_part<<<dim3(C, SPL), 256, 0, stream>>>(s_att, buf1, clu_list, clu_off, pm, pz, pmacc);
  hg_bu_chain<<<C, 256, 0, stream>>>(pm, pz, pmacc, buWv, bubv, Wot, bubo, Wcat_t, bcat,
                                     nullptr, nullptr, nullptr, tish, ccell, nullptr, nullptr, nullptr);

  hg_pool<<<PB, 256, 0, stream>>>(ccell, tish, clu_cnt, poolp);
  hg_mlp<<<1, 256, 0, stream>>>(poolp, Wc1t, bc1, Wc2t, bc2, Wc3, bc3, outp);
}